// Round 6
// baseline (467.884 us; speedup 1.0000x reference)
//
#include <hip/hip_runtime.h>
#include <hip/hip_bf16.h>
#include <math.h>

// Problem constants
#define BB 2
#define SS 1024
#define DD 1024
#define FF 4096
#define HH 16
#define EE 8
#define MM (BB*SS)          // 2048 tokens
#define MAX_TILES 24        // sum_e ceil(cnt_e/128) <= 2048/128 + 8

typedef __attribute__((ext_vector_type(8))) short bf16x8;
typedef __attribute__((ext_vector_type(8))) short s16x8;
typedef __attribute__((ext_vector_type(4))) short s16x4;
typedef __attribute__((ext_vector_type(4))) float f32x4;

// ---------------- workspace layout (bytes) ----------------
#define OFF_WIT  ((size_t)0)            // wi^T bf16: 8*4096*1024*2 = 67108864
#define OFF_WOT  ((size_t)67108864)     // wo^T bf16: 33554432
#define OFF_WQH  ((size_t)100663296)    // w_qkv hi bf16: 6291456   (later: K split hi/lo, 8MB)
#define OFF_WQL  ((size_t)106954752)    // w_qkv lo bf16: 6291456
#define OFF_WOH  ((size_t)113246208)    // w_out hi bf16: 2097152
#define OFF_WOL  ((size_t)115343360)    // w_out lo bf16: 2097152
#define OFF_H1H  ((size_t)117440512)    // h1 hi bf16: 4194304      (later: VT hi)
#define OFF_H1L  ((size_t)121634816)    // h1 lo bf16: 4194304      (later: VT lo)
#define OFF_QKV  ((size_t)125829120)    // qkv f32: 25165824; later hid bf16 (17.8MB incl tail-pad reads)
#define OFF_H2F  ((size_t)142606336)    // h2 f32: 8388608
#define OFF_OH   ((size_t)150994944)    // attn o hi bf16: 4194304
#define OFF_OL   ((size_t)155189248)    // attn o lo bf16: 4194304
#define OFF_X2   ((size_t)159383552)    // x2 f32: 8388608
#define OFF_H2B  ((size_t)167772160)    // h2 bf16: 4194304
#define OFF_GATE ((size_t)180879360)
#define OFF_EID  ((size_t)180887552)
#define OFF_PERM ((size_t)180895744)
#define OFF_CNT  ((size_t)180903936)    // 17 ints zeroed by k_ln<1>
#define OFF_FILL ((size_t)180903968)
#define OFF_NT   ((size_t)180904000)
#define OFF_TE   ((size_t)180904192)
#define OFF_TS   ((size_t)180904320)
#define OFF_TR   ((size_t)180904448)
// attention K/V split buffers (reuse dead regions)
#define OFF_KSH  OFF_WQH                         // 4MB
#define OFF_KSL  (OFF_WQH + 4194304)             // 4MB (spills into wqL region - dead)
#define OFF_VTH  OFF_H1H                         // 4MB
#define OFF_VTL  OFF_H1L                         // 4MB

// ---------------- async global->LDS (16B per lane) ----------------
__device__ __forceinline__ void gload16(const void* g, void* l) {
    __builtin_amdgcn_global_load_lds(
        (const __attribute__((address_space(1))) unsigned int*)g,
        (__attribute__((address_space(3))) unsigned int*)l, 16, 0, 0);
}

__device__ __forceinline__ short bfh(float v) {
    __hip_bfloat16 h = __float2bfloat16(v);
    return *(short*)&h;
}
__device__ __forceinline__ float bf2f(short s) {
    __hip_bfloat16 h = *(__hip_bfloat16*)&s;
    return __bfloat162float(h);
}

__device__ __forceinline__ void split_write(float v, __hip_bfloat16* hp, __hip_bfloat16* lp, size_t idx) {
    __hip_bfloat16 h = __float2bfloat16(v);
    hp[idx] = h;
    lp[idx] = __float2bfloat16(v - __bfloat162float(h));
}

// ---------------- f32 -> bf16 hi/lo split convert ----------------
__global__ void k_cvt_split(const float* __restrict__ in, __hip_bfloat16* __restrict__ hi,
                            __hip_bfloat16* __restrict__ lo, int n4) {
    int i = blockIdx.x * 256 + threadIdx.x;
    if (i >= n4) return;
    float4 v = ((const float4*)in)[i];
    split_write(v.x, hi, lo, (size_t)i * 4 + 0);
    split_write(v.y, hi, lo, (size_t)i * 4 + 1);
    split_write(v.z, hi, lo, (size_t)i * 4 + 2);
    split_write(v.w, hi, lo, (size_t)i * 4 + 3);
}

// ---------------- batched transpose-convert: in (R,C) f32 -> out (C,R) bf16 ----------------
__global__ void k_tcvt(const float* __restrict__ in, __hip_bfloat16* __restrict__ out, int R, int C) {
    __shared__ float tile[32][33];
    int c0 = blockIdx.x * 32, r0 = blockIdx.y * 32;
    size_t eoff = (size_t)blockIdx.z * R * C;
    in += eoff; out += eoff;
    int t = threadIdx.x;
    int i = t >> 3, j0 = (t & 7) * 4;
    float4 v = *(const float4*)&in[(size_t)(r0 + i) * C + c0 + j0];
    tile[i][j0 + 0] = v.x; tile[i][j0 + 1] = v.y; tile[i][j0 + 2] = v.z; tile[i][j0 + 3] = v.w;
    __syncthreads();
#pragma unroll
    for (int q = 0; q < 4; ++q)
        out[(size_t)(c0 + i) * R + r0 + j0 + q] = __float2bfloat16(tile[j0 + q][i]);
}

// ---------------- LayerNorm: MODE 0 = +RoPE, hi/lo out; MODE 1 = plain, bf16+f32 out ----------------
template<int MODE>
__global__ void k_ln(const float* __restrict__ x, const float* __restrict__ w,
                     const float* __restrict__ b, __hip_bfloat16* __restrict__ hi,
                     __hip_bfloat16* __restrict__ lo, float* __restrict__ f32o,
                     int* __restrict__ zero17) {
    int m = blockIdx.x;
    int s = m & (SS - 1);
    __shared__ float row[DD];
    __shared__ float red[8];
    int t = threadIdx.x;
    if (MODE == 1 && m == 0 && t < 17) zero17[t] = 0;   // routing counters
    const float* xp = x + (size_t)m * DD;
    float sum = 0.f, sumsq = 0.f;
#pragma unroll
    for (int l = 0; l < 4; ++l) {
        int i = t + l * 256;
        float v = xp[i];
        row[i] = v;
        sum += v; sumsq += v * v;
    }
#pragma unroll
    for (int off = 32; off; off >>= 1) {
        sum   += __shfl_xor(sum, off);
        sumsq += __shfl_xor(sumsq, off);
    }
    int wid = t >> 6, lane = t & 63;
    if (lane == 0) { red[wid] = sum; red[4 + wid] = sumsq; }
    __syncthreads();
    sum   = red[0] + red[1] + red[2] + red[3];
    sumsq = red[4] + red[5] + red[6] + red[7];
    float mean = sum * (1.f / DD);
    float var  = sumsq * (1.f / DD) - mean * mean;
    float rstd = rsqrtf(var + 1e-5f);
    size_t base = (size_t)m * DD;
    if (MODE == 0) {
        const float kln = logf(10000.f) / 512.f;
#pragma unroll
        for (int l = 0; l < 2; ++l) {
            int i = t + l * 256;   // 0..511
            float n1 = (row[i]       - mean) * rstd * w[i]       + b[i];
            float n2 = (row[i + 512] - mean) * rstd * w[i + 512] + b[i + 512];
            float inv = expf(-(float)i * kln);
            float ang = (float)s * inv;
            float c = cosf(ang), sn = sinf(ang);
            split_write(n1 * c - n2 * sn,  hi, lo, base + i);
            split_write(n1 * sn + n2 * c, hi, lo, base + i + 512);
        }
    } else {
#pragma unroll
        for (int l = 0; l < 4; ++l) {
            int i = t + l * 256;
            float v = (row[i] - mean) * rstd * w[i] + b[i];
            hi[base + i] = __float2bfloat16(v);
            f32o[base + i] = v;
        }
    }
}

// ---------------- split-precision MFMA GEMM: C = A @ Bt^T + bias (+addsrc) ----------------
template<int MODE>
__global__ void k_mfma_split(const __hip_bfloat16* __restrict__ Ah, const __hip_bfloat16* __restrict__ Al,
                             const __hip_bfloat16* __restrict__ Bh, const __hip_bfloat16* __restrict__ Bl,
                             const float* __restrict__ bias, const float* __restrict__ addsrc,
                             float* __restrict__ Cf, int M, int N, int K) {
    __shared__ __align__(16) short AsH[128 * 32];
    __shared__ __align__(16) short AsL[128 * 32];
    __shared__ __align__(16) short BsH[128 * 32];
    __shared__ __align__(16) short BsL[128 * 32];
    int m0 = blockIdx.y * 128, n0 = blockIdx.x * 128;
    const int t = threadIdx.x;
    const int w = t >> 6, lane = t & 63;
    const int wr = w >> 1, wc = w & 1;
    const int sid = w * 64 + lane;

    f32x4 acc[4][4] = {};

    for (int k0 = 0; k0 < K; k0 += 32) {
#pragma unroll
        for (int j = 0; j < 2; ++j) {
            int id = j * 256 + sid;
            int rrow = id >> 2, sl = id & 3;
            int slog = sl ^ ((rrow >> 1) & 3);
            size_t lbase = (size_t)(j * 256 + w * 64) * 8;
            size_t gaoff = (size_t)(m0 + rrow) * K + k0 + slog * 8;
            gload16(Ah + gaoff, &AsH[lbase]);
            gload16(Al + gaoff, &AsL[lbase]);
            size_t gboff = (size_t)(n0 + rrow) * K + k0 + slog * 8;
            gload16(Bh + gboff, &BsH[lbase]);
            gload16(Bl + gboff, &BsL[lbase]);
        }
        __syncthreads();
        bf16x8 ah[4], al[4], bh[4], bl[4];
#pragma unroll
        for (int i = 0; i < 4; ++i) {
            int ra = wr * 64 + i * 16 + (lane & 15);
            int pa = (lane >> 4) ^ ((ra >> 1) & 3);
            ah[i] = *(const bf16x8*)&AsH[ra * 32 + pa * 8];
            al[i] = *(const bf16x8*)&AsL[ra * 32 + pa * 8];
            int rb = wc * 64 + i * 16 + (lane & 15);
            int pb = (lane >> 4) ^ ((rb >> 1) & 3);
            bh[i] = *(const bf16x8*)&BsH[rb * 32 + pb * 8];
            bl[i] = *(const bf16x8*)&BsL[rb * 32 + pb * 8];
        }
#pragma unroll
        for (int i = 0; i < 4; ++i)
#pragma unroll
            for (int n = 0; n < 4; ++n) {
                acc[i][n] = __builtin_amdgcn_mfma_f32_16x16x32_bf16(ah[i], bh[n], acc[i][n], 0, 0, 0);
                acc[i][n] = __builtin_amdgcn_mfma_f32_16x16x32_bf16(ah[i], bl[n], acc[i][n], 0, 0, 0);
                acc[i][n] = __builtin_amdgcn_mfma_f32_16x16x32_bf16(al[i], bh[n], acc[i][n], 0, 0, 0);
            }
        __syncthreads();
    }

    int cn = n0 + wc * 64 + (lane & 15);
#pragma unroll
    for (int i = 0; i < 4; ++i) {
#pragma unroll
        for (int n = 0; n < 4; ++n) {
            int col = cn + n * 16;
#pragma unroll
            for (int q = 0; q < 4; ++q) {
                int r = wr * 64 + i * 16 + (lane >> 4) * 4 + q;
                float v = acc[i][n][q] + bias[col];
                if (MODE == 1) v += addsrc[(size_t)(m0 + r) * N + col];
                Cf[(size_t)(m0 + r) * N + col] = v;
            }
        }
    }
}

// ---------------- plain bf16 MFMA GEMM for MoE ----------------
// MODE 2: gather A rows via perm; Cb = bf16(acc)                (up-proj -> hid)
// MODE 3: A = hid, silu(a)*g fused in A-staging; out = addsrc + gate*acc
template<int MODE>
__global__ void k_mfma(const __hip_bfloat16* __restrict__ A,
                       const __hip_bfloat16* __restrict__ Bt,
                       const float* __restrict__ addsrc,
                       float* __restrict__ Cf,
                       __hip_bfloat16* __restrict__ Cb,
                       int N, int K,
                       const int* __restrict__ perm,
                       const int* __restrict__ te, const int* __restrict__ ts,
                       const int* __restrict__ tr, const int* __restrict__ ntl,
                       const float* __restrict__ gate) {
    __shared__ __align__(16) short As[128 * 32];
    __shared__ __align__(16) short Bs[128 * 32];
    __shared__ int permS[128];
    int tile = blockIdx.y;
    if (tile >= *ntl) return;
    int e = te[tile], rs = ts[tile], rows = tr[tile];
    if (threadIdx.x < 128) {
        int r = threadIdx.x;
        permS[r] = (r < rows) ? perm[rs + r] : 0;
    }
    __syncthreads();
    int n0 = blockIdx.x * 128;
    const int t = threadIdx.x;
    const int w = t >> 6, lane = t & 63;
    const int wr = w >> 1, wc = w & 1;
    const int sid = w * 64 + lane;

    const __hip_bfloat16* Bp = Bt + (size_t)e * (size_t)N * (size_t)K;

    f32x4 acc[4][4] = {};

    for (int k0 = 0; k0 < K; k0 += 32) {
#pragma unroll
        for (int j = 0; j < 2; ++j) {
            int id = j * 256 + sid;
            int rrow = id >> 2, sl = id & 3;
            int slog = sl ^ ((rrow >> 1) & 3);
            if (MODE == 2) {
                const __hip_bfloat16* ga = A + (size_t)permS[rrow] * K + k0 + slog * 8;
                gload16(ga, &As[(size_t)id * 8]);
            } else {
                // fused silu(a)*g staging from hid (row stride FF, g-half at +2048)
                const __hip_bfloat16* pa = A + (size_t)(rs + rrow) * FF + k0 + slog * 8;
                bf16x8 av = *(const bf16x8*)pa;
                bf16x8 gv = *(const bf16x8*)(pa + 2048);
                bf16x8 res;
#pragma unroll
                for (int q = 0; q < 8; ++q) {
                    float a = bf2f(av[q]);
                    float g = bf2f(gv[q]);
                    res[q] = bfh((a / (1.f + expf(-a))) * g);
                }
                *(bf16x8*)&As[(size_t)id * 8] = res;
            }
            gload16(Bp + (size_t)(n0 + rrow) * K + k0 + slog * 8, &Bs[(size_t)id * 8]);
        }
        __syncthreads();
        bf16x8 af[4], bfr[4];
#pragma unroll
        for (int i = 0; i < 4; ++i) {
            int ra = wr * 64 + i * 16 + (lane & 15);
            int pa = (lane >> 4) ^ ((ra >> 1) & 3);
            af[i] = *(const bf16x8*)&As[ra * 32 + pa * 8];
            int rb = wc * 64 + i * 16 + (lane & 15);
            int pb = (lane >> 4) ^ ((rb >> 1) & 3);
            bfr[i] = *(const bf16x8*)&Bs[rb * 32 + pb * 8];
        }
#pragma unroll
        for (int i = 0; i < 4; ++i)
#pragma unroll
            for (int n = 0; n < 4; ++n)
                acc[i][n] = __builtin_amdgcn_mfma_f32_16x16x32_bf16(af[i], bfr[n], acc[i][n], 0, 0, 0);
        __syncthreads();
    }

    int cn = n0 + wc * 64 + (lane & 15);
#pragma unroll
    for (int i = 0; i < 4; ++i) {
#pragma unroll
        for (int n = 0; n < 4; ++n) {
            int col = cn + n * 16;
#pragma unroll
            for (int q = 0; q < 4; ++q) {
                int r = wr * 64 + i * 16 + (lane >> 4) * 4 + q;
                if (r >= rows) continue;
                float v = acc[i][n][q];
                if (MODE == 2) {
                    Cb[(size_t)(rs + r) * N + col] = __float2bfloat16(v);
                } else {
                    int tok = permS[r];
                    Cf[(size_t)tok * N + col] = addsrc[(size_t)tok * N + col] + gate[tok] * v;
                }
            }
        }
    }
}

// ---------------- attention prep: split K -> [b,h,s,d] swz, V^T -> [b,h,d,s] swz ----------------
__global__ void k_prep(const float* __restrict__ qkv, short* __restrict__ KH, short* __restrict__ KL,
                       short* __restrict__ VH, short* __restrict__ VL) {
    __shared__ float tile[64][65];
    int b = blockIdx.z, h = blockIdx.y, s0 = blockIdx.x * 64;
    int t = threadIdx.x;
    int row = t >> 2, c0 = (t & 3) * 16;
    const float* kp = qkv + (size_t)(b * SS + s0 + row) * 3072 + 1024 + h * 64 + c0;
    const float* vp = kp + 1024;
    // K: split + slot-swizzled write
    {
        size_t krow = ((size_t)(b * HH + h) * SS + s0 + row) * 64;
        int key = (s0 + row) & 7;
#pragma unroll
        for (int g2 = 0; g2 < 2; ++g2) {
            s16x8 hv, lv;
#pragma unroll
            for (int j = 0; j < 8; ++j) {
                float v = kp[g2 * 8 + j];
                short hh = bfh(v);
                hv[j] = hh; lv[j] = bfh(v - bf2f(hh));
            }
            int p = ((c0 >> 3) + g2) ^ key;
            *(s16x8*)&KH[krow + p * 8] = hv;
            *(s16x8*)&KL[krow + p * 8] = lv;
        }
    }
    // V: stage f32, transpose, split + slot-swizzled write
#pragma unroll
    for (int j = 0; j < 16; ++j) tile[row][c0 + j] = vp[j];
    __syncthreads();
    {
        int d = t >> 2, sc = (t & 3) * 16;
        size_t vrow = ((size_t)(b * HH + h) * 64 + d) * SS + s0;
        int key = d & 7;
#pragma unroll
        for (int g2 = 0; g2 < 2; ++g2) {
            s16x8 hv, lv;
#pragma unroll
            for (int j = 0; j < 8; ++j) {
                float v = tile[sc + g2 * 8 + j][d];
                short hh = bfh(v);
                hv[j] = hh; lv[j] = bfh(v - bf2f(hh));
            }
            int p = ((sc >> 3) + g2) ^ key;
            *(s16x8*)&VH[vrow + p * 8] = hv;
            *(s16x8*)&VL[vrow + p * 8] = lv;
        }
    }
}

// ---------------- MFMA flash attention, split precision, dbuf 2-phase, 8 waves x 16 q-rows ----------------
#define LDP 72
__global__ __launch_bounds__(512, 1)
void k_attn_mfma(const float* __restrict__ qkv,
                 const short* __restrict__ KH, const short* __restrict__ KL,
                 const short* __restrict__ VH, const short* __restrict__ VL,
                 __hip_bfloat16* __restrict__ ohi, __hip_bfloat16* __restrict__ olo) {
    __shared__ __align__(16) short Ks[2][64 * 64], Kl2[2][64 * 64], Vs[2][64 * 64], Vl2[2][64 * 64];
    __shared__ __align__(16) short PhS[8][16 * LDP], PlS[8][16 * LDP];
    int b = blockIdx.z, h = blockIdx.y, q0 = blockIdx.x * 128;
    int t = threadIdx.x;
    int w = t >> 6, lane = t & 63;
    int g = lane >> 4, r16 = lane & 15;
    int srow = t >> 3, sslot = t & 7;

    const size_t kbase = ((size_t)(b * HH + h) * SS) * 64;
    const size_t vbase = ((size_t)(b * HH + h) * 64) * SS;

    // ---- Q fragments direct from f32 qkv, prescale 1/8, split in-reg
    bf16x8 qfh[2], qfl[2];
    {
        const float* qp = qkv + (size_t)(b * SS + q0 + w * 16 + r16) * 3072 + h * 64;
#pragma unroll
        for (int ks = 0; ks < 2; ++ks) {
            float vv[8];
            *(float4*)&vv[0] = *(const float4*)(qp + ks * 32 + g * 8);
            *(float4*)&vv[4] = *(const float4*)(qp + ks * 32 + g * 8 + 4);
#pragma unroll
            for (int j = 0; j < 8; ++j) {
                float sv = vv[j] * 0.125f;
                short hh = bfh(sv);
                qfh[ks][j] = hh;
                qfl[ks][j] = bfh(sv - bf2f(hh));
            }
        }
    }

    float mrun[4], lrun[4];
    f32x4 oacc[4] = {};
#pragma unroll
    for (int q = 0; q < 4; ++q) { mrun[q] = -1e30f; lrun[q] = 0.f; }

    // prologue: stage tile 0 into buf 0
    gload16(KH + kbase + (size_t)srow * 64 + sslot * 8, &Ks[0][w * 512]);
    gload16(KL + kbase + (size_t)srow * 64 + sslot * 8, &Kl2[0][w * 512]);
    gload16(VH + vbase + (size_t)srow * SS + sslot * 8, &Vs[0][w * 512]);
    gload16(VL + vbase + (size_t)srow * SS + sslot * 8, &Vl2[0][w * 512]);
    __syncthreads();

    int cur = 0;
    for (int k0 = 0; k0 < SS; k0 += 64) {
        // ---- prefetch next tile into alternate buffer (async, drained by end-of-iter sync)
        if (k0 + 64 < SS) {
            int kn = k0 + 64;
            gload16(KH + kbase + (size_t)(kn + srow) * 64 + sslot * 8, &Ks[cur ^ 1][w * 512]);
            gload16(KL + kbase + (size_t)(kn + srow) * 64 + sslot * 8, &Kl2[cur ^ 1][w * 512]);
            gload16(VH + vbase + (size_t)srow * SS + kn + sslot * 8,   &Vs[cur ^ 1][w * 512]);
            gload16(VL + vbase + (size_t)srow * SS + kn + sslot * 8,   &Vl2[cur ^ 1][w * 512]);
        }

        // ---- S = Q K^T (split, 3 MFMA per fragment)
        f32x4 accs[4] = {};
#pragma unroll
        for (int ks = 0; ks < 2; ++ks) {
            bf16x8 kfh[4], kfl[4];
#pragma unroll
            for (int n = 0; n < 4; ++n) {
                int rb = n * 16 + r16;
                int p = (ks * 4 + g) ^ (r16 & 7);
                kfh[n] = *(const bf16x8*)&Ks[cur][rb * 64 + p * 8];
                kfl[n] = *(const bf16x8*)&Kl2[cur][rb * 64 + p * 8];
            }
            __builtin_amdgcn_s_setprio(1);
#pragma unroll
            for (int n = 0; n < 4; ++n) {
                accs[n] = __builtin_amdgcn_mfma_f32_16x16x32_bf16(qfh[ks], kfh[n], accs[n], 0, 0, 0);
                accs[n] = __builtin_amdgcn_mfma_f32_16x16x32_bf16(qfh[ks], kfl[n], accs[n], 0, 0, 0);
                accs[n] = __builtin_amdgcn_mfma_f32_16x16x32_bf16(qfl[ks], kfh[n], accs[n], 0, 0, 0);
            }
            __builtin_amdgcn_s_setprio(0);
        }

        // ---- online softmax
        float mn[4], corr[4], psum[4];
#pragma unroll
        for (int q = 0; q < 4; ++q) {
            float m = fmaxf(fmaxf(accs[0][q], accs[1][q]), fmaxf(accs[2][q], accs[3][q]));
            m = fmaxf(m, __shfl_xor(m, 1));
            m = fmaxf(m, __shfl_xor(m, 2));
            m = fmaxf(m, __shfl_xor(m, 4));
            m = fmaxf(m, __shfl_xor(m, 8));
            mn[q] = fmaxf(mrun[q], m);
            corr[q] = expf(mrun[q] - mn[q]);
            mrun[q] = mn[q];
            psum[q] = 0.f;
        }
#pragma unroll
        for (int n = 0; n < 4; ++n)
#pragma unroll
            for (int q = 0; q < 4; ++q) {
                float p = expf(accs[n][q] - mn[q]);
                psum[q] += p;
                short ph = bfh(p);
                PhS[w][(g * 4 + q) * LDP + n * 16 + r16] = ph;
                PlS[w][(g * 4 + q) * LDP + n * 16 + r16] = bfh(p - bf2f(ph));
            }
#pragma unroll
        for (int q = 0; q < 4; ++q) {
            psum[q] += __shfl_xor(psum[q], 1);
            psum[q] += __shfl_xor(psum[q], 2);
            psum[q] += __shfl_xor(psum[q], 4);
            psum[q] += __shfl_xor(psum[q], 8);
            lrun[q] = lrun[q] * corr[q] + psum[q];
#pragma unroll
            for (int n = 0; n < 4; ++n) oacc[n][q] *= corr[q];
        }

        // ---- O += P V (split)
#pragma unroll
        for (int ks = 0; ks < 2; ++ks) {
            bf16x8 vfh[4], vfl[4];
#pragma unroll
            for (int n = 0; n < 4; ++n) {
                int rb = n * 16 + r16;
                int p = (ks * 4 + g) ^ (r16 & 7);
                vfh[n] = *(const bf16x8*)&Vs[cur][rb * 64 + p * 8];
                vfl[n] = *(const bf16x8*)&Vl2[cur][rb * 64 + p * 8];
            }
            bf16x8 pfh = *(const bf16x8*)&PhS[w][r16 * LDP + ks * 32 + g * 8];
            bf16x8 pfl = *(const bf16x8*)&PlS[w][r16 * LDP + ks * 32 + g * 8];
            __builtin_amdgcn_s_setprio(1);
#pragma unroll
            for (int n = 0; n < 4; ++n) {
                oacc[n] = __builtin_amdgcn_mfma_f32_16x16x32_bf16(pfh, vfh[n], oacc[n], 0, 0, 0);
                oacc[n] = __builtin_amdgcn_mfma_f32_16x16x32_bf16(pfh, vfl[n], oacc[n], 0, 0, 0);
                oacc[n] = __builtin_amdgcn_mfma_f32_16x16x32_bf16(pfl, vfh[n], oacc[n], 0, 0, 0);
            }
            __builtin_amdgcn_s_setprio(0);
        }
        __syncthreads();   // drains prefetch vmcnt + barriers buffer reuse
        cur ^= 1;
    }

    // ---- epilogue
    float invl[4];
#pragma unroll
    for (int q = 0; q < 4; ++q) invl[q] = 1.f / lrun[q];
#pragma unroll
    for (int n = 0; n < 4; ++n) {
        int col = h * 64 + n * 16 + r16;
#pragma unroll
        for (int q = 0; q < 4; ++q) {
            int rowg = b * SS + q0 + w * 16 + g * 4 + q;
            split_write(oacc[n][q] * invl[q], ohi, olo, (size_t)rowg * DD + col);
        }
    }
}

// ---------------- router (f32 h2 in), 4 tokens/block ----------------
__global__ void k_router(const float* __restrict__ h2, const float* __restrict__ wr,
                         float* __restrict__ logits_out, float* __restrict__ gate,
                         int* __restrict__ eid, int* __restrict__ counts) {
    int m = blockIdx.x * 4 + (threadIdx.x >> 6);
    int lane = threadIdx.x & 63;
    const float* hp = h2 + (size_t)m * DD;
    float acc[EE] = {};
    for (int k = lane; k < DD; k += 64) {
        float v = hp[k];
        const float* wp = wr + (size_t)k * EE;
#pragma unroll
        for (int n = 0; n < EE; ++n) acc[n] += v * wp[n];
    }
#pragma unroll
    for (int off = 32; off; off >>= 1)
#pragma unroll
        for (int n = 0; n < EE; ++n) acc[n] += __shfl_xor(acc[n], off);
    if (lane == 0) {
        float mx = acc[0]; int best = 0;
#pragma unroll
        for (int n = 1; n < EE; ++n) if (acc[n] > mx) { mx = acc[n]; best = n; }
        float den = 0.f;
#pragma unroll
        for (int n = 0; n < EE; ++n) den += expf(acc[n] - mx);
        gate[m] = 1.f / den;
        eid[m] = best;
        atomicAdd(&counts[best], 1);
#pragma unroll
        for (int n = 0; n < EE; ++n) logits_out[(size_t)m * EE + n] = acc[n];
    }
}

// ---------------- fused routing bookkeeping: offsets + tiles + scatter (1 block) ----------------
__global__ void k_offscatter(const int* __restrict__ counts,
                             int* __restrict__ te, int* __restrict__ ts, int* __restrict__ tr,
                             int* __restrict__ ntl, const int* __restrict__ eid,
                             int* __restrict__ fill, int* __restrict__ perm) {
    __shared__ int soffs[EE];
    int t = threadIdx.x;
    if (t == 0) {
        int off = 0, nt = 0;
        for (int e = 0; e < EE; ++e) {
            soffs[e] = off;
            int c = counts[e];
            for (int t0 = 0; t0 < c; t0 += 128) {
                te[nt] = e; ts[nt] = off + t0; tr[nt] = (c - t0 < 128) ? (c - t0) : 128; ++nt;
            }
            off += c;
        }
        *ntl = nt;
    }
    __syncthreads();
#pragma unroll
    for (int tok = t; tok < MM; tok += 1024) {
        int e = eid[tok];
        int pos = soffs[e] + atomicAdd(&fill[e], 1);
        perm[pos] = tok;
    }
}

// ---------------- launch ----------------
extern "C" void kernel_launch(void* const* d_in, const int* in_sizes, int n_in,
                              void* d_out, int out_size, void* d_ws, size_t ws_size,
                              hipStream_t stream) {
    const float* x     = (const float*)d_in[0];
    const float* ln1w  = (const float*)d_in[1];
    const float* ln1b  = (const float*)d_in[2];
    const float* ln2w  = (const float*)d_in[3];
    const float* ln2b  = (const float*)d_in[4];
    const float* w_qkv = (const float*)d_in[5];
    const float* b_qkv = (const float*)d_in[6];
    const float* w_out = (const float*)d_in[7];
    const float* b_out = (const float*)d_in[8];
    const float* w_rtr = (const float*)d_in[9];
    const float* wi    = (const float*)d_in[10];
    const float* wo    = (const float*)d_in[11];
    float* out = (float*)d_out;

    char* wsb = (char*)d_ws;
    __hip_bfloat16* wiT  = (__hip_bfloat16*)(wsb + OFF_WIT);
    __hip_bfloat16* woT  = (__hip_bfloat16*)(wsb + OFF_WOT);
    __hip_bfloat16* wqH  = (__hip_bfloat16*)(wsb + OFF_WQH);
    __hip_bfloat16* wqL  = (__hip_bfloat16*)(wsb + OFF_WQL);
    __hip_bfloat16* woH  = (__hip_bfloat16*)(wsb + OFF_WOH);
    __hip_bfloat16* woL  = (__hip_bfloat16*)(wsb + OFF_WOL);
    __hip_bfloat16* h1H  = (__hip_bfloat16*)(wsb + OFF_H1H);
    __hip_bfloat16* h1L  = (__hip_bfloat16*)(wsb + OFF_H1L);
    float*          qkvF = (float*)(wsb + OFF_QKV);
    __hip_bfloat16* hidB = (__hip_bfloat16*)(wsb + OFF_QKV);   // reuse after attn
    float*          h2F  = (float*)(wsb + OFF_H2F);
    __hip_bfloat16* oH   = (__hip_bfloat16*)(wsb + OFF_OH);
    __hip_bfloat16* oL   = (__hip_bfloat16*)(wsb + OFF_OL);
    float*          x2F  = (float*)(wsb + OFF_X2);
    __hip_bfloat16* h2B  = (__hip_bfloat16*)(wsb + OFF_H2B);
    short* KSH = (short*)(wsb + OFF_KSH);
    short* KSL = (short*)(wsb + OFF_KSL);
    short* VTH = (short*)(wsb + OFF_VTH);
    short* VTL = (short*)(wsb + OFF_VTL);
    float* gate = (float*)(wsb + OFF_GATE);
    int* eid    = (int*)(wsb + OFF_EID);
    int* perm   = (int*)(wsb + OFF_PERM);
    int* counts = (int*)(wsb + OFF_CNT);
    int* fill   = (int*)(wsb + OFF_FILL);
    int* ntl    = (int*)(wsb + OFF_NT);
    int* te     = (int*)(wsb + OFF_TE);
    int* tsx    = (int*)(wsb + OFF_TS);
    int* trx    = (int*)(wsb + OFF_TR);

    // 0. weight conversion
    k_cvt_split<<<3072, 256, 0, stream>>>(w_qkv, wqH, wqL, 3072 * 1024 / 4);
    k_cvt_split<<<1024, 256, 0, stream>>>(w_out, woH, woL, 1024 * 1024 / 4);
    k_tcvt<<<dim3(4096 / 32, 1024 / 32, EE), 256, 0, stream>>>(wi, wiT, 1024, 4096);
    k_tcvt<<<dim3(1024 / 32, 2048 / 32, EE), 256, 0, stream>>>(wo, woT, 2048, 1024);

    // 1. LN1 + RoPE -> h1 hi/lo
    k_ln<0><<<MM, 256, 0, stream>>>(x, ln1w, ln1b, h1H, h1L, nullptr, nullptr);
    // 2. qkv = h1 @ w_qkv^T + b_qkv (split precision, f32 out)
    k_mfma_split<0><<<dim3(3072 / 128, MM / 128), 256, 0, stream>>>(
        h1H, h1L, wqH, wqL, b_qkv, nullptr, qkvF, MM, 3072, DD);
    // 2.5 prep: split K + transposed V (overwrites dead wq/h1 regions)
    k_prep<<<dim3(SS / 64, HH, BB), 256, 0, stream>>>(qkvF, KSH, KSL, VTH, VTL);
    // 3. attention (split-precision MFMA, double-buffered, hi/lo bf16 out)
    k_attn_mfma<<<dim3(SS / 128, HH, BB), 512, 0, stream>>>(qkvF, KSH, KSL, VTH, VTL, oH, oL);
    // 4. x2 = x + o @ w_out^T + b_out (split precision, f32)
    k_mfma_split<1><<<dim3(DD / 128, MM / 128), 256, 0, stream>>>(
        oH, oL, woH, woL, b_out, x, x2F, MM, DD, DD);
    // 5. LN2 -> h2 (bf16 + f32); zeroes routing counters (17 ints)
    k_ln<1><<<MM, 256, 0, stream>>>(x2F, ln2w, ln2b, h2B, nullptr, h2F, counts);
    // 6. router (f32 h2 -> exact logits/argmax)
    k_router<<<MM / 4, 256, 0, stream>>>(h2F, w_rtr, out + (size_t)MM * DD, gate, eid, counts);
    // 7. fused offsets + tiles + scatter
    k_offscatter<<<1, 1024, 0, stream>>>(counts, te, tsx, trx, ntl, eid, fill, perm);
    // 8. hid = h2[perm] @ wiT[e]^T (bf16 out)
    k_mfma<2><<<dim3(FF / 128, MAX_TILES), 256, 0, stream>>>(
        h2B, wiT, nullptr, nullptr, hidB, FF, DD,
        perm, te, tsx, trx, ntl, nullptr);
    // 9. out = x2 + gate * (silu(a)*g @ woT[e]^T), silu fused in staging
    k_mfma<3><<<dim3(DD / 128, MAX_TILES), 256, 0, stream>>>(
        hidB, woT, x2F, out, nullptr, DD, FF / 2,
        perm, te, tsx, trx, ntl, gate);
}

// Round 7
// 387.127 us; speedup vs baseline: 1.2086x; 1.2086x over previous
//
#include <hip/hip_runtime.h>
#include <hip/hip_bf16.h>
#include <math.h>

// Problem constants
#define BB 2
#define SS 1024
#define DD 1024
#define FF 4096
#define HH 16
#define EE 8
#define MM (BB*SS)          // 2048 tokens
#define MAX_TILES 24        // sum_e ceil(cnt_e/128) <= 2048/128 + 8

typedef __attribute__((ext_vector_type(8))) short bf16x8;
typedef __attribute__((ext_vector_type(8))) short s16x8;
typedef __attribute__((ext_vector_type(4))) short s16x4;
typedef __attribute__((ext_vector_type(4))) float f32x4;

// ---------------- workspace layout (bytes) ----------------
#define OFF_WIT  ((size_t)0)            // wi^T bf16: 8*4096*1024*2 = 67108864
#define OFF_WOT  ((size_t)67108864)     // wo^T bf16: 33554432
#define OFF_WQH  ((size_t)100663296)    // w_qkv hi bf16: 6291456   (later: K split hi/lo, 8MB)
#define OFF_WQL  ((size_t)106954752)    // w_qkv lo bf16: 6291456
#define OFF_WOH  ((size_t)113246208)    // w_out hi bf16: 2097152
#define OFF_WOL  ((size_t)115343360)    // w_out lo bf16: 2097152
#define OFF_H1H  ((size_t)117440512)    // h1 hi bf16: 4194304      (later: VT hi)
#define OFF_H1L  ((size_t)121634816)    // h1 lo bf16: 4194304      (later: VT lo)
#define OFF_QKV  ((size_t)125829120)    // qkv f32: 25165824
#define OFF_H2F  ((size_t)142606336)    // h2 f32: 8388608
#define OFF_OH   ((size_t)150994944)    // attn o hi bf16: 4194304
#define OFF_OL   ((size_t)155189248)    // attn o lo bf16: 4194304
#define OFF_X2   ((size_t)159383552)    // x2 f32: 8388608
#define OFF_H2B  ((size_t)167772160)    // h2 bf16: 4194304
#define OFF_ACT  ((size_t)171966464)    // act bf16 (2048+128 rows)*2048*2 = 8912896
#define OFF_GATE ((size_t)180879360)
#define OFF_EID  ((size_t)180887552)
#define OFF_PERM ((size_t)180895744)
#define OFF_CNT  ((size_t)180903936)    // 17 ints zeroed by k_ln<1>
#define OFF_FILL ((size_t)180903968)
#define OFF_NT   ((size_t)180904000)
#define OFF_TE   ((size_t)180904192)
#define OFF_TS   ((size_t)180904320)
#define OFF_TR   ((size_t)180904448)
// attention K/V split buffers (reuse dead regions)
#define OFF_KSH  OFF_WQH                         // 4MB
#define OFF_KSL  (OFF_WQH + 4194304)             // 4MB (spills into wqL region - dead)
#define OFF_VTH  OFF_H1H                         // 4MB
#define OFF_VTL  OFF_H1L                         // 4MB

// ---------------- async global->LDS (16B per lane) ----------------
__device__ __forceinline__ void gload16(const void* g, void* l) {
    __builtin_amdgcn_global_load_lds(
        (const __attribute__((address_space(1))) unsigned int*)g,
        (__attribute__((address_space(3))) unsigned int*)l, 16, 0, 0);
}

__device__ __forceinline__ short bfh(float v) {
    __hip_bfloat16 h = __float2bfloat16(v);
    return *(short*)&h;
}
__device__ __forceinline__ float bf2f(short s) {
    __hip_bfloat16 h = *(__hip_bfloat16*)&s;
    return __bfloat162float(h);
}

__device__ __forceinline__ void split_write(float v, __hip_bfloat16* hp, __hip_bfloat16* lp, size_t idx) {
    __hip_bfloat16 h = __float2bfloat16(v);
    hp[idx] = h;
    lp[idx] = __float2bfloat16(v - __bfloat162float(h));
}

// ---------------- f32 -> bf16 hi/lo split convert, two tensors in one launch ----------------
__global__ void k_cvt2(const float* __restrict__ in1, __hip_bfloat16* __restrict__ hi1,
                       __hip_bfloat16* __restrict__ lo1, int n4_1,
                       const float* __restrict__ in2, __hip_bfloat16* __restrict__ hi2,
                       __hip_bfloat16* __restrict__ lo2, int n4_2) {
    int i = blockIdx.x * 256 + threadIdx.x;
    const float* in; __hip_bfloat16 *hi, *lo; int idx;
    if (i < n4_1) { in = in1; hi = hi1; lo = lo1; idx = i; }
    else { idx = i - n4_1; if (idx >= n4_2) return; in = in2; hi = hi2; lo = lo2; }
    float4 v = ((const float4*)in)[idx];
    split_write(v.x, hi, lo, (size_t)idx * 4 + 0);
    split_write(v.y, hi, lo, (size_t)idx * 4 + 1);
    split_write(v.z, hi, lo, (size_t)idx * 4 + 2);
    split_write(v.w, hi, lo, (size_t)idx * 4 + 3);
}

// ---------------- batched transpose-convert: in (R,C) f32 -> out (C,R) bf16 ----------------
__global__ void k_tcvt(const float* __restrict__ in, __hip_bfloat16* __restrict__ out, int R, int C) {
    __shared__ float tile[32][33];
    int c0 = blockIdx.x * 32, r0 = blockIdx.y * 32;
    size_t eoff = (size_t)blockIdx.z * R * C;
    in += eoff; out += eoff;
    int t = threadIdx.x;
    int i = t >> 3, j0 = (t & 7) * 4;
    float4 v = *(const float4*)&in[(size_t)(r0 + i) * C + c0 + j0];
    tile[i][j0 + 0] = v.x; tile[i][j0 + 1] = v.y; tile[i][j0 + 2] = v.z; tile[i][j0 + 3] = v.w;
    __syncthreads();
#pragma unroll
    for (int q = 0; q < 4; ++q)
        out[(size_t)(c0 + i) * R + r0 + j0 + q] = __float2bfloat16(tile[j0 + q][i]);
}

// ---------------- LayerNorm: MODE 0 = +RoPE, hi/lo out; MODE 1 = plain, bf16+f32 out ----------------
template<int MODE>
__global__ void k_ln(const float* __restrict__ x, const float* __restrict__ w,
                     const float* __restrict__ b, __hip_bfloat16* __restrict__ hi,
                     __hip_bfloat16* __restrict__ lo, float* __restrict__ f32o,
                     int* __restrict__ zero17) {
    int m = blockIdx.x;
    int s = m & (SS - 1);
    __shared__ float row[DD];
    __shared__ float red[8];
    int t = threadIdx.x;
    if (MODE == 1 && m == 0 && t < 17) zero17[t] = 0;   // routing counters
    const float* xp = x + (size_t)m * DD;
    float sum = 0.f, sumsq = 0.f;
#pragma unroll
    for (int l = 0; l < 4; ++l) {
        int i = t + l * 256;
        float v = xp[i];
        row[i] = v;
        sum += v; sumsq += v * v;
    }
#pragma unroll
    for (int off = 32; off; off >>= 1) {
        sum   += __shfl_xor(sum, off);
        sumsq += __shfl_xor(sumsq, off);
    }
    int wid = t >> 6, lane = t & 63;
    if (lane == 0) { red[wid] = sum; red[4 + wid] = sumsq; }
    __syncthreads();
    sum   = red[0] + red[1] + red[2] + red[3];
    sumsq = red[4] + red[5] + red[6] + red[7];
    float mean = sum * (1.f / DD);
    float var  = sumsq * (1.f / DD) - mean * mean;
    float rstd = rsqrtf(var + 1e-5f);
    size_t base = (size_t)m * DD;
    if (MODE == 0) {
        const float kln = logf(10000.f) / 512.f;
#pragma unroll
        for (int l = 0; l < 2; ++l) {
            int i = t + l * 256;   // 0..511
            float n1 = (row[i]       - mean) * rstd * w[i]       + b[i];
            float n2 = (row[i + 512] - mean) * rstd * w[i + 512] + b[i + 512];
            float inv = expf(-(float)i * kln);
            float ang = (float)s * inv;
            float c = cosf(ang), sn = sinf(ang);
            split_write(n1 * c - n2 * sn,  hi, lo, base + i);
            split_write(n1 * sn + n2 * c, hi, lo, base + i + 512);
        }
    } else {
#pragma unroll
        for (int l = 0; l < 4; ++l) {
            int i = t + l * 256;
            float v = (row[i] - mean) * rstd * w[i] + b[i];
            hi[base + i] = __float2bfloat16(v);
            f32o[base + i] = v;
        }
    }
}

// ---------------- split-precision MFMA GEMM: C = A @ Bt^T + bias (+addsrc) ----------------
template<int MODE>
__global__ void k_mfma_split(const __hip_bfloat16* __restrict__ Ah, const __hip_bfloat16* __restrict__ Al,
                             const __hip_bfloat16* __restrict__ Bh, const __hip_bfloat16* __restrict__ Bl,
                             const float* __restrict__ bias, const float* __restrict__ addsrc,
                             float* __restrict__ Cf, int M, int N, int K) {
    __shared__ __align__(16) short AsH[128 * 32];
    __shared__ __align__(16) short AsL[128 * 32];
    __shared__ __align__(16) short BsH[128 * 32];
    __shared__ __align__(16) short BsL[128 * 32];
    int m0 = blockIdx.y * 128, n0 = blockIdx.x * 128;
    const int t = threadIdx.x;
    const int w = t >> 6, lane = t & 63;
    const int wr = w >> 1, wc = w & 1;
    const int sid = w * 64 + lane;

    f32x4 acc[4][4] = {};

    for (int k0 = 0; k0 < K; k0 += 32) {
#pragma unroll
        for (int j = 0; j < 2; ++j) {
            int id = j * 256 + sid;
            int rrow = id >> 2, sl = id & 3;
            int slog = sl ^ ((rrow >> 1) & 3);
            size_t lbase = (size_t)(j * 256 + w * 64) * 8;
            size_t gaoff = (size_t)(m0 + rrow) * K + k0 + slog * 8;
            gload16(Ah + gaoff, &AsH[lbase]);
            gload16(Al + gaoff, &AsL[lbase]);
            size_t gboff = (size_t)(n0 + rrow) * K + k0 + slog * 8;
            gload16(Bh + gboff, &BsH[lbase]);
            gload16(Bl + gboff, &BsL[lbase]);
        }
        __syncthreads();
        bf16x8 ah[4], al[4], bh[4], bl[4];
#pragma unroll
        for (int i = 0; i < 4; ++i) {
            int ra = wr * 64 + i * 16 + (lane & 15);
            int pa = (lane >> 4) ^ ((ra >> 1) & 3);
            ah[i] = *(const bf16x8*)&AsH[ra * 32 + pa * 8];
            al[i] = *(const bf16x8*)&AsL[ra * 32 + pa * 8];
            int rb = wc * 64 + i * 16 + (lane & 15);
            int pb = (lane >> 4) ^ ((rb >> 1) & 3);
            bh[i] = *(const bf16x8*)&BsH[rb * 32 + pb * 8];
            bl[i] = *(const bf16x8*)&BsL[rb * 32 + pb * 8];
        }
#pragma unroll
        for (int i = 0; i < 4; ++i)
#pragma unroll
            for (int n = 0; n < 4; ++n) {
                acc[i][n] = __builtin_amdgcn_mfma_f32_16x16x32_bf16(ah[i], bh[n], acc[i][n], 0, 0, 0);
                acc[i][n] = __builtin_amdgcn_mfma_f32_16x16x32_bf16(ah[i], bl[n], acc[i][n], 0, 0, 0);
                acc[i][n] = __builtin_amdgcn_mfma_f32_16x16x32_bf16(al[i], bh[n], acc[i][n], 0, 0, 0);
            }
        __syncthreads();
    }

    int cn = n0 + wc * 64 + (lane & 15);
#pragma unroll
    for (int i = 0; i < 4; ++i) {
#pragma unroll
        for (int n = 0; n < 4; ++n) {
            int col = cn + n * 16;
#pragma unroll
            for (int q = 0; q < 4; ++q) {
                int r = wr * 64 + i * 16 + (lane >> 4) * 4 + q;
                float v = acc[i][n][q] + bias[col];
                if (MODE == 1) v += addsrc[(size_t)(m0 + r) * N + col];
                Cf[(size_t)(m0 + r) * N + col] = v;
            }
        }
    }
}

// ---------------- MoE up-proj with interleaved a/g columns + fused silu epilogue ----------------
// Block computes act cols [c0, c0+64) for one token-tile. B-panel rows interleave
// wiT a-rows (c0+..) and g-rows (2048+c0+..) at 16-row granularity, so each thread's
// acc fragment pair (n even, n odd) is (a, g) of the SAME column -> silu in epilogue.
__global__ void k_moe_up(const __hip_bfloat16* __restrict__ A,     // h2 bf16 (M,1024)
                         const __hip_bfloat16* __restrict__ Bt,    // wiT (E,4096,1024)
                         __hip_bfloat16* __restrict__ act,         // (perm rows, 2048)
                         const int* __restrict__ perm,
                         const int* __restrict__ te, const int* __restrict__ ts,
                         const int* __restrict__ tr, const int* __restrict__ ntl) {
    __shared__ __align__(16) short As[128 * 32];
    __shared__ __align__(16) short Bs[128 * 32];
    __shared__ int permS[128];
    int tile = blockIdx.y;
    if (tile >= *ntl) return;
    int e = te[tile], rs = ts[tile], rows = tr[tile];
    if (threadIdx.x < 128) {
        int r = threadIdx.x;
        permS[r] = (r < rows) ? perm[rs + r] : 0;
    }
    __syncthreads();
    int c0 = blockIdx.x * 64;
    const int t = threadIdx.x;
    const int w = t >> 6, lane = t & 63;
    const int wr = w >> 1, wc = w & 1;
    const int sid = w * 64 + lane;
    const int g = lane >> 4, r16 = lane & 15;

    const __hip_bfloat16* Bp = Bt + (size_t)e * FF * DD;

    f32x4 acc[4][4] = {};

    for (int k0 = 0; k0 < DD; k0 += 32) {
#pragma unroll
        for (int j = 0; j < 2; ++j) {
            int id = j * 256 + sid;
            int rrow = id >> 2, sl = id & 3;
            int slog = sl ^ ((rrow >> 1) & 3);
            size_t lbase = (size_t)(j * 256 + w * 64) * 8;
            gload16(A + (size_t)permS[rrow] * DD + k0 + slog * 8, &As[lbase]);
            int q = rrow >> 4, rr = rrow & 15;
            int wrow = c0 + (q >> 2) * 32 + ((q & 3) >> 1) * 16 + rr + (q & 1) * 2048;
            gload16(Bp + (size_t)wrow * DD + k0 + slog * 8, &Bs[lbase]);
        }
        __syncthreads();
        bf16x8 af[4], bfr[4];
#pragma unroll
        for (int i = 0; i < 4; ++i) {
            int ra = wr * 64 + i * 16 + r16;
            int pa = g ^ ((ra >> 1) & 3);
            af[i] = *(const bf16x8*)&As[ra * 32 + pa * 8];
            int rb = wc * 64 + i * 16 + r16;
            int pb = g ^ ((rb >> 1) & 3);
            bfr[i] = *(const bf16x8*)&Bs[rb * 32 + pb * 8];
        }
#pragma unroll
        for (int i = 0; i < 4; ++i)
#pragma unroll
            for (int n = 0; n < 4; ++n)
                acc[i][n] = __builtin_amdgcn_mfma_f32_16x16x32_bf16(af[i], bfr[n], acc[i][n], 0, 0, 0);
        __syncthreads();
    }

    // epilogue: act[r, col] = silu(a)*g ; (n=2p, n=2p+1) pair same col
#pragma unroll
    for (int i = 0; i < 4; ++i) {
#pragma unroll
        for (int p2 = 0; p2 < 2; ++p2) {
            int col = c0 + wc * 32 + p2 * 16 + r16;
#pragma unroll
            for (int q = 0; q < 4; ++q) {
                int r = wr * 64 + i * 16 + g * 4 + q;
                if (r < rows) {
                    float a  = acc[i][2 * p2][q];
                    float gv = acc[i][2 * p2 + 1][q];
                    act[(size_t)(rs + r) * 2048 + col] =
                        __float2bfloat16((a / (1.f + expf(-a))) * gv);
                }
            }
        }
    }
}

// ---------------- MoE down-proj: out = x2 + gate * (act @ woT[e]^T) ----------------
__global__ void k_moe_dn(const __hip_bfloat16* __restrict__ A,     // act (perm rows, 2048)
                         const __hip_bfloat16* __restrict__ Bt,    // woT (E,1024,2048)
                         const float* __restrict__ addsrc, float* __restrict__ Cf,
                         const int* __restrict__ perm,
                         const int* __restrict__ te, const int* __restrict__ ts,
                         const int* __restrict__ tr, const int* __restrict__ ntl,
                         const float* __restrict__ gate) {
    __shared__ __align__(16) short As[128 * 32];
    __shared__ __align__(16) short Bs[128 * 32];
    __shared__ int permS[128];
    int tile = blockIdx.y;
    if (tile >= *ntl) return;
    int e = te[tile], rs = ts[tile], rows = tr[tile];
    if (threadIdx.x < 128) {
        int r = threadIdx.x;
        permS[r] = (r < rows) ? perm[rs + r] : 0;
    }
    __syncthreads();
    int n0 = blockIdx.x * 128;
    const int t = threadIdx.x;
    const int w = t >> 6, lane = t & 63;
    const int wr = w >> 1, wc = w & 1;
    const int sid = w * 64 + lane;
    const int K = FF / 2;

    const __hip_bfloat16* Bp = Bt + (size_t)e * DD * (FF / 2);

    f32x4 acc[4][4] = {};

    for (int k0 = 0; k0 < K; k0 += 32) {
#pragma unroll
        for (int j = 0; j < 2; ++j) {
            int id = j * 256 + sid;
            int rrow = id >> 2, sl = id & 3;
            int slog = sl ^ ((rrow >> 1) & 3);
            size_t lbase = (size_t)(j * 256 + w * 64) * 8;
            gload16(A + (size_t)(rs + rrow) * K + k0 + slog * 8, &As[lbase]);
            gload16(Bp + (size_t)(n0 + rrow) * K + k0 + slog * 8, &Bs[lbase]);
        }
        __syncthreads();
        bf16x8 af[4], bfr[4];
#pragma unroll
        for (int i = 0; i < 4; ++i) {
            int ra = wr * 64 + i * 16 + (lane & 15);
            int pa = (lane >> 4) ^ ((ra >> 1) & 3);
            af[i] = *(const bf16x8*)&As[ra * 32 + pa * 8];
            int rb = wc * 64 + i * 16 + (lane & 15);
            int pb = (lane >> 4) ^ ((rb >> 1) & 3);
            bfr[i] = *(const bf16x8*)&Bs[rb * 32 + pb * 8];
        }
#pragma unroll
        for (int i = 0; i < 4; ++i)
#pragma unroll
            for (int n = 0; n < 4; ++n)
                acc[i][n] = __builtin_amdgcn_mfma_f32_16x16x32_bf16(af[i], bfr[n], acc[i][n], 0, 0, 0);
        __syncthreads();
    }

    int cn = n0 + wc * 64 + (lane & 15);
#pragma unroll
    for (int i = 0; i < 4; ++i) {
#pragma unroll
        for (int n = 0; n < 4; ++n) {
            int col = cn + n * 16;
#pragma unroll
            for (int q = 0; q < 4; ++q) {
                int r = wr * 64 + i * 16 + (lane >> 4) * 4 + q;
                if (r >= rows) continue;
                int tok = permS[r];
                Cf[(size_t)tok * DD + col] = addsrc[(size_t)tok * DD + col] + gate[tok] * acc[i][n][q];
            }
        }
    }
}

// ---------------- attention prep: split K -> [b,h,s,d] swz, V^T -> [b,h,d,s] swz ----------------
__global__ void k_prep(const float* __restrict__ qkv, short* __restrict__ KH, short* __restrict__ KL,
                       short* __restrict__ VH, short* __restrict__ VL) {
    __shared__ float tile[64][65];
    int b = blockIdx.z, h = blockIdx.y, s0 = blockIdx.x * 64;
    int t = threadIdx.x;
    int row = t >> 2, c0 = (t & 3) * 16;
    const float* kp = qkv + (size_t)(b * SS + s0 + row) * 3072 + 1024 + h * 64 + c0;
    const float* vp = kp + 1024;
    // K: split + slot-swizzled write
    {
        size_t krow = ((size_t)(b * HH + h) * SS + s0 + row) * 64;
        int key = (s0 + row) & 7;
#pragma unroll
        for (int g2 = 0; g2 < 2; ++g2) {
            s16x8 hv, lv;
#pragma unroll
            for (int j = 0; j < 8; ++j) {
                float v = kp[g2 * 8 + j];
                short hh = bfh(v);
                hv[j] = hh; lv[j] = bfh(v - bf2f(hh));
            }
            int p = ((c0 >> 3) + g2) ^ key;
            *(s16x8*)&KH[krow + p * 8] = hv;
            *(s16x8*)&KL[krow + p * 8] = lv;
        }
    }
    // V: stage f32, transpose, split + slot-swizzled write
#pragma unroll
    for (int j = 0; j < 16; ++j) tile[row][c0 + j] = vp[j];
    __syncthreads();
    {
        int d = t >> 2, sc = (t & 3) * 16;
        size_t vrow = ((size_t)(b * HH + h) * 64 + d) * SS + s0;
        int key = d & 7;
#pragma unroll
        for (int g2 = 0; g2 < 2; ++g2) {
            s16x8 hv, lv;
#pragma unroll
            for (int j = 0; j < 8; ++j) {
                float v = tile[sc + g2 * 8 + j][d];
                short hh = bfh(v);
                hv[j] = hh; lv[j] = bfh(v - bf2f(hh));
            }
            int p = ((sc >> 3) + g2) ^ key;
            *(s16x8*)&VH[vrow + p * 8] = hv;
            *(s16x8*)&VL[vrow + p * 8] = lv;
        }
    }
}

// ---------------- MFMA flash attention, split precision, dbuf 2-phase, 8 waves x 16 q-rows ----------------
#define LDP 72
__global__ __launch_bounds__(512, 1)
void k_attn_mfma(const float* __restrict__ qkv,
                 const short* __restrict__ KH, const short* __restrict__ KL,
                 const short* __restrict__ VH, const short* __restrict__ VL,
                 __hip_bfloat16* __restrict__ ohi, __hip_bfloat16* __restrict__ olo) {
    __shared__ __align__(16) short Ks[2][64 * 64], Kl2[2][64 * 64], Vs[2][64 * 64], Vl2[2][64 * 64];
    __shared__ __align__(16) short PhS[8][16 * LDP], PlS[8][16 * LDP];
    int b = blockIdx.z, h = blockIdx.y, q0 = blockIdx.x * 128;
    int t = threadIdx.x;
    int w = t >> 6, lane = t & 63;
    int g = lane >> 4, r16 = lane & 15;
    int srow = t >> 3, sslot = t & 7;

    const size_t kbase = ((size_t)(b * HH + h) * SS) * 64;
    const size_t vbase = ((size_t)(b * HH + h) * 64) * SS;

    // ---- Q fragments direct from f32 qkv, prescale 1/8, split in-reg
    bf16x8 qfh[2], qfl[2];
    {
        const float* qp = qkv + (size_t)(b * SS + q0 + w * 16 + r16) * 3072 + h * 64;
#pragma unroll
        for (int ks = 0; ks < 2; ++ks) {
            float vv[8];
            *(float4*)&vv[0] = *(const float4*)(qp + ks * 32 + g * 8);
            *(float4*)&vv[4] = *(const float4*)(qp + ks * 32 + g * 8 + 4);
#pragma unroll
            for (int j = 0; j < 8; ++j) {
                float sv = vv[j] * 0.125f;
                short hh = bfh(sv);
                qfh[ks][j] = hh;
                qfl[ks][j] = bfh(sv - bf2f(hh));
            }
        }
    }

    float mrun[4], lrun[4];
    f32x4 oacc[4] = {};
#pragma unroll
    for (int q = 0; q < 4; ++q) { mrun[q] = -1e30f; lrun[q] = 0.f; }

    // prologue: stage tile 0 into buf 0
    gload16(KH + kbase + (size_t)srow * 64 + sslot * 8, &Ks[0][w * 512]);
    gload16(KL + kbase + (size_t)srow * 64 + sslot * 8, &Kl2[0][w * 512]);
    gload16(VH + vbase + (size_t)srow * SS + sslot * 8, &Vs[0][w * 512]);
    gload16(VL + vbase + (size_t)srow * SS + sslot * 8, &Vl2[0][w * 512]);
    __syncthreads();

    int cur = 0;
    for (int k0 = 0; k0 < SS; k0 += 64) {
        // ---- prefetch next tile into alternate buffer (async, drained by end-of-iter sync)
        if (k0 + 64 < SS) {
            int kn = k0 + 64;
            gload16(KH + kbase + (size_t)(kn + srow) * 64 + sslot * 8, &Ks[cur ^ 1][w * 512]);
            gload16(KL + kbase + (size_t)(kn + srow) * 64 + sslot * 8, &Kl2[cur ^ 1][w * 512]);
            gload16(VH + vbase + (size_t)srow * SS + kn + sslot * 8,   &Vs[cur ^ 1][w * 512]);
            gload16(VL + vbase + (size_t)srow * SS + kn + sslot * 8,   &Vl2[cur ^ 1][w * 512]);
        }

        // ---- S = Q K^T (split, 3 MFMA per fragment)
        f32x4 accs[4] = {};
#pragma unroll
        for (int ks = 0; ks < 2; ++ks) {
            bf16x8 kfh[4], kfl[4];
#pragma unroll
            for (int n = 0; n < 4; ++n) {
                int rb = n * 16 + r16;
                int p = (ks * 4 + g) ^ (r16 & 7);
                kfh[n] = *(const bf16x8*)&Ks[cur][rb * 64 + p * 8];
                kfl[n] = *(const bf16x8*)&Kl2[cur][rb * 64 + p * 8];
            }
            __builtin_amdgcn_s_setprio(1);
#pragma unroll
            for (int n = 0; n < 4; ++n) {
                accs[n] = __builtin_amdgcn_mfma_f32_16x16x32_bf16(qfh[ks], kfh[n], accs[n], 0, 0, 0);
                accs[n] = __builtin_amdgcn_mfma_f32_16x16x32_bf16(qfh[ks], kfl[n], accs[n], 0, 0, 0);
                accs[n] = __builtin_amdgcn_mfma_f32_16x16x32_bf16(qfl[ks], kfh[n], accs[n], 0, 0, 0);
            }
            __builtin_amdgcn_s_setprio(0);
        }

        // ---- online softmax
        float mn[4], corr[4], psum[4];
#pragma unroll
        for (int q = 0; q < 4; ++q) {
            float m = fmaxf(fmaxf(accs[0][q], accs[1][q]), fmaxf(accs[2][q], accs[3][q]));
            m = fmaxf(m, __shfl_xor(m, 1));
            m = fmaxf(m, __shfl_xor(m, 2));
            m = fmaxf(m, __shfl_xor(m, 4));
            m = fmaxf(m, __shfl_xor(m, 8));
            mn[q] = fmaxf(mrun[q], m);
            corr[q] = expf(mrun[q] - mn[q]);
            mrun[q] = mn[q];
            psum[q] = 0.f;
        }
#pragma unroll
        for (int n = 0; n < 4; ++n)
#pragma unroll
            for (int q = 0; q < 4; ++q) {
                float p = expf(accs[n][q] - mn[q]);
                psum[q] += p;
                short ph = bfh(p);
                PhS[w][(g * 4 + q) * LDP + n * 16 + r16] = ph;
                PlS[w][(g * 4 + q) * LDP + n * 16 + r16] = bfh(p - bf2f(ph));
            }
#pragma unroll
        for (int q = 0; q < 4; ++q) {
            psum[q] += __shfl_xor(psum[q], 1);
            psum[q] += __shfl_xor(psum[q], 2);
            psum[q] += __shfl_xor(psum[q], 4);
            psum[q] += __shfl_xor(psum[q], 8);
            lrun[q] = lrun[q] * corr[q] + psum[q];
#pragma unroll
            for (int n = 0; n < 4; ++n) oacc[n][q] *= corr[q];
        }

        // ---- O += P V (split)
#pragma unroll
        for (int ks = 0; ks < 2; ++ks) {
            bf16x8 vfh[4], vfl[4];
#pragma unroll
            for (int n = 0; n < 4; ++n) {
                int rb = n * 16 + r16;
                int p = (ks * 4 + g) ^ (r16 & 7);
                vfh[n] = *(const bf16x8*)&Vs[cur][rb * 64 + p * 8];
                vfl[n] = *(const bf16x8*)&Vl2[cur][rb * 64 + p * 8];
            }
            bf16x8 pfh = *(const bf16x8*)&PhS[w][r16 * LDP + ks * 32 + g * 8];
            bf16x8 pfl = *(const bf16x8*)&PlS[w][r16 * LDP + ks * 32 + g * 8];
            __builtin_amdgcn_s_setprio(1);
#pragma unroll
            for (int n = 0; n < 4; ++n) {
                oacc[n] = __builtin_amdgcn_mfma_f32_16x16x32_bf16(pfh, vfh[n], oacc[n], 0, 0, 0);
                oacc[n] = __builtin_amdgcn_mfma_f32_16x16x32_bf16(pfh, vfl[n], oacc[n], 0, 0, 0);
                oacc[n] = __builtin_amdgcn_mfma_f32_16x16x32_bf16(pfl, vfh[n], oacc[n], 0, 0, 0);
            }
            __builtin_amdgcn_s_setprio(0);
        }
        __syncthreads();   // drains prefetch vmcnt + barriers buffer reuse
        cur ^= 1;
    }

    // ---- epilogue
    float invl[4];
#pragma unroll
    for (int q = 0; q < 4; ++q) invl[q] = 1.f / lrun[q];
#pragma unroll
    for (int n = 0; n < 4; ++n) {
        int col = h * 64 + n * 16 + r16;
#pragma unroll
        for (int q = 0; q < 4; ++q) {
            int rowg = b * SS + q0 + w * 16 + g * 4 + q;
            split_write(oacc[n][q] * invl[q], ohi, olo, (size_t)rowg * DD + col);
        }
    }
}

// ---------------- router (f32 h2 in), 4 tokens/block ----------------
__global__ void k_router(const float* __restrict__ h2, const float* __restrict__ wr,
                         float* __restrict__ logits_out, float* __restrict__ gate,
                         int* __restrict__ eid, int* __restrict__ counts) {
    int m = blockIdx.x * 4 + (threadIdx.x >> 6);
    int lane = threadIdx.x & 63;
    const float* hp = h2 + (size_t)m * DD;
    float acc[EE] = {};
    for (int k = lane; k < DD; k += 64) {
        float v = hp[k];
        const float* wp = wr + (size_t)k * EE;
#pragma unroll
        for (int n = 0; n < EE; ++n) acc[n] += v * wp[n];
    }
#pragma unroll
    for (int off = 32; off; off >>= 1)
#pragma unroll
        for (int n = 0; n < EE; ++n) acc[n] += __shfl_xor(acc[n], off);
    if (lane == 0) {
        float mx = acc[0]; int best = 0;
#pragma unroll
        for (int n = 1; n < EE; ++n) if (acc[n] > mx) { mx = acc[n]; best = n; }
        float den = 0.f;
#pragma unroll
        for (int n = 0; n < EE; ++n) den += expf(acc[n] - mx);
        gate[m] = 1.f / den;
        eid[m] = best;
        atomicAdd(&counts[best], 1);
#pragma unroll
        for (int n = 0; n < EE; ++n) logits_out[(size_t)m * EE + n] = acc[n];
    }
}

// ---------------- fused routing bookkeeping: offsets + tiles + scatter (1 block) ----------------
__global__ void k_offscatter(const int* __restrict__ counts,
                             int* __restrict__ te, int* __restrict__ ts, int* __restrict__ tr,
                             int* __restrict__ ntl, const int* __restrict__ eid,
                             int* __restrict__ fill, int* __restrict__ perm) {
    __shared__ int soffs[EE];
    int t = threadIdx.x;
    if (t == 0) {
        int off = 0, nt = 0;
        for (int e = 0; e < EE; ++e) {
            soffs[e] = off;
            int c = counts[e];
            for (int t0 = 0; t0 < c; t0 += 128) {
                te[nt] = e; ts[nt] = off + t0; tr[nt] = (c - t0 < 128) ? (c - t0) : 128; ++nt;
            }
            off += c;
        }
        *ntl = nt;
    }
    __syncthreads();
#pragma unroll
    for (int tok = t; tok < MM; tok += 1024) {
        int e = eid[tok];
        int pos = soffs[e] + atomicAdd(&fill[e], 1);
        perm[pos] = tok;
    }
}

// ---------------- launch ----------------
extern "C" void kernel_launch(void* const* d_in, const int* in_sizes, int n_in,
                              void* d_out, int out_size, void* d_ws, size_t ws_size,
                              hipStream_t stream) {
    const float* x     = (const float*)d_in[0];
    const float* ln1w  = (const float*)d_in[1];
    const float* ln1b  = (const float*)d_in[2];
    const float* ln2w  = (const float*)d_in[3];
    const float* ln2b  = (const float*)d_in[4];
    const float* w_qkv = (const float*)d_in[5];
    const float* b_qkv = (const float*)d_in[6];
    const float* w_out = (const float*)d_in[7];
    const float* b_out = (const float*)d_in[8];
    const float* w_rtr = (const float*)d_in[9];
    const float* wi    = (const float*)d_in[10];
    const float* wo    = (const float*)d_in[11];
    float* out = (float*)d_out;

    char* wsb = (char*)d_ws;
    __hip_bfloat16* wiT  = (__hip_bfloat16*)(wsb + OFF_WIT);
    __hip_bfloat16* woT  = (__hip_bfloat16*)(wsb + OFF_WOT);
    __hip_bfloat16* wqH  = (__hip_bfloat16*)(wsb + OFF_WQH);
    __hip_bfloat16* wqL  = (__hip_bfloat16*)(wsb + OFF_WQL);
    __hip_bfloat16* woH  = (__hip_bfloat16*)(wsb + OFF_WOH);
    __hip_bfloat16* woL  = (__hip_bfloat16*)(wsb + OFF_WOL);
    __hip_bfloat16* h1H  = (__hip_bfloat16*)(wsb + OFF_H1H);
    __hip_bfloat16* h1L  = (__hip_bfloat16*)(wsb + OFF_H1L);
    float*          qkvF = (float*)(wsb + OFF_QKV);
    float*          h2F  = (float*)(wsb + OFF_H2F);
    __hip_bfloat16* oH   = (__hip_bfloat16*)(wsb + OFF_OH);
    __hip_bfloat16* oL   = (__hip_bfloat16*)(wsb + OFF_OL);
    float*          x2F  = (float*)(wsb + OFF_X2);
    __hip_bfloat16* h2B  = (__hip_bfloat16*)(wsb + OFF_H2B);
    __hip_bfloat16* actB = (__hip_bfloat16*)(wsb + OFF_ACT);
    short* KSH = (short*)(wsb + OFF_KSH);
    short* KSL = (short*)(wsb + OFF_KSL);
    short* VTH = (short*)(wsb + OFF_VTH);
    short* VTL = (short*)(wsb + OFF_VTL);
    float* gate = (float*)(wsb + OFF_GATE);
    int* eid    = (int*)(wsb + OFF_EID);
    int* perm   = (int*)(wsb + OFF_PERM);
    int* counts = (int*)(wsb + OFF_CNT);
    int* fill   = (int*)(wsb + OFF_FILL);
    int* ntl    = (int*)(wsb + OFF_NT);
    int* te     = (int*)(wsb + OFF_TE);
    int* tsx    = (int*)(wsb + OFF_TS);
    int* trx    = (int*)(wsb + OFF_TR);

    // 0. weight conversion (qkv+out in one launch; wi/wo transposes)
    k_cvt2<<<4096, 256, 0, stream>>>(w_qkv, wqH, wqL, 3072 * 1024 / 4,
                                     w_out, woH, woL, 1024 * 1024 / 4);
    k_tcvt<<<dim3(4096 / 32, 1024 / 32, EE), 256, 0, stream>>>(wi, wiT, 1024, 4096);
    k_tcvt<<<dim3(1024 / 32, 2048 / 32, EE), 256, 0, stream>>>(wo, woT, 2048, 1024);

    // 1. LN1 + RoPE -> h1 hi/lo
    k_ln<0><<<MM, 256, 0, stream>>>(x, ln1w, ln1b, h1H, h1L, nullptr, nullptr);
    // 2. qkv = h1 @ w_qkv^T + b_qkv (split precision, f32 out)
    k_mfma_split<0><<<dim3(3072 / 128, MM / 128), 256, 0, stream>>>(
        h1H, h1L, wqH, wqL, b_qkv, nullptr, qkvF, MM, 3072, DD);
    // 2.5 prep: split K + transposed V (overwrites dead wq/h1 regions)
    k_prep<<<dim3(SS / 64, HH, BB), 256, 0, stream>>>(qkvF, KSH, KSL, VTH, VTL);
    // 3. attention (split-precision MFMA, double-buffered, hi/lo bf16 out)
    k_attn_mfma<<<dim3(SS / 128, HH, BB), 512, 0, stream>>>(qkvF, KSH, KSL, VTH, VTL, oH, oL);
    // 4. x2 = x + o @ w_out^T + b_out (split precision, f32)
    k_mfma_split<1><<<dim3(DD / 128, MM / 128), 256, 0, stream>>>(
        oH, oL, woH, woL, b_out, x, x2F, MM, DD, DD);
    // 5. LN2 -> h2 (bf16 + f32); zeroes routing counters (17 ints)
    k_ln<1><<<MM, 256, 0, stream>>>(x2F, ln2w, ln2b, h2B, nullptr, h2F, counts);
    // 6. router (f32 h2 -> exact logits/argmax)
    k_router<<<MM / 4, 256, 0, stream>>>(h2F, w_rtr, out + (size_t)MM * DD, gate, eid, counts);
    // 7. fused offsets + tiles + scatter
    k_offscatter<<<1, 1024, 0, stream>>>(counts, te, tsx, trx, ntl, eid, fill, perm);
    // 8. act = silu(h2[perm] @ wiT_a) * (h2[perm] @ wiT_g)  — fused epilogue
    k_moe_up<<<dim3(2048 / 64, MAX_TILES), 256, 0, stream>>>(
        h2B, wiT, actB, perm, te, tsx, trx, ntl);
    // 9. out = x2 + gate * (act @ woT[e]^T)
    k_moe_dn<<<dim3(DD / 128, MAX_TILES), 256, 0, stream>>>(
        actB, woT, x2F, out, perm, te, tsx, trx, ntl, gate);
}

// Round 8
// 384.386 us; speedup vs baseline: 1.2172x; 1.0071x over previous
//
#include <hip/hip_runtime.h>
#include <hip/hip_bf16.h>
#include <math.h>

// Problem constants
#define BB 2
#define SS 1024
#define DD 1024
#define FF 4096
#define HH 16
#define EE 8
#define MM (BB*SS)          // 2048 tokens
#define MAX_TILES 24        // sum_e ceil(cnt_e/128) <= 2048/128 + 8

typedef __attribute__((ext_vector_type(8))) short bf16x8;
typedef __attribute__((ext_vector_type(8))) short s16x8;
typedef __attribute__((ext_vector_type(4))) float f32x4;

// ---------------- workspace layout (bytes) ----------------
#define OFF_WIT  ((size_t)0)            // wi^T bf16: 8*4096*1024*2 = 67108864
#define OFF_WOT  ((size_t)67108864)     // wo^T bf16: 33554432
#define OFF_WQH  ((size_t)100663296)    // w_qkv hi bf16: 6291456   (later: K split hi/lo, 8MB)
#define OFF_WQL  ((size_t)106954752)    // w_qkv lo bf16: 6291456
#define OFF_WOH  ((size_t)113246208)    // w_out hi bf16: 2097152
#define OFF_WOL  ((size_t)115343360)    // w_out lo bf16: 2097152
#define OFF_H1H  ((size_t)117440512)    // h1 hi bf16: 4194304      (later: VT hi)
#define OFF_H1L  ((size_t)121634816)    // h1 lo bf16: 4194304      (later: VT lo)
#define OFF_QKV  ((size_t)125829120)    // qkv f32: 25165824
#define OFF_H2F  ((size_t)142606336)    // h2 f32: 8388608
#define OFF_OH   ((size_t)150994944)    // attn o hi bf16: 4194304
#define OFF_OL   ((size_t)155189248)    // attn o lo bf16: 4194304
#define OFF_X2   ((size_t)159383552)    // x2 f32: 8388608
#define OFF_H2B  ((size_t)167772160)    // h2 bf16: 4194304
#define OFF_ACT  ((size_t)171966464)    // act bf16 (2048+128 rows)*2048*2 = 8912896
#define OFF_GATE ((size_t)180879360)
#define OFF_EID  ((size_t)180887552)
#define OFF_PERM ((size_t)180895744)
#define OFF_CNT  ((size_t)180903936)    // 17 ints zeroed by k_ln<1>
#define OFF_FILL ((size_t)180903968)
#define OFF_NT   ((size_t)180904000)
#define OFF_TE   ((size_t)180904192)
#define OFF_TS   ((size_t)180904320)
#define OFF_TR   ((size_t)180904448)
// attention K/V split buffers (reuse dead regions)
#define OFF_KSH  OFF_WQH                         // 4MB
#define OFF_KSL  (OFF_WQH + 4194304)             // 4MB (spills into wqL region - dead)
#define OFF_VTH  OFF_H1H                         // 4MB
#define OFF_VTL  OFF_H1L                         // 4MB

// ---------------- async global->LDS (16B per lane) ----------------
__device__ __forceinline__ void gload16(const void* g, void* l) {
    __builtin_amdgcn_global_load_lds(
        (const __attribute__((address_space(1))) unsigned int*)g,
        (__attribute__((address_space(3))) unsigned int*)l, 16, 0, 0);
}

__device__ __forceinline__ short bfh(float v) {
    __hip_bfloat16 h = __float2bfloat16(v);
    return *(short*)&h;
}
__device__ __forceinline__ float bf2f(short s) {
    __hip_bfloat16 h = *(__hip_bfloat16*)&s;
    return __bfloat162float(h);
}

__device__ __forceinline__ void split_write(float v, __hip_bfloat16* hp, __hip_bfloat16* lp, size_t idx) {
    __hip_bfloat16 h = __float2bfloat16(v);
    hp[idx] = h;
    lp[idx] = __float2bfloat16(v - __bfloat162float(h));
}

// ---------------- f32 -> bf16 hi/lo split convert, two tensors in one launch ----------------
__global__ void k_cvt2(const float* __restrict__ in1, __hip_bfloat16* __restrict__ hi1,
                       __hip_bfloat16* __restrict__ lo1, int n4_1,
                       const float* __restrict__ in2, __hip_bfloat16* __restrict__ hi2,
                       __hip_bfloat16* __restrict__ lo2, int n4_2) {
    int i = blockIdx.x * 256 + threadIdx.x;
    const float* in; __hip_bfloat16 *hi, *lo; int idx;
    if (i < n4_1) { in = in1; hi = hi1; lo = lo1; idx = i; }
    else { idx = i - n4_1; if (idx >= n4_2) return; in = in2; hi = hi2; lo = lo2; }
    float4 v = ((const float4*)in)[idx];
    split_write(v.x, hi, lo, (size_t)idx * 4 + 0);
    split_write(v.y, hi, lo, (size_t)idx * 4 + 1);
    split_write(v.z, hi, lo, (size_t)idx * 4 + 2);
    split_write(v.w, hi, lo, (size_t)idx * 4 + 3);
}

// ---------------- batched transpose-convert, 64x64 tiles, vectorized 16B stores ----------------
// in (R,C) f32 -> out (C,R) bf16
__global__ void k_tcvt64(const float* __restrict__ in, __hip_bfloat16* __restrict__ out, int R, int C) {
    __shared__ float tile[64][65];
    int c0 = blockIdx.x * 64, r0 = blockIdx.y * 64;
    size_t eoff = (size_t)blockIdx.z * R * C;
    in += eoff; out += eoff;
    int t = threadIdx.x;
    {
        int ri = t >> 2, cj = (t & 3) * 16;
        const float* ip = &in[(size_t)(r0 + ri) * C + c0 + cj];
#pragma unroll
        for (int k = 0; k < 4; ++k) {
            float4 v = *(const float4*)(ip + k * 4);
            tile[ri][cj + k * 4 + 0] = v.x;
            tile[ri][cj + k * 4 + 1] = v.y;
            tile[ri][cj + k * 4 + 2] = v.z;
            tile[ri][cj + k * 4 + 3] = v.w;
        }
    }
    __syncthreads();
    {
        int co = t >> 2, rj = (t & 3) * 16;
        bf16x8 v8a, v8b;
#pragma unroll
        for (int q = 0; q < 8; ++q) v8a[q] = bfh(tile[rj + q][co]);
#pragma unroll
        for (int q = 0; q < 8; ++q) v8b[q] = bfh(tile[rj + 8 + q][co]);
        __hip_bfloat16* op = &out[(size_t)(c0 + co) * R + r0 + rj];
        *(bf16x8*)op = v8a;
        *(bf16x8*)(op + 8) = v8b;
    }
}

// ---------------- LayerNorm: MODE 0 = +RoPE, hi/lo out; MODE 1 = plain, bf16+f32 out ----------------
template<int MODE>
__global__ void k_ln(const float* __restrict__ x, const float* __restrict__ w,
                     const float* __restrict__ b, __hip_bfloat16* __restrict__ hi,
                     __hip_bfloat16* __restrict__ lo, float* __restrict__ f32o,
                     int* __restrict__ zero17) {
    int m = blockIdx.x;
    int s = m & (SS - 1);
    __shared__ float row[DD];
    __shared__ float red[8];
    int t = threadIdx.x;
    if (MODE == 1 && m == 0 && t < 17) zero17[t] = 0;   // routing counters
    const float* xp = x + (size_t)m * DD;
    float sum = 0.f, sumsq = 0.f;
#pragma unroll
    for (int l = 0; l < 4; ++l) {
        int i = t + l * 256;
        float v = xp[i];
        row[i] = v;
        sum += v; sumsq += v * v;
    }
#pragma unroll
    for (int off = 32; off; off >>= 1) {
        sum   += __shfl_xor(sum, off);
        sumsq += __shfl_xor(sumsq, off);
    }
    int wid = t >> 6, lane = t & 63;
    if (lane == 0) { red[wid] = sum; red[4 + wid] = sumsq; }
    __syncthreads();
    sum   = red[0] + red[1] + red[2] + red[3];
    sumsq = red[4] + red[5] + red[6] + red[7];
    float mean = sum * (1.f / DD);
    float var  = sumsq * (1.f / DD) - mean * mean;
    float rstd = rsqrtf(var + 1e-5f);
    size_t base = (size_t)m * DD;
    if (MODE == 0) {
        const float kln = logf(10000.f) / 512.f;
#pragma unroll
        for (int l = 0; l < 2; ++l) {
            int i = t + l * 256;   // 0..511
            float n1 = (row[i]       - mean) * rstd * w[i]       + b[i];
            float n2 = (row[i + 512] - mean) * rstd * w[i + 512] + b[i + 512];
            float inv = expf(-(float)i * kln);
            float ang = (float)s * inv;
            float c = cosf(ang), sn = sinf(ang);
            split_write(n1 * c - n2 * sn,  hi, lo, base + i);
            split_write(n1 * sn + n2 * c, hi, lo, base + i + 512);
        }
    } else {
#pragma unroll
        for (int l = 0; l < 4; ++l) {
            int i = t + l * 256;
            float v = (row[i] - mean) * rstd * w[i] + b[i];
            hi[base + i] = __float2bfloat16(v);
            f32o[base + i] = v;
        }
    }
}

// ---------------- split-precision MFMA GEMM: C = A @ Bt^T + bias (+addsrc) ----------------
template<int MODE>
__global__ void k_mfma_split(const __hip_bfloat16* __restrict__ Ah, const __hip_bfloat16* __restrict__ Al,
                             const __hip_bfloat16* __restrict__ Bh, const __hip_bfloat16* __restrict__ Bl,
                             const float* __restrict__ bias, const float* __restrict__ addsrc,
                             float* __restrict__ Cf, int M, int N, int K) {
    __shared__ __align__(16) short AsH[128 * 32];
    __shared__ __align__(16) short AsL[128 * 32];
    __shared__ __align__(16) short BsH[128 * 32];
    __shared__ __align__(16) short BsL[128 * 32];
    int m0 = blockIdx.y * 128, n0 = blockIdx.x * 128;
    const int t = threadIdx.x;
    const int w = t >> 6, lane = t & 63;
    const int wr = w >> 1, wc = w & 1;
    const int sid = w * 64 + lane;

    f32x4 acc[4][4] = {};

    for (int k0 = 0; k0 < K; k0 += 32) {
#pragma unroll
        for (int j = 0; j < 2; ++j) {
            int id = j * 256 + sid;
            int rrow = id >> 2, sl = id & 3;
            int slog = sl ^ ((rrow >> 1) & 3);
            size_t lbase = (size_t)(j * 256 + w * 64) * 8;
            size_t gaoff = (size_t)(m0 + rrow) * K + k0 + slog * 8;
            gload16(Ah + gaoff, &AsH[lbase]);
            gload16(Al + gaoff, &AsL[lbase]);
            size_t gboff = (size_t)(n0 + rrow) * K + k0 + slog * 8;
            gload16(Bh + gboff, &BsH[lbase]);
            gload16(Bl + gboff, &BsL[lbase]);
        }
        __syncthreads();
        bf16x8 ah[4], al[4], bh[4], bl[4];
#pragma unroll
        for (int i = 0; i < 4; ++i) {
            int ra = wr * 64 + i * 16 + (lane & 15);
            int pa = (lane >> 4) ^ ((ra >> 1) & 3);
            ah[i] = *(const bf16x8*)&AsH[ra * 32 + pa * 8];
            al[i] = *(const bf16x8*)&AsL[ra * 32 + pa * 8];
            int rb = wc * 64 + i * 16 + (lane & 15);
            int pb = (lane >> 4) ^ ((rb >> 1) & 3);
            bh[i] = *(const bf16x8*)&BsH[rb * 32 + pb * 8];
            bl[i] = *(const bf16x8*)&BsL[rb * 32 + pb * 8];
        }
#pragma unroll
        for (int i = 0; i < 4; ++i)
#pragma unroll
            for (int n = 0; n < 4; ++n) {
                acc[i][n] = __builtin_amdgcn_mfma_f32_16x16x32_bf16(ah[i], bh[n], acc[i][n], 0, 0, 0);
                acc[i][n] = __builtin_amdgcn_mfma_f32_16x16x32_bf16(ah[i], bl[n], acc[i][n], 0, 0, 0);
                acc[i][n] = __builtin_amdgcn_mfma_f32_16x16x32_bf16(al[i], bh[n], acc[i][n], 0, 0, 0);
            }
        __syncthreads();
    }

    int cn = n0 + wc * 64 + (lane & 15);
#pragma unroll
    for (int i = 0; i < 4; ++i) {
#pragma unroll
        for (int n = 0; n < 4; ++n) {
            int col = cn + n * 16;
#pragma unroll
            for (int q = 0; q < 4; ++q) {
                int r = wr * 64 + i * 16 + (lane >> 4) * 4 + q;
                float v = acc[i][n][q] + bias[col];
                if (MODE == 1) v += addsrc[(size_t)(m0 + r) * N + col];
                Cf[(size_t)(m0 + r) * N + col] = v;
            }
        }
    }
}

// ---------------- MoE up-proj with interleaved a/g columns + fused silu epilogue ----------------
__global__ void k_moe_up(const __hip_bfloat16* __restrict__ A,     // h2 bf16 (M,1024)
                         const __hip_bfloat16* __restrict__ Bt,    // wiT (E,4096,1024)
                         __hip_bfloat16* __restrict__ act,         // (perm rows, 2048)
                         const int* __restrict__ perm,
                         const int* __restrict__ te, const int* __restrict__ ts,
                         const int* __restrict__ tr, const int* __restrict__ ntl) {
    __shared__ __align__(16) short As[128 * 32];
    __shared__ __align__(16) short Bs[128 * 32];
    __shared__ int permS[128];
    int tile = blockIdx.y;
    if (tile >= *ntl) return;
    int e = te[tile], rs = ts[tile], rows = tr[tile];
    if (threadIdx.x < 128) {
        int r = threadIdx.x;
        permS[r] = (r < rows) ? perm[rs + r] : 0;
    }
    __syncthreads();
    int c0 = blockIdx.x * 64;
    const int t = threadIdx.x;
    const int w = t >> 6, lane = t & 63;
    const int wr = w >> 1, wc = w & 1;
    const int sid = w * 64 + lane;
    const int g = lane >> 4, r16 = lane & 15;

    const __hip_bfloat16* Bp = Bt + (size_t)e * FF * DD;

    f32x4 acc[4][4] = {};

    for (int k0 = 0; k0 < DD; k0 += 32) {
#pragma unroll
        for (int j = 0; j < 2; ++j) {
            int id = j * 256 + sid;
            int rrow = id >> 2, sl = id & 3;
            int slog = sl ^ ((rrow >> 1) & 3);
            size_t lbase = (size_t)(j * 256 + w * 64) * 8;
            gload16(A + (size_t)permS[rrow] * DD + k0 + slog * 8, &As[lbase]);
            int q = rrow >> 4, rr = rrow & 15;
            int wrow = c0 + (q >> 2) * 32 + ((q & 3) >> 1) * 16 + rr + (q & 1) * 2048;
            gload16(Bp + (size_t)wrow * DD + k0 + slog * 8, &Bs[lbase]);
        }
        __syncthreads();
        bf16x8 af[4], bfr[4];
#pragma unroll
        for (int i = 0; i < 4; ++i) {
            int ra = wr * 64 + i * 16 + r16;
            int pa = g ^ ((ra >> 1) & 3);
            af[i] = *(const bf16x8*)&As[ra * 32 + pa * 8];
            int rb = wc * 64 + i * 16 + r16;
            int pb = g ^ ((rb >> 1) & 3);
            bfr[i] = *(const bf16x8*)&Bs[rb * 32 + pb * 8];
        }
#pragma unroll
        for (int i = 0; i < 4; ++i)
#pragma unroll
            for (int n = 0; n < 4; ++n)
                acc[i][n] = __builtin_amdgcn_mfma_f32_16x16x32_bf16(af[i], bfr[n], acc[i][n], 0, 0, 0);
        __syncthreads();
    }

    // epilogue: act[r, col] = silu(a)*g ; (n=2p, n=2p+1) pair same col
#pragma unroll
    for (int i = 0; i < 4; ++i) {
#pragma unroll
        for (int p2 = 0; p2 < 2; ++p2) {
            int col = c0 + wc * 32 + p2 * 16 + r16;
#pragma unroll
            for (int q = 0; q < 4; ++q) {
                int r = wr * 64 + i * 16 + g * 4 + q;
                if (r < rows) {
                    float a  = acc[i][2 * p2][q];
                    float gv = acc[i][2 * p2 + 1][q];
                    act[(size_t)(rs + r) * 2048 + col] =
                        __float2bfloat16((a / (1.f + expf(-a))) * gv);
                }
            }
        }
    }
}

// ---------------- MoE down-proj: out = x2 + gate * (act @ woT[e]^T) ----------------
__global__ void k_moe_dn(const __hip_bfloat16* __restrict__ A,     // act (perm rows, 2048)
                         const __hip_bfloat16* __restrict__ Bt,    // woT (E,1024,2048)
                         const float* __restrict__ addsrc, float* __restrict__ Cf,
                         const int* __restrict__ perm,
                         const int* __restrict__ te, const int* __restrict__ ts,
                         const int* __restrict__ tr, const int* __restrict__ ntl,
                         const float* __restrict__ gate) {
    __shared__ __align__(16) short As[128 * 32];
    __shared__ __align__(16) short Bs[128 * 32];
    __shared__ int permS[128];
    int tile = blockIdx.y;
    if (tile >= *ntl) return;
    int e = te[tile], rs = ts[tile], rows = tr[tile];
    if (threadIdx.x < 128) {
        int r = threadIdx.x;
        permS[r] = (r < rows) ? perm[rs + r] : 0;
    }
    __syncthreads();
    int n0 = blockIdx.x * 128;
    const int t = threadIdx.x;
    const int w = t >> 6, lane = t & 63;
    const int wr = w >> 1, wc = w & 1;
    const int sid = w * 64 + lane;
    const int K = FF / 2;

    const __hip_bfloat16* Bp = Bt + (size_t)e * DD * (FF / 2);

    f32x4 acc[4][4] = {};

    for (int k0 = 0; k0 < K; k0 += 32) {
#pragma unroll
        for (int j = 0; j < 2; ++j) {
            int id = j * 256 + sid;
            int rrow = id >> 2, sl = id & 3;
            int slog = sl ^ ((rrow >> 1) & 3);
            size_t lbase = (size_t)(j * 256 + w * 64) * 8;
            gload16(A + (size_t)(rs + rrow) * K + k0 + slog * 8, &As[lbase]);
            gload16(Bp + (size_t)(n0 + rrow) * K + k0 + slog * 8, &Bs[lbase]);
        }
        __syncthreads();
        bf16x8 af[4], bfr[4];
#pragma unroll
        for (int i = 0; i < 4; ++i) {
            int ra = wr * 64 + i * 16 + (lane & 15);
            int pa = (lane >> 4) ^ ((ra >> 1) & 3);
            af[i] = *(const bf16x8*)&As[ra * 32 + pa * 8];
            int rb = wc * 64 + i * 16 + (lane & 15);
            int pb = (lane >> 4) ^ ((rb >> 1) & 3);
            bfr[i] = *(const bf16x8*)&Bs[rb * 32 + pb * 8];
        }
#pragma unroll
        for (int i = 0; i < 4; ++i)
#pragma unroll
            for (int n = 0; n < 4; ++n)
                acc[i][n] = __builtin_amdgcn_mfma_f32_16x16x32_bf16(af[i], bfr[n], acc[i][n], 0, 0, 0);
        __syncthreads();
    }

    int cn = n0 + wc * 64 + (lane & 15);
#pragma unroll
    for (int i = 0; i < 4; ++i) {
#pragma unroll
        for (int n = 0; n < 4; ++n) {
            int col = cn + n * 16;
#pragma unroll
            for (int q = 0; q < 4; ++q) {
                int r = wr * 64 + i * 16 + (lane >> 4) * 4 + q;
                if (r >= rows) continue;
                int tok = permS[r];
                Cf[(size_t)tok * DD + col] = addsrc[(size_t)tok * DD + col] + gate[tok] * acc[i][n][q];
            }
        }
    }
}

// ---------------- attention prep: split K -> [b,h,s,d] swz, V^T -> [b,h,d,s] swz ----------------
__global__ void k_prep(const float* __restrict__ qkv, short* __restrict__ KH, short* __restrict__ KL,
                       short* __restrict__ VH, short* __restrict__ VL) {
    __shared__ float tile[64][65];
    int b = blockIdx.z, h = blockIdx.y, s0 = blockIdx.x * 64;
    int t = threadIdx.x;
    int row = t >> 2, c0 = (t & 3) * 16;
    const float* kp = qkv + (size_t)(b * SS + s0 + row) * 3072 + 1024 + h * 64 + c0;
    const float* vp = kp + 1024;
    // K: split + slot-swizzled write
    {
        size_t krow = ((size_t)(b * HH + h) * SS + s0 + row) * 64;
        int key = (s0 + row) & 7;
#pragma unroll
        for (int g2 = 0; g2 < 2; ++g2) {
            s16x8 hv, lv;
#pragma unroll
            for (int j = 0; j < 8; ++j) {
                float v = kp[g2 * 8 + j];
                short hh = bfh(v);
                hv[j] = hh; lv[j] = bfh(v - bf2f(hh));
            }
            int p = ((c0 >> 3) + g2) ^ key;
            *(s16x8*)&KH[krow + p * 8] = hv;
            *(s16x8*)&KL[krow + p * 8] = lv;
        }
    }
    // V: stage f32, transpose, split + slot-swizzled write
#pragma unroll
    for (int j = 0; j < 16; ++j) tile[row][c0 + j] = vp[j];
    __syncthreads();
    {
        int d = t >> 2, sc = (t & 3) * 16;
        size_t vrow = ((size_t)(b * HH + h) * 64 + d) * SS + s0;
        int key = d & 7;
#pragma unroll
        for (int g2 = 0; g2 < 2; ++g2) {
            s16x8 hv, lv;
#pragma unroll
            for (int j = 0; j < 8; ++j) {
                float v = tile[sc + g2 * 8 + j][d];
                short hh = bfh(v);
                hv[j] = hh; lv[j] = bfh(v - bf2f(hh));
            }
            int p = ((sc >> 3) + g2) ^ key;
            *(s16x8*)&VH[vrow + p * 8] = hv;
            *(s16x8*)&VL[vrow + p * 8] = lv;
        }
    }
}

// ---------------- MFMA flash attention: 4 waves x 16 q-rows (QB=64), 512 blocks,
// single-buffered K/V (50.6KB LDS -> multi-block/CU), XCD-swizzled grid ----------------
#define LDP 72
__global__ __launch_bounds__(256, 3)
void k_attn_mfma(const float* __restrict__ qkv,
                 const short* __restrict__ KH, const short* __restrict__ KL,
                 const short* __restrict__ VH, const short* __restrict__ VL,
                 __hip_bfloat16* __restrict__ ohi, __hip_bfloat16* __restrict__ olo) {
    __shared__ __align__(16) short Ks[64 * 64], Kl2[64 * 64], Vs[64 * 64], Vl2[64 * 64];
    __shared__ __align__(16) short PhS[4][16 * LDP], PlS[4][16 * LDP];
    // XCD swizzle: 512 blocks, 8 XCDs, 64 slots each; 4 (b,h) groups per XCD
    int id = blockIdx.x;
    int xcd = id & 7, slot = id >> 3;
    int bh = xcd * 4 + (slot >> 4);
    int qt = slot & 15;
    int b = bh >> 4, h = bh & 15, q0 = qt * 64;
    int t = threadIdx.x;
    int w = t >> 6, lane = t & 63;
    int g = lane >> 4, r16 = lane & 15;

    const size_t kbase = ((size_t)bh * SS) * 64;
    const size_t vbase = ((size_t)bh * 64) * SS;

    // ---- Q fragments direct from f32 qkv, prescale 1/8, split in-reg
    bf16x8 qfh[2], qfl[2];
    {
        const float* qp = qkv + (size_t)(b * SS + q0 + w * 16 + r16) * 3072 + h * 64;
#pragma unroll
        for (int ks = 0; ks < 2; ++ks) {
            float vv[8];
            *(float4*)&vv[0] = *(const float4*)(qp + ks * 32 + g * 8);
            *(float4*)&vv[4] = *(const float4*)(qp + ks * 32 + g * 8 + 4);
#pragma unroll
            for (int j = 0; j < 8; ++j) {
                float sv = vv[j] * 0.125f;
                short hh = bfh(sv);
                qfh[ks][j] = hh;
                qfl[ks][j] = bfh(sv - bf2f(hh));
            }
        }
    }

    float mrun[4], lrun[4];
    f32x4 oacc[4] = {};
#pragma unroll
    for (int q = 0; q < 4; ++q) { mrun[q] = -1e30f; lrun[q] = 0.f; }

    for (int k0 = 0; k0 < SS; k0 += 64) {
        // ---- stage K/V tile (8 gload16/thread; linear copy, swizzle in global layout)
#pragma unroll
        for (int pass = 0; pass < 2; ++pass) {
            int idb = pass * 256 + w * 64;       // wave-uniform base
            int sidl = idb + lane;
            int row = sidl >> 3, sl = sidl & 7;
            gload16(KH + kbase + (size_t)(k0 + row) * 64 + sl * 8, &Ks[(size_t)idb * 8]);
            gload16(KL + kbase + (size_t)(k0 + row) * 64 + sl * 8, &Kl2[(size_t)idb * 8]);
            gload16(VH + vbase + (size_t)row * SS + k0 + sl * 8,   &Vs[(size_t)idb * 8]);
            gload16(VL + vbase + (size_t)row * SS + k0 + sl * 8,   &Vl2[(size_t)idb * 8]);
        }
        __syncthreads();   // drains gload vmcnt

        // ---- S = Q K^T (split, 3 MFMA per fragment)
        f32x4 accs[4] = {};
#pragma unroll
        for (int ks = 0; ks < 2; ++ks) {
            bf16x8 kfh[4], kfl[4];
#pragma unroll
            for (int n = 0; n < 4; ++n) {
                int rb = n * 16 + r16;
                int p = (ks * 4 + g) ^ (r16 & 7);
                kfh[n] = *(const bf16x8*)&Ks[rb * 64 + p * 8];
                kfl[n] = *(const bf16x8*)&Kl2[rb * 64 + p * 8];
            }
            __builtin_amdgcn_s_setprio(1);
#pragma unroll
            for (int n = 0; n < 4; ++n) {
                accs[n] = __builtin_amdgcn_mfma_f32_16x16x32_bf16(qfh[ks], kfh[n], accs[n], 0, 0, 0);
                accs[n] = __builtin_amdgcn_mfma_f32_16x16x32_bf16(qfh[ks], kfl[n], accs[n], 0, 0, 0);
                accs[n] = __builtin_amdgcn_mfma_f32_16x16x32_bf16(qfl[ks], kfh[n], accs[n], 0, 0, 0);
            }
            __builtin_amdgcn_s_setprio(0);
        }

        // ---- online softmax
        float mn[4], corr[4], psum[4];
#pragma unroll
        for (int q = 0; q < 4; ++q) {
            float m = fmaxf(fmaxf(accs[0][q], accs[1][q]), fmaxf(accs[2][q], accs[3][q]));
            m = fmaxf(m, __shfl_xor(m, 1));
            m = fmaxf(m, __shfl_xor(m, 2));
            m = fmaxf(m, __shfl_xor(m, 4));
            m = fmaxf(m, __shfl_xor(m, 8));
            mn[q] = fmaxf(mrun[q], m);
            corr[q] = expf(mrun[q] - mn[q]);
            mrun[q] = mn[q];
            psum[q] = 0.f;
        }
#pragma unroll
        for (int n = 0; n < 4; ++n)
#pragma unroll
            for (int q = 0; q < 4; ++q) {
                float p = expf(accs[n][q] - mn[q]);
                psum[q] += p;
                short ph = bfh(p);
                PhS[w][(g * 4 + q) * LDP + n * 16 + r16] = ph;
                PlS[w][(g * 4 + q) * LDP + n * 16 + r16] = bfh(p - bf2f(ph));
            }
#pragma unroll
        for (int q = 0; q < 4; ++q) {
            psum[q] += __shfl_xor(psum[q], 1);
            psum[q] += __shfl_xor(psum[q], 2);
            psum[q] += __shfl_xor(psum[q], 4);
            psum[q] += __shfl_xor(psum[q], 8);
            lrun[q] = lrun[q] * corr[q] + psum[q];
#pragma unroll
            for (int n = 0; n < 4; ++n) oacc[n][q] *= corr[q];
        }

        // ---- O += P V (split)
#pragma unroll
        for (int ks = 0; ks < 2; ++ks) {
            bf16x8 vfh[4], vfl[4];
#pragma unroll
            for (int n = 0; n < 4; ++n) {
                int rb = n * 16 + r16;
                int p = (ks * 4 + g) ^ (r16 & 7);
                vfh[n] = *(const bf16x8*)&Vs[rb * 64 + p * 8];
                vfl[n] = *(const bf16x8*)&Vl2[rb * 64 + p * 8];
            }
            bf16x8 pfh = *(const bf16x8*)&PhS[w][r16 * LDP + ks * 32 + g * 8];
            bf16x8 pfl = *(const bf16x8*)&PlS[w][r16 * LDP + ks * 32 + g * 8];
            __builtin_amdgcn_s_setprio(1);
#pragma unroll
            for (int n = 0; n < 4; ++n) {
                oacc[n] = __builtin_amdgcn_mfma_f32_16x16x32_bf16(pfh, vfh[n], oacc[n], 0, 0, 0);
                oacc[n] = __builtin_amdgcn_mfma_f32_16x16x32_bf16(pfh, vfl[n], oacc[n], 0, 0, 0);
                oacc[n] = __builtin_amdgcn_mfma_f32_16x16x32_bf16(pfl, vfh[n], oacc[n], 0, 0, 0);
            }
            __builtin_amdgcn_s_setprio(0);
        }
        __syncthreads();   // all waves done reading before next stage overwrites
    }

    // ---- epilogue
    float invl[4];
#pragma unroll
    for (int q = 0; q < 4; ++q) invl[q] = 1.f / lrun[q];
#pragma unroll
    for (int n = 0; n < 4; ++n) {
        int col = h * 64 + n * 16 + r16;
#pragma unroll
        for (int q = 0; q < 4; ++q) {
            int rowg = b * SS + q0 + w * 16 + g * 4 + q;
            split_write(oacc[n][q] * invl[q], ohi, olo, (size_t)rowg * DD + col);
        }
    }
}

// ---------------- router (f32 h2 in), 4 tokens/block ----------------
__global__ void k_router(const float* __restrict__ h2, const float* __restrict__ wr,
                         float* __restrict__ logits_out, float* __restrict__ gate,
                         int* __restrict__ eid, int* __restrict__ counts) {
    int m = blockIdx.x * 4 + (threadIdx.x >> 6);
    int lane = threadIdx.x & 63;
    const float* hp = h2 + (size_t)m * DD;
    float acc[EE] = {};
    for (int k = lane; k < DD; k += 64) {
        float v = hp[k];
        const float* wp = wr + (size_t)k * EE;
#pragma unroll
        for (int n = 0; n < EE; ++n) acc[n] += v * wp[n];
    }
#pragma unroll
    for (int off = 32; off; off >>= 1)
#pragma unroll
        for (int n = 0; n < EE; ++n) acc[n] += __shfl_xor(acc[n], off);
    if (lane == 0) {
        float mx = acc[0]; int best = 0;
#pragma unroll
        for (int n = 1; n < EE; ++n) if (acc[n] > mx) { mx = acc[n]; best = n; }
        float den = 0.f;
#pragma unroll
        for (int n = 0; n < EE; ++n) den += expf(acc[n] - mx);
        gate[m] = 1.f / den;
        eid[m] = best;
        atomicAdd(&counts[best], 1);
#pragma unroll
        for (int n = 0; n < EE; ++n) logits_out[(size_t)m * EE + n] = acc[n];
    }
}

// ---------------- fused routing bookkeeping: offsets + tiles + scatter (1 block) ----------------
__global__ void k_offscatter(const int* __restrict__ counts,
                             int* __restrict__ te, int* __restrict__ ts, int* __restrict__ tr,
                             int* __restrict__ ntl, const int* __restrict__ eid,
                             int* __restrict__ fill, int* __restrict__ perm) {
    __shared__ int soffs[EE];
    int t = threadIdx.x;
    if (t == 0) {
        int off = 0, nt = 0;
        for (int e = 0; e < EE; ++e) {
            soffs[e] = off;
            int c = counts[e];
            for (int t0 = 0; t0 < c; t0 += 128) {
                te[nt] = e; ts[nt] = off + t0; tr[nt] = (c - t0 < 128) ? (c - t0) : 128; ++nt;
            }
            off += c;
        }
        *ntl = nt;
    }
    __syncthreads();
#pragma unroll
    for (int tok = t; tok < MM; tok += 1024) {
        int e = eid[tok];
        int pos = soffs[e] + atomicAdd(&fill[e], 1);
        perm[pos] = tok;
    }
}

// ---------------- launch ----------------
extern "C" void kernel_launch(void* const* d_in, const int* in_sizes, int n_in,
                              void* d_out, int out_size, void* d_ws, size_t ws_size,
                              hipStream_t stream) {
    const float* x     = (const float*)d_in[0];
    const float* ln1w  = (const float*)d_in[1];
    const float* ln1b  = (const float*)d_in[2];
    const float* ln2w  = (const float*)d_in[3];
    const float* ln2b  = (const float*)d_in[4];
    const float* w_qkv = (const float*)d_in[5];
    const float* b_qkv = (const float*)d_in[6];
    const float* w_out = (const float*)d_in[7];
    const float* b_out = (const float*)d_in[8];
    const float* w_rtr = (const float*)d_in[9];
    const float* wi    = (const float*)d_in[10];
    const float* wo    = (const float*)d_in[11];
    float* out = (float*)d_out;

    char* wsb = (char*)d_ws;
    __hip_bfloat16* wiT  = (__hip_bfloat16*)(wsb + OFF_WIT);
    __hip_bfloat16* woT  = (__hip_bfloat16*)(wsb + OFF_WOT);
    __hip_bfloat16* wqH  = (__hip_bfloat16*)(wsb + OFF_WQH);
    __hip_bfloat16* wqL  = (__hip_bfloat16*)(wsb + OFF_WQL);
    __hip_bfloat16* woH  = (__hip_bfloat16*)(wsb + OFF_WOH);
    __hip_bfloat16* woL  = (__hip_bfloat16*)(wsb + OFF_WOL);
    __hip_bfloat16* h1H  = (__hip_bfloat16*)(wsb + OFF_H1H);
    __hip_bfloat16* h1L  = (__hip_bfloat16*)(wsb + OFF_H1L);
    float*          qkvF = (float*)(wsb + OFF_QKV);
    float*          h2F  = (float*)(wsb + OFF_H2F);
    __hip_bfloat16* oH   = (__hip_bfloat16*)(wsb + OFF_OH);
    __hip_bfloat16* oL   = (__hip_bfloat16*)(wsb + OFF_OL);
    float*          x2F  = (float*)(wsb + OFF_X2);
    __hip_bfloat16* h2B  = (__hip_bfloat16*)(wsb + OFF_H2B);
    __hip_bfloat16* actB = (__hip_bfloat16*)(wsb + OFF_ACT);
    short* KSH = (short*)(wsb + OFF_KSH);
    short* KSL = (short*)(wsb + OFF_KSL);
    short* VTH = (short*)(wsb + OFF_VTH);
    short* VTL = (short*)(wsb + OFF_VTL);
    float* gate = (float*)(wsb + OFF_GATE);
    int* eid    = (int*)(wsb + OFF_EID);
    int* perm   = (int*)(wsb + OFF_PERM);
    int* counts = (int*)(wsb + OFF_CNT);
    int* fill   = (int*)(wsb + OFF_FILL);
    int* ntl    = (int*)(wsb + OFF_NT);
    int* te     = (int*)(wsb + OFF_TE);
    int* tsx    = (int*)(wsb + OFF_TS);
    int* trx    = (int*)(wsb + OFF_TR);

    // 0. weight conversion (qkv+out in one launch; wi/wo transposes, 64x64 tiles)
    k_cvt2<<<4096, 256, 0, stream>>>(w_qkv, wqH, wqL, 3072 * 1024 / 4,
                                     w_out, woH, woL, 1024 * 1024 / 4);
    k_tcvt64<<<dim3(4096 / 64, 1024 / 64, EE), 256, 0, stream>>>(wi, wiT, 1024, 4096);
    k_tcvt64<<<dim3(1024 / 64, 2048 / 64, EE), 256, 0, stream>>>(wo, woT, 2048, 1024);

    // 1. LN1 + RoPE -> h1 hi/lo
    k_ln<0><<<MM, 256, 0, stream>>>(x, ln1w, ln1b, h1H, h1L, nullptr, nullptr);
    // 2. qkv = h1 @ w_qkv^T + b_qkv (split precision, f32 out)
    k_mfma_split<0><<<dim3(3072 / 128, MM / 128), 256, 0, stream>>>(
        h1H, h1L, wqH, wqL, b_qkv, nullptr, qkvF, MM, 3072, DD);
    // 2.5 prep: split K + transposed V (overwrites dead wq/h1 regions)
    k_prep<<<dim3(SS / 64, HH, BB), 256, 0, stream>>>(qkvF, KSH, KSL, VTH, VTL);
    // 3. attention (split-precision MFMA, QB=64, XCD-swizzled 512 blocks)
    k_attn_mfma<<<512, 256, 0, stream>>>(qkvF, KSH, KSL, VTH, VTL, oH, oL);
    // 4. x2 = x + o @ w_out^T + b_out (split precision, f32)
    k_mfma_split<1><<<dim3(DD / 128, MM / 128), 256, 0, stream>>>(
        oH, oL, woH, woL, b_out, x, x2F, MM, DD, DD);
    // 5. LN2 -> h2 (bf16 + f32); zeroes routing counters (17 ints)
    k_ln<1><<<MM, 256, 0, stream>>>(x2F, ln2w, ln2b, h2B, nullptr, h2F, counts);
    // 6. router (f32 h2 -> exact logits/argmax)
    k_router<<<MM / 4, 256, 0, stream>>>(h2F, w_rtr, out + (size_t)MM * DD, gate, eid, counts);
    // 7. fused offsets + tiles + scatter
    k_offscatter<<<1, 1024, 0, stream>>>(counts, te, tsx, trx, ntl, eid, fill, perm);
    // 8. act = silu(h2[perm] @ wiT_a) * (h2[perm] @ wiT_g)  — fused epilogue
    k_moe_up<<<dim3(2048 / 64, MAX_TILES), 256, 0, stream>>>(
        h2B, wiT, actB, perm, te, tsx, trx, ntl);
    // 9. out = x2 + gate * (act @ woT[e]^T)
    k_moe_dn<<<dim3(DD / 128, MAX_TILES), 256, 0, stream>>>(
        actB, woT, x2F, out, perm, te, tsx, trx, ntl, gate);
}

// Round 9
// 370.492 us; speedup vs baseline: 1.2629x; 1.0375x over previous
//
#include <hip/hip_runtime.h>
#include <hip/hip_bf16.h>
#include <math.h>

// Problem constants
#define BB 2
#define SS 1024
#define DD 1024
#define FF 4096
#define HH 16
#define EE 8
#define MM (BB*SS)          // 2048 tokens
#define MAX_TILES 24        // sum_e ceil(cnt_e/128) <= 2048/128 + 8

typedef __attribute__((ext_vector_type(8))) short bf16x8;
typedef __attribute__((ext_vector_type(8))) short s16x8;
typedef __attribute__((ext_vector_type(4))) float f32x4;

// ---------------- workspace layout (bytes) ----------------
#define OFF_WIT  ((size_t)0)            // wi^T bf16: 8*4096*1024*2 = 67108864
#define OFF_WOT  ((size_t)67108864)     // wo^T bf16: 33554432
#define OFF_WQH  ((size_t)100663296)    // w_qkv hi bf16 (later: K split hi/lo)
#define OFF_WQL  ((size_t)106954752)    // w_qkv lo bf16
#define OFF_WOH  ((size_t)113246208)    // w_out hi bf16
#define OFF_WOL  ((size_t)115343360)    // w_out lo bf16
#define OFF_H1H  ((size_t)117440512)    // h1 hi bf16 (later: VT hi)
#define OFF_H1L  ((size_t)121634816)    // h1 lo bf16 (later: VT lo)
#define OFF_QKV  ((size_t)125829120)    // qkv f32: 25165824
#define OFF_OH   ((size_t)150994944)    // attn o hi bf16
#define OFF_OL   ((size_t)155189248)    // attn o lo bf16
#define OFF_X2   ((size_t)159383552)    // x2 f32: 8388608
#define OFF_H2B  ((size_t)167772160)    // h2 bf16: 4194304
#define OFF_ACT  ((size_t)171966464)    // act bf16
#define OFF_GATE ((size_t)180879360)
#define OFF_EID  ((size_t)180887552)
#define OFF_PERM ((size_t)180895744)
#define OFF_CNT  ((size_t)180903936)    // 17 ints zeroed by out-proj block 0
#define OFF_FILL ((size_t)180903968)
#define OFF_NT   ((size_t)180904000)
#define OFF_TE   ((size_t)180904192)
#define OFF_TS   ((size_t)180904320)
#define OFF_TR   ((size_t)180904448)
// attention K/V split buffers (reuse dead regions)
#define OFF_KSH  OFF_WQH
#define OFF_KSL  (OFF_WQH + 4194304)
#define OFF_VTH  OFF_H1H
#define OFF_VTL  OFF_H1L

// ---------------- async global->LDS (16B per lane) ----------------
__device__ __forceinline__ void gload16(const void* g, void* l) {
    __builtin_amdgcn_global_load_lds(
        (const __attribute__((address_space(1))) unsigned int*)g,
        (__attribute__((address_space(3))) unsigned int*)l, 16, 0, 0);
}

__device__ __forceinline__ short bfh(float v) {
    __hip_bfloat16 h = __float2bfloat16(v);
    return *(short*)&h;
}
__device__ __forceinline__ float bf2f(short s) {
    __hip_bfloat16 h = *(__hip_bfloat16*)&s;
    return __bfloat162float(h);
}

__device__ __forceinline__ void split_write(float v, __hip_bfloat16* hp, __hip_bfloat16* lp, size_t idx) {
    __hip_bfloat16 h = __float2bfloat16(v);
    hp[idx] = h;
    lp[idx] = __float2bfloat16(v - __bfloat162float(h));
}

// ---------------- transpose-convert body: in (R,C) f32 -> out (C,R) bf16, 64x64 tile ----------------
__device__ __forceinline__ void tcvt64_body(const float* __restrict__ in, __hip_bfloat16* __restrict__ out,
                                            int R, int C, int r0, int c0, float* tile /*64*65*/) {
    int t = threadIdx.x;
    {
        int ri = t >> 2, cj = (t & 3) * 16;
        const float* ip = &in[(size_t)(r0 + ri) * C + c0 + cj];
#pragma unroll
        for (int k = 0; k < 4; ++k) {
            float4 v = *(const float4*)(ip + k * 4);
            tile[ri * 65 + cj + k * 4 + 0] = v.x;
            tile[ri * 65 + cj + k * 4 + 1] = v.y;
            tile[ri * 65 + cj + k * 4 + 2] = v.z;
            tile[ri * 65 + cj + k * 4 + 3] = v.w;
        }
    }
    __syncthreads();
    {
        int co = t >> 2, rj = (t & 3) * 16;
        bf16x8 v8a, v8b;
#pragma unroll
        for (int q = 0; q < 8; ++q) v8a[q] = bfh(tile[(rj + q) * 65 + co]);
#pragma unroll
        for (int q = 0; q < 8; ++q) v8b[q] = bfh(tile[(rj + 8 + q) * 65 + co]);
        __hip_bfloat16* op = &out[(size_t)(c0 + co) * R + r0 + rj];
        *(bf16x8*)op = v8a;
        *(bf16x8*)(op + 8) = v8b;
    }
}

// ---------------- phase-0 mega kernel: LN1+RoPE | w_qkv/w_out split-cvt | wi/wo transpose-cvt ----------------
// blocks [0,2048): LN1+RoPE ; [2048,6144): cvt2 ; [6144,14336): wi tcvt ; [14336,18432): wo tcvt
__global__ void k_phase0(const float* __restrict__ x, const float* __restrict__ ln1w,
                         const float* __restrict__ ln1b,
                         __hip_bfloat16* __restrict__ h1H, __hip_bfloat16* __restrict__ h1L,
                         const float* __restrict__ w_qkv, __hip_bfloat16* __restrict__ wqH,
                         __hip_bfloat16* __restrict__ wqL,
                         const float* __restrict__ w_out, __hip_bfloat16* __restrict__ woH,
                         __hip_bfloat16* __restrict__ woL,
                         const float* __restrict__ wi, __hip_bfloat16* __restrict__ wiT,
                         const float* __restrict__ wo, __hip_bfloat16* __restrict__ woT) {
    __shared__ __align__(16) float smem[64 * 65];
    int bid = blockIdx.x, t = threadIdx.x;
    if (bid < 2048) {
        // ---- LN1 + RoPE -> h1 hi/lo
        int m = bid, s = m & (SS - 1);
        float* row = smem;
        float* red = smem + 1024;
        const float* xp = x + (size_t)m * DD;
        float sum = 0.f, sumsq = 0.f;
#pragma unroll
        for (int l = 0; l < 4; ++l) {
            int i = t + l * 256;
            float v = xp[i];
            row[i] = v;
            sum += v; sumsq += v * v;
        }
#pragma unroll
        for (int off = 32; off; off >>= 1) {
            sum   += __shfl_xor(sum, off);
            sumsq += __shfl_xor(sumsq, off);
        }
        int wid = t >> 6, lane = t & 63;
        if (lane == 0) { red[wid] = sum; red[4 + wid] = sumsq; }
        __syncthreads();
        sum   = red[0] + red[1] + red[2] + red[3];
        sumsq = red[4] + red[5] + red[6] + red[7];
        float mean = sum * (1.f / DD);
        float var  = sumsq * (1.f / DD) - mean * mean;
        float rstd = rsqrtf(var + 1e-5f);
        size_t base = (size_t)m * DD;
        const float kln = logf(10000.f) / 512.f;
#pragma unroll
        for (int l = 0; l < 2; ++l) {
            int i = t + l * 256;   // 0..511
            float n1 = (row[i]       - mean) * rstd * ln1w[i]       + ln1b[i];
            float n2 = (row[i + 512] - mean) * rstd * ln1w[i + 512] + ln1b[i + 512];
            float inv = expf(-(float)i * kln);
            float ang = (float)s * inv;
            float c = cosf(ang), sn = sinf(ang);
            split_write(n1 * c - n2 * sn,  h1H, h1L, base + i);
            split_write(n1 * sn + n2 * c, h1H, h1L, base + i + 512);
        }
    } else if (bid < 6144) {
        // ---- split-convert w_qkv (786432 float4) then w_out (262144 float4)
        int i = (bid - 2048) * 256 + t;
        const float* in; __hip_bfloat16 *hi, *lo; int idx;
        if (i < 786432) { in = w_qkv; hi = wqH; lo = wqL; idx = i; }
        else            { idx = i - 786432; in = w_out; hi = woH; lo = woL; }
        float4 v = ((const float4*)in)[idx];
        split_write(v.x, hi, lo, (size_t)idx * 4 + 0);
        split_write(v.y, hi, lo, (size_t)idx * 4 + 1);
        split_write(v.z, hi, lo, (size_t)idx * 4 + 2);
        split_write(v.w, hi, lo, (size_t)idx * 4 + 3);
    } else if (bid < 14336) {
        // ---- wi (E,1024,4096) -> wiT (E,4096,1024): 16 rtiles x 64 ctiles per expert
        int j = bid - 6144;
        int e = j >> 10, rem = j & 1023;
        int ry = rem >> 6, cx = rem & 63;
        tcvt64_body(wi + (size_t)e * DD * FF, (__hip_bfloat16*)wiT + (size_t)e * DD * FF,
                    1024, 4096, ry * 64, cx * 64, smem);
    } else {
        // ---- wo (E,2048,1024) -> woT (E,1024,2048): 32 rtiles x 16 ctiles per expert
        int j = bid - 14336;
        int e = j >> 9, rem = j & 511;
        int ry = rem >> 4, cx = rem & 15;
        tcvt64_body(wo + (size_t)e * 2048 * 1024, (__hip_bfloat16*)woT + (size_t)e * 2048 * 1024,
                    2048, 1024, ry * 64, cx * 64, smem);
    }
}

// ---------------- split-precision MFMA GEMM: C = A @ Bt^T + bias (+addsrc) ----------------
// MODE 1 block (0,0) additionally zeroes the 17 routing counters (race-free: prior kernel in stream)
template<int MODE>
__global__ void k_mfma_split(const __hip_bfloat16* __restrict__ Ah, const __hip_bfloat16* __restrict__ Al,
                             const __hip_bfloat16* __restrict__ Bh, const __hip_bfloat16* __restrict__ Bl,
                             const float* __restrict__ bias, const float* __restrict__ addsrc,
                             float* __restrict__ Cf, int M, int N, int K, int* __restrict__ zero17) {
    __shared__ __align__(16) short AsH[128 * 32];
    __shared__ __align__(16) short AsL[128 * 32];
    __shared__ __align__(16) short BsH[128 * 32];
    __shared__ __align__(16) short BsL[128 * 32];
    int m0 = blockIdx.y * 128, n0 = blockIdx.x * 128;
    const int t = threadIdx.x;
    if (MODE == 1 && blockIdx.x == 0 && blockIdx.y == 0 && t < 17) zero17[t] = 0;
    const int w = t >> 6, lane = t & 63;
    const int wr = w >> 1, wc = w & 1;
    const int sid = w * 64 + lane;

    f32x4 acc[4][4] = {};

    for (int k0 = 0; k0 < K; k0 += 32) {
#pragma unroll
        for (int j = 0; j < 2; ++j) {
            int id = j * 256 + sid;
            int rrow = id >> 2, sl = id & 3;
            int slog = sl ^ ((rrow >> 1) & 3);
            size_t lbase = (size_t)(j * 256 + w * 64) * 8;
            size_t gaoff = (size_t)(m0 + rrow) * K + k0 + slog * 8;
            gload16(Ah + gaoff, &AsH[lbase]);
            gload16(Al + gaoff, &AsL[lbase]);
            size_t gboff = (size_t)(n0 + rrow) * K + k0 + slog * 8;
            gload16(Bh + gboff, &BsH[lbase]);
            gload16(Bl + gboff, &BsL[lbase]);
        }
        __syncthreads();
        bf16x8 ah[4], al[4], bh[4], bl[4];
#pragma unroll
        for (int i = 0; i < 4; ++i) {
            int ra = wr * 64 + i * 16 + (lane & 15);
            int pa = (lane >> 4) ^ ((ra >> 1) & 3);
            ah[i] = *(const bf16x8*)&AsH[ra * 32 + pa * 8];
            al[i] = *(const bf16x8*)&AsL[ra * 32 + pa * 8];
            int rb = wc * 64 + i * 16 + (lane & 15);
            int pb = (lane >> 4) ^ ((rb >> 1) & 3);
            bh[i] = *(const bf16x8*)&BsH[rb * 32 + pb * 8];
            bl[i] = *(const bf16x8*)&BsL[rb * 32 + pb * 8];
        }
#pragma unroll
        for (int i = 0; i < 4; ++i)
#pragma unroll
            for (int n = 0; n < 4; ++n) {
                acc[i][n] = __builtin_amdgcn_mfma_f32_16x16x32_bf16(ah[i], bh[n], acc[i][n], 0, 0, 0);
                acc[i][n] = __builtin_amdgcn_mfma_f32_16x16x32_bf16(ah[i], bl[n], acc[i][n], 0, 0, 0);
                acc[i][n] = __builtin_amdgcn_mfma_f32_16x16x32_bf16(al[i], bh[n], acc[i][n], 0, 0, 0);
            }
        __syncthreads();
    }

    int cn = n0 + wc * 64 + (lane & 15);
#pragma unroll
    for (int i = 0; i < 4; ++i) {
#pragma unroll
        for (int n = 0; n < 4; ++n) {
            int col = cn + n * 16;
#pragma unroll
            for (int q = 0; q < 4; ++q) {
                int r = wr * 64 + i * 16 + (lane >> 4) * 4 + q;
                float v = acc[i][n][q] + bias[col];
                if (MODE == 1) v += addsrc[(size_t)(m0 + r) * N + col];
                Cf[(size_t)(m0 + r) * N + col] = v;
            }
        }
    }
}

// ---------------- MoE up-proj with interleaved a/g columns + fused silu epilogue ----------------
__global__ void k_moe_up(const __hip_bfloat16* __restrict__ A,     // h2 bf16 (M,1024)
                         const __hip_bfloat16* __restrict__ Bt,    // wiT (E,4096,1024)
                         __hip_bfloat16* __restrict__ act,         // (perm rows, 2048)
                         const int* __restrict__ perm,
                         const int* __restrict__ te, const int* __restrict__ ts,
                         const int* __restrict__ tr, const int* __restrict__ ntl) {
    __shared__ __align__(16) short As[128 * 32];
    __shared__ __align__(16) short Bs[128 * 32];
    __shared__ int permS[128];
    int tile = blockIdx.y;
    if (tile >= *ntl) return;
    int e = te[tile], rs = ts[tile], rows = tr[tile];
    if (threadIdx.x < 128) {
        int r = threadIdx.x;
        permS[r] = (r < rows) ? perm[rs + r] : 0;
    }
    __syncthreads();
    int c0 = blockIdx.x * 64;
    const int t = threadIdx.x;
    const int w = t >> 6, lane = t & 63;
    const int wr = w >> 1, wc = w & 1;
    const int sid = w * 64 + lane;
    const int g = lane >> 4, r16 = lane & 15;

    const __hip_bfloat16* Bp = Bt + (size_t)e * FF * DD;

    f32x4 acc[4][4] = {};

    for (int k0 = 0; k0 < DD; k0 += 32) {
#pragma unroll
        for (int j = 0; j < 2; ++j) {
            int id = j * 256 + sid;
            int rrow = id >> 2, sl = id & 3;
            int slog = sl ^ ((rrow >> 1) & 3);
            size_t lbase = (size_t)(j * 256 + w * 64) * 8;
            gload16(A + (size_t)permS[rrow] * DD + k0 + slog * 8, &As[lbase]);
            int q = rrow >> 4, rr = rrow & 15;
            int wrow = c0 + (q >> 2) * 32 + ((q & 3) >> 1) * 16 + rr + (q & 1) * 2048;
            gload16(Bp + (size_t)wrow * DD + k0 + slog * 8, &Bs[lbase]);
        }
        __syncthreads();
        bf16x8 af[4], bfr[4];
#pragma unroll
        for (int i = 0; i < 4; ++i) {
            int ra = wr * 64 + i * 16 + r16;
            int pa = g ^ ((ra >> 1) & 3);
            af[i] = *(const bf16x8*)&As[ra * 32 + pa * 8];
            int rb = wc * 64 + i * 16 + r16;
            int pb = g ^ ((rb >> 1) & 3);
            bfr[i] = *(const bf16x8*)&Bs[rb * 32 + pb * 8];
        }
#pragma unroll
        for (int i = 0; i < 4; ++i)
#pragma unroll
            for (int n = 0; n < 4; ++n)
                acc[i][n] = __builtin_amdgcn_mfma_f32_16x16x32_bf16(af[i], bfr[n], acc[i][n], 0, 0, 0);
        __syncthreads();
    }

#pragma unroll
    for (int i = 0; i < 4; ++i) {
#pragma unroll
        for (int p2 = 0; p2 < 2; ++p2) {
            int col = c0 + wc * 32 + p2 * 16 + r16;
#pragma unroll
            for (int q = 0; q < 4; ++q) {
                int r = wr * 64 + i * 16 + g * 4 + q;
                if (r < rows) {
                    float a  = acc[i][2 * p2][q];
                    float gv = acc[i][2 * p2 + 1][q];
                    act[(size_t)(rs + r) * 2048 + col] =
                        __float2bfloat16((a / (1.f + expf(-a))) * gv);
                }
            }
        }
    }
}

// ---------------- MoE down-proj: out = x2 + gate * (act @ woT[e]^T) ----------------
__global__ void k_moe_dn(const __hip_bfloat16* __restrict__ A,
                         const __hip_bfloat16* __restrict__ Bt,
                         const float* __restrict__ addsrc, float* __restrict__ Cf,
                         const int* __restrict__ perm,
                         const int* __restrict__ te, const int* __restrict__ ts,
                         const int* __restrict__ tr, const int* __restrict__ ntl,
                         const float* __restrict__ gate) {
    __shared__ __align__(16) short As[128 * 32];
    __shared__ __align__(16) short Bs[128 * 32];
    __shared__ int permS[128];
    int tile = blockIdx.y;
    if (tile >= *ntl) return;
    int e = te[tile], rs = ts[tile], rows = tr[tile];
    if (threadIdx.x < 128) {
        int r = threadIdx.x;
        permS[r] = (r < rows) ? perm[rs + r] : 0;
    }
    __syncthreads();
    int n0 = blockIdx.x * 128;
    const int t = threadIdx.x;
    const int w = t >> 6, lane = t & 63;
    const int wr = w >> 1, wc = w & 1;
    const int sid = w * 64 + lane;
    const int K = FF / 2;

    const __hip_bfloat16* Bp = Bt + (size_t)e * DD * (FF / 2);

    f32x4 acc[4][4] = {};

    for (int k0 = 0; k0 < K; k0 += 32) {
#pragma unroll
        for (int j = 0; j < 2; ++j) {
            int id = j * 256 + sid;
            int rrow = id >> 2, sl = id & 3;
            int slog = sl ^ ((rrow >> 1) & 3);
            size_t lbase = (size_t)(j * 256 + w * 64) * 8;
            gload16(A + (size_t)(rs + rrow) * K + k0 + slog * 8, &As[lbase]);
            gload16(Bp + (size_t)(n0 + rrow) * K + k0 + slog * 8, &Bs[lbase]);
        }
        __syncthreads();
        bf16x8 af[4], bfr[4];
#pragma unroll
        for (int i = 0; i < 4; ++i) {
            int ra = wr * 64 + i * 16 + (lane & 15);
            int pa = (lane >> 4) ^ ((ra >> 1) & 3);
            af[i] = *(const bf16x8*)&As[ra * 32 + pa * 8];
            int rb = wc * 64 + i * 16 + (lane & 15);
            int pb = (lane >> 4) ^ ((rb >> 1) & 3);
            bfr[i] = *(const bf16x8*)&Bs[rb * 32 + pb * 8];
        }
#pragma unroll
        for (int i = 0; i < 4; ++i)
#pragma unroll
            for (int n = 0; n < 4; ++n)
                acc[i][n] = __builtin_amdgcn_mfma_f32_16x16x32_bf16(af[i], bfr[n], acc[i][n], 0, 0, 0);
        __syncthreads();
    }

    int cn = n0 + wc * 64 + (lane & 15);
#pragma unroll
    for (int i = 0; i < 4; ++i) {
#pragma unroll
        for (int n = 0; n < 4; ++n) {
            int col = cn + n * 16;
#pragma unroll
            for (int q = 0; q < 4; ++q) {
                int r = wr * 64 + i * 16 + (lane >> 4) * 4 + q;
                if (r >= rows) continue;
                int tok = permS[r];
                Cf[(size_t)tok * DD + col] = addsrc[(size_t)tok * DD + col] + gate[tok] * acc[i][n][q];
            }
        }
    }
}

// ---------------- attention prep: split K -> [b,h,s,d] swz, V^T -> [b,h,d,s] swz ----------------
__global__ void k_prep(const float* __restrict__ qkv, short* __restrict__ KH, short* __restrict__ KL,
                       short* __restrict__ VH, short* __restrict__ VL) {
    __shared__ float tile[64][65];
    int b = blockIdx.z, h = blockIdx.y, s0 = blockIdx.x * 64;
    int t = threadIdx.x;
    int row = t >> 2, c0 = (t & 3) * 16;
    const float* kp = qkv + (size_t)(b * SS + s0 + row) * 3072 + 1024 + h * 64 + c0;
    const float* vp = kp + 1024;
    {
        size_t krow = ((size_t)(b * HH + h) * SS + s0 + row) * 64;
        int key = (s0 + row) & 7;
#pragma unroll
        for (int g2 = 0; g2 < 2; ++g2) {
            s16x8 hv, lv;
#pragma unroll
            for (int j = 0; j < 8; ++j) {
                float v = kp[g2 * 8 + j];
                short hh = bfh(v);
                hv[j] = hh; lv[j] = bfh(v - bf2f(hh));
            }
            int p = ((c0 >> 3) + g2) ^ key;
            *(s16x8*)&KH[krow + p * 8] = hv;
            *(s16x8*)&KL[krow + p * 8] = lv;
        }
    }
#pragma unroll
    for (int j = 0; j < 16; ++j) tile[row][c0 + j] = vp[j];
    __syncthreads();
    {
        int d = t >> 2, sc = (t & 3) * 16;
        size_t vrow = ((size_t)(b * HH + h) * 64 + d) * SS + s0;
        int key = d & 7;
#pragma unroll
        for (int g2 = 0; g2 < 2; ++g2) {
            s16x8 hv, lv;
#pragma unroll
            for (int j = 0; j < 8; ++j) {
                float v = tile[sc + g2 * 8 + j][d];
                short hh = bfh(v);
                hv[j] = hh; lv[j] = bfh(v - bf2f(hh));
            }
            int p = ((sc >> 3) + g2) ^ key;
            *(s16x8*)&VH[vrow + p * 8] = hv;
            *(s16x8*)&VL[vrow + p * 8] = lv;
        }
    }
}

// ---------------- MFMA flash attention, split precision, dbuf, 8 waves x 16 q-rows (QB=128),
// 1D XCD-swizzled grid: 256 blocks, id&7 = XCD, 4 (b,h) per XCD (2MB K/V < 4MB L2) ----------------
#define LDP 72
__global__ __launch_bounds__(512, 1)
void k_attn_mfma(const float* __restrict__ qkv,
                 const short* __restrict__ KH, const short* __restrict__ KL,
                 const short* __restrict__ VH, const short* __restrict__ VL,
                 __hip_bfloat16* __restrict__ ohi, __hip_bfloat16* __restrict__ olo) {
    __shared__ __align__(16) short Ks[2][64 * 64], Kl2[2][64 * 64], Vs[2][64 * 64], Vl2[2][64 * 64];
    __shared__ __align__(16) short PhS[8][16 * LDP], PlS[8][16 * LDP];
    int id = blockIdx.x;
    int xcd = id & 7, slot = id >> 3;        // 32 slots per XCD
    int bh = xcd * 4 + (slot >> 3);          // 4 (b,h) groups per XCD
    int q0 = (slot & 7) * 128;               // 8 q-tiles per (b,h)
    int b = bh >> 4, h = bh & 15;
    int t = threadIdx.x;
    int w = t >> 6, lane = t & 63;
    int g = lane >> 4, r16 = lane & 15;
    int srow = t >> 3, sslot = t & 7;

    const size_t kbase = ((size_t)bh * SS) * 64;
    const size_t vbase = ((size_t)bh * 64) * SS;

    // ---- Q fragments direct from f32 qkv, prescale 1/8, split in-reg
    bf16x8 qfh[2], qfl[2];
    {
        const float* qp = qkv + (size_t)(b * SS + q0 + w * 16 + r16) * 3072 + h * 64;
#pragma unroll
        for (int ks = 0; ks < 2; ++ks) {
            float vv[8];
            *(float4*)&vv[0] = *(const float4*)(qp + ks * 32 + g * 8);
            *(float4*)&vv[4] = *(const float4*)(qp + ks * 32 + g * 8 + 4);
#pragma unroll
            for (int j = 0; j < 8; ++j) {
                float sv = vv[j] * 0.125f;
                short hh = bfh(sv);
                qfh[ks][j] = hh;
                qfl[ks][j] = bfh(sv - bf2f(hh));
            }
        }
    }

    float mrun[4], lrun[4];
    f32x4 oacc[4] = {};
#pragma unroll
    for (int q = 0; q < 4; ++q) { mrun[q] = -1e30f; lrun[q] = 0.f; }

    // prologue: stage tile 0 into buf 0
    gload16(KH + kbase + (size_t)srow * 64 + sslot * 8, &Ks[0][w * 512]);
    gload16(KL + kbase + (size_t)srow * 64 + sslot * 8, &Kl2[0][w * 512]);
    gload16(VH + vbase + (size_t)srow * SS + sslot * 8, &Vs[0][w * 512]);
    gload16(VL + vbase + (size_t)srow * SS + sslot * 8, &Vl2[0][w * 512]);
    __syncthreads();

    int cur = 0;
    for (int k0 = 0; k0 < SS; k0 += 64) {
        // ---- prefetch next tile into alternate buffer
        if (k0 + 64 < SS) {
            int kn = k0 + 64;
            gload16(KH + kbase + (size_t)(kn + srow) * 64 + sslot * 8, &Ks[cur ^ 1][w * 512]);
            gload16(KL + kbase + (size_t)(kn + srow) * 64 + sslot * 8, &Kl2[cur ^ 1][w * 512]);
            gload16(VH + vbase + (size_t)srow * SS + kn + sslot * 8,   &Vs[cur ^ 1][w * 512]);
            gload16(VL + vbase + (size_t)srow * SS + kn + sslot * 8,   &Vl2[cur ^ 1][w * 512]);
        }

        // ---- S = Q K^T (split, 3 MFMA per fragment)
        f32x4 accs[4] = {};
#pragma unroll
        for (int ks = 0; ks < 2; ++ks) {
            bf16x8 kfh[4], kfl[4];
#pragma unroll
            for (int n = 0; n < 4; ++n) {
                int rb = n * 16 + r16;
                int p = (ks * 4 + g) ^ (r16 & 7);
                kfh[n] = *(const bf16x8*)&Ks[cur][rb * 64 + p * 8];
                kfl[n] = *(const bf16x8*)&Kl2[cur][rb * 64 + p * 8];
            }
            __builtin_amdgcn_s_setprio(1);
#pragma unroll
            for (int n = 0; n < 4; ++n) {
                accs[n] = __builtin_amdgcn_mfma_f32_16x16x32_bf16(qfh[ks], kfh[n], accs[n], 0, 0, 0);
                accs[n] = __builtin_amdgcn_mfma_f32_16x16x32_bf16(qfh[ks], kfl[n], accs[n], 0, 0, 0);
                accs[n] = __builtin_amdgcn_mfma_f32_16x16x32_bf16(qfl[ks], kfh[n], accs[n], 0, 0, 0);
            }
            __builtin_amdgcn_s_setprio(0);
        }

        // ---- online softmax
        float mn[4], corr[4], psum[4];
#pragma unroll
        for (int q = 0; q < 4; ++q) {
            float m = fmaxf(fmaxf(accs[0][q], accs[1][q]), fmaxf(accs[2][q], accs[3][q]));
            m = fmaxf(m, __shfl_xor(m, 1));
            m = fmaxf(m, __shfl_xor(m, 2));
            m = fmaxf(m, __shfl_xor(m, 4));
            m = fmaxf(m, __shfl_xor(m, 8));
            mn[q] = fmaxf(mrun[q], m);
            corr[q] = expf(mrun[q] - mn[q]);
            mrun[q] = mn[q];
            psum[q] = 0.f;
        }
#pragma unroll
        for (int n = 0; n < 4; ++n)
#pragma unroll
            for (int q = 0; q < 4; ++q) {
                float p = expf(accs[n][q] - mn[q]);
                psum[q] += p;
                short ph = bfh(p);
                PhS[w][(g * 4 + q) * LDP + n * 16 + r16] = ph;
                PlS[w][(g * 4 + q) * LDP + n * 16 + r16] = bfh(p - bf2f(ph));
            }
#pragma unroll
        for (int q = 0; q < 4; ++q) {
            psum[q] += __shfl_xor(psum[q], 1);
            psum[q] += __shfl_xor(psum[q], 2);
            psum[q] += __shfl_xor(psum[q], 4);
            psum[q] += __shfl_xor(psum[q], 8);
            lrun[q] = lrun[q] * corr[q] + psum[q];
#pragma unroll
            for (int n = 0; n < 4; ++n) oacc[n][q] *= corr[q];
        }

        // ---- O += P V (split)
#pragma unroll
        for (int ks = 0; ks < 2; ++ks) {
            bf16x8 vfh[4], vfl[4];
#pragma unroll
            for (int n = 0; n < 4; ++n) {
                int rb = n * 16 + r16;
                int p = (ks * 4 + g) ^ (r16 & 7);
                vfh[n] = *(const bf16x8*)&Vs[cur][rb * 64 + p * 8];
                vfl[n] = *(const bf16x8*)&Vl2[cur][rb * 64 + p * 8];
            }
            bf16x8 pfh = *(const bf16x8*)&PhS[w][r16 * LDP + ks * 32 + g * 8];
            bf16x8 pfl = *(const bf16x8*)&PlS[w][r16 * LDP + ks * 32 + g * 8];
            __builtin_amdgcn_s_setprio(1);
#pragma unroll
            for (int n = 0; n < 4; ++n) {
                oacc[n] = __builtin_amdgcn_mfma_f32_16x16x32_bf16(pfh, vfh[n], oacc[n], 0, 0, 0);
                oacc[n] = __builtin_amdgcn_mfma_f32_16x16x32_bf16(pfh, vfl[n], oacc[n], 0, 0, 0);
                oacc[n] = __builtin_amdgcn_mfma_f32_16x16x32_bf16(pfl, vfh[n], oacc[n], 0, 0, 0);
            }
            __builtin_amdgcn_s_setprio(0);
        }
        __syncthreads();   // drains prefetch vmcnt + barriers buffer reuse
        cur ^= 1;
    }

    // ---- epilogue
    float invl[4];
#pragma unroll
    for (int q = 0; q < 4; ++q) invl[q] = 1.f / lrun[q];
#pragma unroll
    for (int n = 0; n < 4; ++n) {
        int col = h * 64 + n * 16 + r16;
#pragma unroll
        for (int q = 0; q < 4; ++q) {
            int rowg = b * SS + q0 + w * 16 + g * 4 + q;
            split_write(oacc[n][q] * invl[q], ohi, olo, (size_t)rowg * DD + col);
        }
    }
}

// ---------------- fused LN2 + router: h2 bf16 out, logits/gate/eid/counts ----------------
__global__ void k_ln2_router(const float* __restrict__ x2, const float* __restrict__ w,
                             const float* __restrict__ b, const float* __restrict__ wr,
                             __hip_bfloat16* __restrict__ h2b, float* __restrict__ logits,
                             float* __restrict__ gate, int* __restrict__ eid,
                             int* __restrict__ counts) {
    int m = blockIdx.x, t = threadIdx.x;
    __shared__ float red[8];
    __shared__ float racc[4][8];
    const float* xp = x2 + (size_t)m * DD;
    float v[4];
    float sum = 0.f, sumsq = 0.f;
#pragma unroll
    for (int l = 0; l < 4; ++l) {
        v[l] = xp[t + l * 256];
        sum += v[l]; sumsq += v[l] * v[l];
    }
#pragma unroll
    for (int off = 32; off; off >>= 1) {
        sum   += __shfl_xor(sum, off);
        sumsq += __shfl_xor(sumsq, off);
    }
    int wid = t >> 6, lane = t & 63;
    if (lane == 0) { red[wid] = sum; red[4 + wid] = sumsq; }
    __syncthreads();
    sum   = red[0] + red[1] + red[2] + red[3];
    sumsq = red[4] + red[5] + red[6] + red[7];
    float mean = sum * (1.f / DD);
    float var  = sumsq * (1.f / DD) - mean * mean;
    float rstd = rsqrtf(var + 1e-5f);
    float acc[EE] = {};
#pragma unroll
    for (int l = 0; l < 4; ++l) {
        int i = t + l * 256;
        float hv = (v[l] - mean) * rstd * w[i] + b[i];
        h2b[(size_t)m * DD + i] = __float2bfloat16(hv);
        const float* wp = wr + (size_t)i * EE;
#pragma unroll
        for (int n = 0; n < EE; ++n) acc[n] += hv * wp[n];
    }
#pragma unroll
    for (int off = 32; off; off >>= 1)
#pragma unroll
        for (int n = 0; n < EE; ++n) acc[n] += __shfl_xor(acc[n], off);
    if (lane == 0)
#pragma unroll
        for (int n = 0; n < EE; ++n) racc[wid][n] = acc[n];
    __syncthreads();
    if (t == 0) {
        float lg[EE];
#pragma unroll
        for (int n = 0; n < EE; ++n) lg[n] = racc[0][n] + racc[1][n] + racc[2][n] + racc[3][n];
        float mx = lg[0]; int best = 0;
#pragma unroll
        for (int n = 1; n < EE; ++n) if (lg[n] > mx) { mx = lg[n]; best = n; }
        float den = 0.f;
#pragma unroll
        for (int n = 0; n < EE; ++n) den += expf(lg[n] - mx);
        gate[m] = 1.f / den;
        eid[m] = best;
        atomicAdd(&counts[best], 1);
#pragma unroll
        for (int n = 0; n < EE; ++n) logits[(size_t)m * EE + n] = lg[n];
    }
}

// ---------------- fused routing bookkeeping: offsets + tiles + scatter (1 block) ----------------
__global__ void k_offscatter(const int* __restrict__ counts,
                             int* __restrict__ te, int* __restrict__ ts, int* __restrict__ tr,
                             int* __restrict__ ntl, const int* __restrict__ eid,
                             int* __restrict__ fill, int* __restrict__ perm) {
    __shared__ int soffs[EE];
    int t = threadIdx.x;
    if (t == 0) {
        int off = 0, nt = 0;
        for (int e = 0; e < EE; ++e) {
            soffs[e] = off;
            int c = counts[e];
            for (int t0 = 0; t0 < c; t0 += 128) {
                te[nt] = e; ts[nt] = off + t0; tr[nt] = (c - t0 < 128) ? (c - t0) : 128; ++nt;
            }
            off += c;
        }
        *ntl = nt;
    }
    __syncthreads();
#pragma unroll
    for (int tok = t; tok < MM; tok += 1024) {
        int e = eid[tok];
        int pos = soffs[e] + atomicAdd(&fill[e], 1);
        perm[pos] = tok;
    }
}

// ---------------- launch ----------------
extern "C" void kernel_launch(void* const* d_in, const int* in_sizes, int n_in,
                              void* d_out, int out_size, void* d_ws, size_t ws_size,
                              hipStream_t stream) {
    const float* x     = (const float*)d_in[0];
    const float* ln1w  = (const float*)d_in[1];
    const float* ln1b  = (const float*)d_in[2];
    const float* ln2w  = (const float*)d_in[3];
    const float* ln2b  = (const float*)d_in[4];
    const float* w_qkv = (const float*)d_in[5];
    const float* b_qkv = (const float*)d_in[6];
    const float* w_out = (const float*)d_in[7];
    const float* b_out = (const float*)d_in[8];
    const float* w_rtr = (const float*)d_in[9];
    const float* wi    = (const float*)d_in[10];
    const float* wo    = (const float*)d_in[11];
    float* out = (float*)d_out;

    char* wsb = (char*)d_ws;
    __hip_bfloat16* wiT  = (__hip_bfloat16*)(wsb + OFF_WIT);
    __hip_bfloat16* woT  = (__hip_bfloat16*)(wsb + OFF_WOT);
    __hip_bfloat16* wqH  = (__hip_bfloat16*)(wsb + OFF_WQH);
    __hip_bfloat16* wqL  = (__hip_bfloat16*)(wsb + OFF_WQL);
    __hip_bfloat16* woH  = (__hip_bfloat16*)(wsb + OFF_WOH);
    __hip_bfloat16* woL  = (__hip_bfloat16*)(wsb + OFF_WOL);
    __hip_bfloat16* h1H  = (__hip_bfloat16*)(wsb + OFF_H1H);
    __hip_bfloat16* h1L  = (__hip_bfloat16*)(wsb + OFF_H1L);
    float*          qkvF = (float*)(wsb + OFF_QKV);
    __hip_bfloat16* oH   = (__hip_bfloat16*)(wsb + OFF_OH);
    __hip_bfloat16* oL   = (__hip_bfloat16*)(wsb + OFF_OL);
    float*          x2F  = (float*)(wsb + OFF_X2);
    __hip_bfloat16* h2B  = (__hip_bfloat16*)(wsb + OFF_H2B);
    __hip_bfloat16* actB = (__hip_bfloat16*)(wsb + OFF_ACT);
    short* KSH = (short*)(wsb + OFF_KSH);
    short* KSL = (short*)(wsb + OFF_KSL);
    short* VTH = (short*)(wsb + OFF_VTH);
    short* VTL = (short*)(wsb + OFF_VTL);
    float* gate = (float*)(wsb + OFF_GATE);
    int* eid    = (int*)(wsb + OFF_EID);
    int* perm   = (int*)(wsb + OFF_PERM);
    int* counts = (int*)(wsb + OFF_CNT);
    int* fill   = (int*)(wsb + OFF_FILL);
    int* ntl    = (int*)(wsb + OFF_NT);
    int* te     = (int*)(wsb + OFF_TE);
    int* tsx    = (int*)(wsb + OFF_TS);
    int* trx    = (int*)(wsb + OFF_TR);

    // 1. phase-0: LN1+RoPE | weight split-cvt | wi/wo transpose-cvt (one launch)
    k_phase0<<<18432, 256, 0, stream>>>(x, ln1w, ln1b, h1H, h1L,
                                        w_qkv, wqH, wqL, w_out, woH, woL,
                                        wi, wiT, wo, woT);
    // 2. qkv = h1 @ w_qkv^T + b_qkv (split precision, f32 out)
    k_mfma_split<0><<<dim3(3072 / 128, MM / 128), 256, 0, stream>>>(
        h1H, h1L, wqH, wqL, b_qkv, nullptr, qkvF, MM, 3072, DD, nullptr);
    // 3. prep: split K + transposed V (overwrites dead wq/h1 regions)
    k_prep<<<dim3(SS / 64, HH, BB), 256, 0, stream>>>(qkvF, KSH, KSL, VTH, VTL);
    // 4. attention (split-precision MFMA, dbuf, XCD-swizzled 256 blocks)
    k_attn_mfma<<<256, 512, 0, stream>>>(qkvF, KSH, KSL, VTH, VTL, oH, oL);
    // 5. x2 = x + o @ w_out^T + b_out (split precision); block 0 zeroes routing counters
    k_mfma_split<1><<<dim3(DD / 128, MM / 128), 256, 0, stream>>>(
        oH, oL, woH, woL, b_out, x, x2F, MM, DD, DD, counts);
    // 6. LN2 + router fused (h2 bf16 + exact f32 logits/argmax)
    k_ln2_router<<<MM, 256, 0, stream>>>(x2F, ln2w, ln2b, w_rtr, h2B,
                                         out + (size_t)MM * DD, gate, eid, counts);
    // 7. fused offsets + tiles + scatter
    k_offscatter<<<1, 1024, 0, stream>>>(counts, te, tsx, trx, ntl, eid, fill, perm);
    // 8. act = silu(h2[perm] @ wiT_a) * (h2[perm] @ wiT_g)
    k_moe_up<<<dim3(2048 / 64, MAX_TILES), 256, 0, stream>>>(
        h2B, wiT, actB, perm, te, tsx, trx, ntl);
    // 9. out = x2 + gate * (act @ woT[e]^T)
    k_moe_dn<<<dim3(DD / 128, MAX_TILES), 256, 0, stream>>>(
        actB, woT, x2F, out, perm, te, tsx, trx, ntl, gate);
}

// Round 10
// 334.882 us; speedup vs baseline: 1.3972x; 1.1063x over previous
//
#include <hip/hip_runtime.h>
#include <hip/hip_bf16.h>
#include <math.h>

// Problem constants
#define BB 2
#define SS 1024
#define DD 1024
#define FF 4096
#define HH 16
#define EE 8
#define MM (BB*SS)          // 2048 tokens
#define MAX_TILES 24        // sum_e ceil(cnt_e/128) <= 2048/128 + 8

typedef __attribute__((ext_vector_type(8))) short bf16x8;
typedef __attribute__((ext_vector_type(8))) short s16x8;
typedef __attribute__((ext_vector_type(4))) float f32x4;

// ---------------- workspace layout (bytes) ----------------
#define OFF_WIT  ((size_t)0)            // wi^T bf16: 8*4096*1024*2 = 67108864
#define OFF_WOT  ((size_t)67108864)     // wo^T bf16: 33554432
#define OFF_WQH  ((size_t)100663296)    // w_qkv hi bf16 (later: K split hi/lo)
#define OFF_WQL  ((size_t)106954752)    // w_qkv lo bf16
#define OFF_WOH  ((size_t)113246208)    // w_out hi bf16
#define OFF_WOL  ((size_t)115343360)    // w_out lo bf16
#define OFF_H1H  ((size_t)117440512)    // h1 hi bf16 (later: VT hi)
#define OFF_H1L  ((size_t)121634816)    // h1 lo bf16 (later: VT lo)
#define OFF_QKV  ((size_t)125829120)    // qkv f32: 25165824
#define OFF_OH   ((size_t)150994944)    // attn o hi bf16
#define OFF_OL   ((size_t)155189248)    // attn o lo bf16
#define OFF_X2   ((size_t)159383552)    // x2 f32: 8388608
#define OFF_H2B  ((size_t)167772160)    // h2 bf16: 4194304
#define OFF_ACT  ((size_t)171966464)    // act bf16
#define OFF_GATE ((size_t)180879360)
#define OFF_EID  ((size_t)180887552)
#define OFF_PERM ((size_t)180895744)
#define OFF_CNT  ((size_t)180903936)    // 17 ints zeroed by out-proj block 0
#define OFF_FILL ((size_t)180903968)
#define OFF_NT   ((size_t)180904000)
#define OFF_TE   ((size_t)180904192)
#define OFF_TS   ((size_t)180904320)
#define OFF_TR   ((size_t)180904448)
// attention K/V split buffers (reuse dead regions)
#define OFF_KSH  OFF_WQH
#define OFF_KSL  (OFF_WQH + 4194304)
#define OFF_VTH  OFF_H1H
#define OFF_VTL  OFF_H1L

// ---------------- async global->LDS (16B per lane) ----------------
__device__ __forceinline__ void gload16(const void* g, void* l) {
    __builtin_amdgcn_global_load_lds(
        (const __attribute__((address_space(1))) unsigned int*)g,
        (__attribute__((address_space(3))) unsigned int*)l, 16, 0, 0);
}

__device__ __forceinline__ short bfh(float v) {
    __hip_bfloat16 h = __float2bfloat16(v);
    return *(short*)&h;
}
__device__ __forceinline__ float bf2f(short s) {
    __hip_bfloat16 h = *(__hip_bfloat16*)&s;
    return __bfloat162float(h);
}

__device__ __forceinline__ void split_write(float v, __hip_bfloat16* hp, __hip_bfloat16* lp, size_t idx) {
    __hip_bfloat16 h = __float2bfloat16(v);
    hp[idx] = h;
    lp[idx] = __float2bfloat16(v - __bfloat162float(h));
}

// ---------------- transpose-convert body: in (R,C) f32 -> out (C,R) bf16, 64x64 tile ----------------
__device__ __forceinline__ void tcvt64_body(const float* __restrict__ in, __hip_bfloat16* __restrict__ out,
                                            int R, int C, int r0, int c0, float* tile /*64*65*/) {
    int t = threadIdx.x;
    {
        int ri = t >> 2, cj = (t & 3) * 16;
        const float* ip = &in[(size_t)(r0 + ri) * C + c0 + cj];
#pragma unroll
        for (int k = 0; k < 4; ++k) {
            float4 v = *(const float4*)(ip + k * 4);
            tile[ri * 65 + cj + k * 4 + 0] = v.x;
            tile[ri * 65 + cj + k * 4 + 1] = v.y;
            tile[ri * 65 + cj + k * 4 + 2] = v.z;
            tile[ri * 65 + cj + k * 4 + 3] = v.w;
        }
    }
    __syncthreads();
    {
        int co = t >> 2, rj = (t & 3) * 16;
        bf16x8 v8a, v8b;
#pragma unroll
        for (int q = 0; q < 8; ++q) v8a[q] = bfh(tile[(rj + q) * 65 + co]);
#pragma unroll
        for (int q = 0; q < 8; ++q) v8b[q] = bfh(tile[(rj + 8 + q) * 65 + co]);
        __hip_bfloat16* op = &out[(size_t)(c0 + co) * R + r0 + rj];
        *(bf16x8*)op = v8a;
        *(bf16x8*)(op + 8) = v8b;
    }
}

// ---------------- slim phase-0: LN1+RoPE [0,2048) | w_qkv split-cvt [2048,5120) ----------------
__global__ void k_phase0(const float* __restrict__ x, const float* __restrict__ ln1w,
                         const float* __restrict__ ln1b,
                         __hip_bfloat16* __restrict__ h1H, __hip_bfloat16* __restrict__ h1L,
                         const float* __restrict__ w_qkv, __hip_bfloat16* __restrict__ wqH,
                         __hip_bfloat16* __restrict__ wqL) {
    __shared__ __align__(16) float smem[1032];
    int bid = blockIdx.x, t = threadIdx.x;
    if (bid < 2048) {
        int m = bid, s = m & (SS - 1);
        float* row = smem;
        float* red = smem + 1024;
        const float* xp = x + (size_t)m * DD;
        float sum = 0.f, sumsq = 0.f;
#pragma unroll
        for (int l = 0; l < 4; ++l) {
            int i = t + l * 256;
            float v = xp[i];
            row[i] = v;
            sum += v; sumsq += v * v;
        }
#pragma unroll
        for (int off = 32; off; off >>= 1) {
            sum   += __shfl_xor(sum, off);
            sumsq += __shfl_xor(sumsq, off);
        }
        int wid = t >> 6, lane = t & 63;
        if (lane == 0) { red[wid] = sum; red[4 + wid] = sumsq; }
        __syncthreads();
        sum   = red[0] + red[1] + red[2] + red[3];
        sumsq = red[4] + red[5] + red[6] + red[7];
        float mean = sum * (1.f / DD);
        float var  = sumsq * (1.f / DD) - mean * mean;
        float rstd = rsqrtf(var + 1e-5f);
        size_t base = (size_t)m * DD;
        const float kln = logf(10000.f) / 512.f;
#pragma unroll
        for (int l = 0; l < 2; ++l) {
            int i = t + l * 256;   // 0..511
            float n1 = (row[i]       - mean) * rstd * ln1w[i]       + ln1b[i];
            float n2 = (row[i + 512] - mean) * rstd * ln1w[i + 512] + ln1b[i + 512];
            float inv = expf(-(float)i * kln);
            float ang = (float)s * inv;
            float c = cosf(ang), sn = sinf(ang);
            split_write(n1 * c - n2 * sn,  h1H, h1L, base + i);
            split_write(n1 * sn + n2 * c, h1H, h1L, base + i + 512);
        }
    } else {
        int idx = (bid - 2048) * 256 + t;        // 786432 float4
        float4 v = ((const float4*)w_qkv)[idx];
        split_write(v.x, wqH, wqL, (size_t)idx * 4 + 0);
        split_write(v.y, wqH, wqL, (size_t)idx * 4 + 1);
        split_write(v.z, wqH, wqL, (size_t)idx * 4 + 2);
        split_write(v.w, wqH, wqL, (size_t)idx * 4 + 3);
    }
}

// ---------------- qkv mega-kernel: split GEMM [0,384) | wi tcvt [384,8576) |
// wo tcvt [8576,12672) | w_out split-cvt [12672,13696) ----------------
// GEMM: qkv = h1 @ w_qkv^T + b_qkv (3 MFMA split). The memory blocks ride the
// GEMM's idle HBM bandwidth; everything they produce is needed only at later dispatches.
__global__ void k_qkv_mega(const __hip_bfloat16* __restrict__ Ah, const __hip_bfloat16* __restrict__ Al,
                           const __hip_bfloat16* __restrict__ Bh, const __hip_bfloat16* __restrict__ Bl,
                           const float* __restrict__ bias, float* __restrict__ Cf,
                           const float* __restrict__ wi, __hip_bfloat16* __restrict__ wiT,
                           const float* __restrict__ wo, __hip_bfloat16* __restrict__ woT,
                           const float* __restrict__ w_out, __hip_bfloat16* __restrict__ woH,
                           __hip_bfloat16* __restrict__ woL) {
    __shared__ __align__(16) char smem[32768];
    int bid = blockIdx.x;
    const int t = threadIdx.x;
    if (bid < 384) {
        const int N = 3072, K = DD;
        short* AsH = (short*)smem;              // 128*32
        short* AsL = (short*)(smem + 8192);
        short* BsH = (short*)(smem + 16384);
        short* BsL = (short*)(smem + 24576);
        int n0 = (bid % 24) * 128, m0 = (bid / 24) * 128;
        const int w = t >> 6, lane = t & 63;
        const int wr = w >> 1, wc = w & 1;
        const int sid = w * 64 + lane;

        f32x4 acc[4][4] = {};

        for (int k0 = 0; k0 < K; k0 += 32) {
#pragma unroll
            for (int j = 0; j < 2; ++j) {
                int id = j * 256 + sid;
                int rrow = id >> 2, sl = id & 3;
                int slog = sl ^ ((rrow >> 1) & 3);
                size_t lbase = (size_t)(j * 256 + w * 64) * 8;
                size_t gaoff = (size_t)(m0 + rrow) * K + k0 + slog * 8;
                gload16(Ah + gaoff, &AsH[lbase]);
                gload16(Al + gaoff, &AsL[lbase]);
                size_t gboff = (size_t)(n0 + rrow) * K + k0 + slog * 8;
                gload16(Bh + gboff, &BsH[lbase]);
                gload16(Bl + gboff, &BsL[lbase]);
            }
            __syncthreads();
            bf16x8 ah[4], al[4], bh[4], bl[4];
#pragma unroll
            for (int i = 0; i < 4; ++i) {
                int ra = wr * 64 + i * 16 + (lane & 15);
                int pa = (lane >> 4) ^ ((ra >> 1) & 3);
                ah[i] = *(const bf16x8*)&AsH[ra * 32 + pa * 8];
                al[i] = *(const bf16x8*)&AsL[ra * 32 + pa * 8];
                int rb = wc * 64 + i * 16 + (lane & 15);
                int pb = (lane >> 4) ^ ((rb >> 1) & 3);
                bh[i] = *(const bf16x8*)&BsH[rb * 32 + pb * 8];
                bl[i] = *(const bf16x8*)&BsL[rb * 32 + pb * 8];
            }
#pragma unroll
            for (int i = 0; i < 4; ++i)
#pragma unroll
                for (int n = 0; n < 4; ++n) {
                    acc[i][n] = __builtin_amdgcn_mfma_f32_16x16x32_bf16(ah[i], bh[n], acc[i][n], 0, 0, 0);
                    acc[i][n] = __builtin_amdgcn_mfma_f32_16x16x32_bf16(ah[i], bl[n], acc[i][n], 0, 0, 0);
                    acc[i][n] = __builtin_amdgcn_mfma_f32_16x16x32_bf16(al[i], bh[n], acc[i][n], 0, 0, 0);
                }
            __syncthreads();
        }

        int cn = n0 + wc * 64 + (lane & 15);
#pragma unroll
        for (int i = 0; i < 4; ++i) {
#pragma unroll
            for (int n = 0; n < 4; ++n) {
                int col = cn + n * 16;
#pragma unroll
                for (int q = 0; q < 4; ++q) {
                    int r = wr * 64 + i * 16 + (lane >> 4) * 4 + q;
                    Cf[(size_t)(m0 + r) * N + col] = acc[i][n][q] + bias[col];
                }
            }
        }
    } else if (bid < 8576) {
        // wi (E,1024,4096) -> wiT (E,4096,1024): 1024 tiles/expert
        int j = bid - 384;
        int e = j >> 10, rem = j & 1023;
        int ry = rem >> 6, cx = rem & 63;
        tcvt64_body(wi + (size_t)e * DD * FF, wiT + (size_t)e * DD * FF,
                    1024, 4096, ry * 64, cx * 64, (float*)smem);
    } else if (bid < 12672) {
        // wo (E,2048,1024) -> woT (E,1024,2048): 512 tiles/expert
        int j = bid - 8576;
        int e = j >> 9, rem = j & 511;
        int ry = rem >> 4, cx = rem & 15;
        tcvt64_body(wo + (size_t)e * 2048 * 1024, woT + (size_t)e * 2048 * 1024,
                    2048, 1024, ry * 64, cx * 64, (float*)smem);
    } else {
        // w_out split-convert: 262144 float4
        int idx = (bid - 12672) * 256 + t;
        float4 v = ((const float4*)w_out)[idx];
        split_write(v.x, woH, woL, (size_t)idx * 4 + 0);
        split_write(v.y, woH, woL, (size_t)idx * 4 + 1);
        split_write(v.z, woH, woL, (size_t)idx * 4 + 2);
        split_write(v.w, woH, woL, (size_t)idx * 4 + 3);
    }
}

// ---------------- split-precision MFMA GEMM (out-proj): C = A @ Bt^T + bias + addsrc ----------------
// Block (0,0) additionally zeroes the 17 routing counters (race-free: later consumers in stream)
__global__ void k_mfma_split1(const __hip_bfloat16* __restrict__ Ah, const __hip_bfloat16* __restrict__ Al,
                              const __hip_bfloat16* __restrict__ Bh, const __hip_bfloat16* __restrict__ Bl,
                              const float* __restrict__ bias, const float* __restrict__ addsrc,
                              float* __restrict__ Cf, int M, int N, int K, int* __restrict__ zero17) {
    __shared__ __align__(16) short AsH[128 * 32];
    __shared__ __align__(16) short AsL[128 * 32];
    __shared__ __align__(16) short BsH[128 * 32];
    __shared__ __align__(16) short BsL[128 * 32];
    int m0 = blockIdx.y * 128, n0 = blockIdx.x * 128;
    const int t = threadIdx.x;
    if (blockIdx.x == 0 && blockIdx.y == 0 && t < 17) zero17[t] = 0;
    const int w = t >> 6, lane = t & 63;
    const int wr = w >> 1, wc = w & 1;
    const int sid = w * 64 + lane;

    f32x4 acc[4][4] = {};

    for (int k0 = 0; k0 < K; k0 += 32) {
#pragma unroll
        for (int j = 0; j < 2; ++j) {
            int id = j * 256 + sid;
            int rrow = id >> 2, sl = id & 3;
            int slog = sl ^ ((rrow >> 1) & 3);
            size_t lbase = (size_t)(j * 256 + w * 64) * 8;
            size_t gaoff = (size_t)(m0 + rrow) * K + k0 + slog * 8;
            gload16(Ah + gaoff, &AsH[lbase]);
            gload16(Al + gaoff, &AsL[lbase]);
            size_t gboff = (size_t)(n0 + rrow) * K + k0 + slog * 8;
            gload16(Bh + gboff, &BsH[lbase]);
            gload16(Bl + gboff, &BsL[lbase]);
        }
        __syncthreads();
        bf16x8 ah[4], al[4], bh[4], bl[4];
#pragma unroll
        for (int i = 0; i < 4; ++i) {
            int ra = wr * 64 + i * 16 + (lane & 15);
            int pa = (lane >> 4) ^ ((ra >> 1) & 3);
            ah[i] = *(const bf16x8*)&AsH[ra * 32 + pa * 8];
            al[i] = *(const bf16x8*)&AsL[ra * 32 + pa * 8];
            int rb = wc * 64 + i * 16 + (lane & 15);
            int pb = (lane >> 4) ^ ((rb >> 1) & 3);
            bh[i] = *(const bf16x8*)&BsH[rb * 32 + pb * 8];
            bl[i] = *(const bf16x8*)&BsL[rb * 32 + pb * 8];
        }
#pragma unroll
        for (int i = 0; i < 4; ++i)
#pragma unroll
            for (int n = 0; n < 4; ++n) {
                acc[i][n] = __builtin_amdgcn_mfma_f32_16x16x32_bf16(ah[i], bh[n], acc[i][n], 0, 0, 0);
                acc[i][n] = __builtin_amdgcn_mfma_f32_16x16x32_bf16(ah[i], bl[n], acc[i][n], 0, 0, 0);
                acc[i][n] = __builtin_amdgcn_mfma_f32_16x16x32_bf16(al[i], bh[n], acc[i][n], 0, 0, 0);
            }
        __syncthreads();
    }

    int cn = n0 + wc * 64 + (lane & 15);
#pragma unroll
    for (int i = 0; i < 4; ++i) {
#pragma unroll
        for (int n = 0; n < 4; ++n) {
            int col = cn + n * 16;
#pragma unroll
            for (int q = 0; q < 4; ++q) {
                int r = wr * 64 + i * 16 + (lane >> 4) * 4 + q;
                Cf[(size_t)(m0 + r) * N + col] =
                    acc[i][n][q] + bias[col] + addsrc[(size_t)(m0 + r) * N + col];
            }
        }
    }
}

// ---------------- MoE up-proj with interleaved a/g columns + fused silu epilogue ----------------
__global__ void k_moe_up(const __hip_bfloat16* __restrict__ A,     // h2 bf16 (M,1024)
                         const __hip_bfloat16* __restrict__ Bt,    // wiT (E,4096,1024)
                         __hip_bfloat16* __restrict__ act,         // (perm rows, 2048)
                         const int* __restrict__ perm,
                         const int* __restrict__ te, const int* __restrict__ ts,
                         const int* __restrict__ tr, const int* __restrict__ ntl) {
    __shared__ __align__(16) short As[128 * 32];
    __shared__ __align__(16) short Bs[128 * 32];
    __shared__ int permS[128];
    int tile = blockIdx.y;
    if (tile >= *ntl) return;
    int e = te[tile], rs = ts[tile], rows = tr[tile];
    if (threadIdx.x < 128) {
        int r = threadIdx.x;
        permS[r] = (r < rows) ? perm[rs + r] : 0;
    }
    __syncthreads();
    int c0 = blockIdx.x * 64;
    const int t = threadIdx.x;
    const int w = t >> 6, lane = t & 63;
    const int wr = w >> 1, wc = w & 1;
    const int sid = w * 64 + lane;
    const int g = lane >> 4, r16 = lane & 15;

    const __hip_bfloat16* Bp = Bt + (size_t)e * FF * DD;

    f32x4 acc[4][4] = {};

    for (int k0 = 0; k0 < DD; k0 += 32) {
#pragma unroll
        for (int j = 0; j < 2; ++j) {
            int id = j * 256 + sid;
            int rrow = id >> 2, sl = id & 3;
            int slog = sl ^ ((rrow >> 1) & 3);
            size_t lbase = (size_t)(j * 256 + w * 64) * 8;
            gload16(A + (size_t)permS[rrow] * DD + k0 + slog * 8, &As[lbase]);
            int q = rrow >> 4, rr = rrow & 15;
            int wrow = c0 + (q >> 2) * 32 + ((q & 3) >> 1) * 16 + rr + (q & 1) * 2048;
            gload16(Bp + (size_t)wrow * DD + k0 + slog * 8, &Bs[lbase]);
        }
        __syncthreads();
        bf16x8 af[4], bfr[4];
#pragma unroll
        for (int i = 0; i < 4; ++i) {
            int ra = wr * 64 + i * 16 + r16;
            int pa = g ^ ((ra >> 1) & 3);
            af[i] = *(const bf16x8*)&As[ra * 32 + pa * 8];
            int rb = wc * 64 + i * 16 + r16;
            int pb = g ^ ((rb >> 1) & 3);
            bfr[i] = *(const bf16x8*)&Bs[rb * 32 + pb * 8];
        }
#pragma unroll
        for (int i = 0; i < 4; ++i)
#pragma unroll
            for (int n = 0; n < 4; ++n)
                acc[i][n] = __builtin_amdgcn_mfma_f32_16x16x32_bf16(af[i], bfr[n], acc[i][n], 0, 0, 0);
        __syncthreads();
    }

#pragma unroll
    for (int i = 0; i < 4; ++i) {
#pragma unroll
        for (int p2 = 0; p2 < 2; ++p2) {
            int col = c0 + wc * 32 + p2 * 16 + r16;
#pragma unroll
            for (int q = 0; q < 4; ++q) {
                int r = wr * 64 + i * 16 + g * 4 + q;
                if (r < rows) {
                    float a  = acc[i][2 * p2][q];
                    float gv = acc[i][2 * p2 + 1][q];
                    act[(size_t)(rs + r) * 2048 + col] =
                        __float2bfloat16((a / (1.f + expf(-a))) * gv);
                }
            }
        }
    }
}

// ---------------- MoE down-proj: out = x2 + gate * (act @ woT[e]^T) ----------------
__global__ void k_moe_dn(const __hip_bfloat16* __restrict__ A,
                         const __hip_bfloat16* __restrict__ Bt,
                         const float* __restrict__ addsrc, float* __restrict__ Cf,
                         const int* __restrict__ perm,
                         const int* __restrict__ te, const int* __restrict__ ts,
                         const int* __restrict__ tr, const int* __restrict__ ntl,
                         const float* __restrict__ gate) {
    __shared__ __align__(16) short As[128 * 32];
    __shared__ __align__(16) short Bs[128 * 32];
    __shared__ int permS[128];
    int tile = blockIdx.y;
    if (tile >= *ntl) return;
    int e = te[tile], rs = ts[tile], rows = tr[tile];
    if (threadIdx.x < 128) {
        int r = threadIdx.x;
        permS[r] = (r < rows) ? perm[rs + r] : 0;
    }
    __syncthreads();
    int n0 = blockIdx.x * 128;
    const int t = threadIdx.x;
    const int w = t >> 6, lane = t & 63;
    const int wr = w >> 1, wc = w & 1;
    const int sid = w * 64 + lane;
    const int K = FF / 2;

    const __hip_bfloat16* Bp = Bt + (size_t)e * DD * (FF / 2);

    f32x4 acc[4][4] = {};

    for (int k0 = 0; k0 < K; k0 += 32) {
#pragma unroll
        for (int j = 0; j < 2; ++j) {
            int id = j * 256 + sid;
            int rrow = id >> 2, sl = id & 3;
            int slog = sl ^ ((rrow >> 1) & 3);
            size_t lbase = (size_t)(j * 256 + w * 64) * 8;
            gload16(A + (size_t)(rs + rrow) * K + k0 + slog * 8, &As[lbase]);
            gload16(Bp + (size_t)(n0 + rrow) * K + k0 + slog * 8, &Bs[lbase]);
        }
        __syncthreads();
        bf16x8 af[4], bfr[4];
#pragma unroll
        for (int i = 0; i < 4; ++i) {
            int ra = wr * 64 + i * 16 + (lane & 15);
            int pa = (lane >> 4) ^ ((ra >> 1) & 3);
            af[i] = *(const bf16x8*)&As[ra * 32 + pa * 8];
            int rb = wc * 64 + i * 16 + (lane & 15);
            int pb = (lane >> 4) ^ ((rb >> 1) & 3);
            bfr[i] = *(const bf16x8*)&Bs[rb * 32 + pb * 8];
        }
#pragma unroll
        for (int i = 0; i < 4; ++i)
#pragma unroll
            for (int n = 0; n < 4; ++n)
                acc[i][n] = __builtin_amdgcn_mfma_f32_16x16x32_bf16(af[i], bfr[n], acc[i][n], 0, 0, 0);
        __syncthreads();
    }

    int cn = n0 + wc * 64 + (lane & 15);
#pragma unroll
    for (int i = 0; i < 4; ++i) {
#pragma unroll
        for (int n = 0; n < 4; ++n) {
            int col = cn + n * 16;
#pragma unroll
            for (int q = 0; q < 4; ++q) {
                int r = wr * 64 + i * 16 + (lane >> 4) * 4 + q;
                if (r >= rows) continue;
                int tok = permS[r];
                Cf[(size_t)tok * DD + col] = addsrc[(size_t)tok * DD + col] + gate[tok] * acc[i][n][q];
            }
        }
    }
}

// ---------------- attention prep: split K -> [b,h,s,d] swz, V^T -> [b,h,d,s] swz ----------------
__global__ void k_prep(const float* __restrict__ qkv, short* __restrict__ KH, short* __restrict__ KL,
                       short* __restrict__ VH, short* __restrict__ VL) {
    __shared__ float tile[64][65];
    int b = blockIdx.z, h = blockIdx.y, s0 = blockIdx.x * 64;
    int t = threadIdx.x;
    int row = t >> 2, c0 = (t & 3) * 16;
    const float* kp = qkv + (size_t)(b * SS + s0 + row) * 3072 + 1024 + h * 64 + c0;
    const float* vp = kp + 1024;
    {
        size_t krow = ((size_t)(b * HH + h) * SS + s0 + row) * 64;
        int key = (s0 + row) & 7;
#pragma unroll
        for (int g2 = 0; g2 < 2; ++g2) {
            s16x8 hv, lv;
#pragma unroll
            for (int j = 0; j < 8; ++j) {
                float v = kp[g2 * 8 + j];
                short hh = bfh(v);
                hv[j] = hh; lv[j] = bfh(v - bf2f(hh));
            }
            int p = ((c0 >> 3) + g2) ^ key;
            *(s16x8*)&KH[krow + p * 8] = hv;
            *(s16x8*)&KL[krow + p * 8] = lv;
        }
    }
#pragma unroll
    for (int j = 0; j < 16; ++j) tile[row][c0 + j] = vp[j];
    __syncthreads();
    {
        int d = t >> 2, sc = (t & 3) * 16;
        size_t vrow = ((size_t)(b * HH + h) * 64 + d) * SS + s0;
        int key = d & 7;
#pragma unroll
        for (int g2 = 0; g2 < 2; ++g2) {
            s16x8 hv, lv;
#pragma unroll
            for (int j = 0; j < 8; ++j) {
                float v = tile[sc + g2 * 8 + j][d];
                short hh = bfh(v);
                hv[j] = hh; lv[j] = bfh(v - bf2f(hh));
            }
            int p = ((sc >> 3) + g2) ^ key;
            *(s16x8*)&VH[vrow + p * 8] = hv;
            *(s16x8*)&VL[vrow + p * 8] = lv;
        }
    }
}

// ---------------- MFMA flash attention, split precision, dbuf, 8 waves x 16 q-rows (QB=128),
// 1D XCD-swizzled grid: 256 blocks, id&7 = XCD, 4 (b,h) per XCD (2MB K/V < 4MB L2) ----------------
#define LDP 72
__global__ __launch_bounds__(512, 1)
void k_attn_mfma(const float* __restrict__ qkv,
                 const short* __restrict__ KH, const short* __restrict__ KL,
                 const short* __restrict__ VH, const short* __restrict__ VL,
                 __hip_bfloat16* __restrict__ ohi, __hip_bfloat16* __restrict__ olo) {
    __shared__ __align__(16) short Ks[2][64 * 64], Kl2[2][64 * 64], Vs[2][64 * 64], Vl2[2][64 * 64];
    __shared__ __align__(16) short PhS[8][16 * LDP], PlS[8][16 * LDP];
    int id = blockIdx.x;
    int xcd = id & 7, slot = id >> 3;        // 32 slots per XCD
    int bh = xcd * 4 + (slot >> 3);          // 4 (b,h) groups per XCD
    int q0 = (slot & 7) * 128;               // 8 q-tiles per (b,h)
    int b = bh >> 4, h = bh & 15;
    int t = threadIdx.x;
    int w = t >> 6, lane = t & 63;
    int g = lane >> 4, r16 = lane & 15;
    int srow = t >> 3, sslot = t & 7;

    const size_t kbase = ((size_t)bh * SS) * 64;
    const size_t vbase = ((size_t)bh * 64) * SS;

    // ---- Q fragments direct from f32 qkv, prescale 1/8, split in-reg
    bf16x8 qfh[2], qfl[2];
    {
        const float* qp = qkv + (size_t)(b * SS + q0 + w * 16 + r16) * 3072 + h * 64;
#pragma unroll
        for (int ks = 0; ks < 2; ++ks) {
            float vv[8];
            *(float4*)&vv[0] = *(const float4*)(qp + ks * 32 + g * 8);
            *(float4*)&vv[4] = *(const float4*)(qp + ks * 32 + g * 8 + 4);
#pragma unroll
            for (int j = 0; j < 8; ++j) {
                float sv = vv[j] * 0.125f;
                short hh = bfh(sv);
                qfh[ks][j] = hh;
                qfl[ks][j] = bfh(sv - bf2f(hh));
            }
        }
    }

    float mrun[4], lrun[4];
    f32x4 oacc[4] = {};
#pragma unroll
    for (int q = 0; q < 4; ++q) { mrun[q] = -1e30f; lrun[q] = 0.f; }

    // prologue: stage tile 0 into buf 0
    gload16(KH + kbase + (size_t)srow * 64 + sslot * 8, &Ks[0][w * 512]);
    gload16(KL + kbase + (size_t)srow * 64 + sslot * 8, &Kl2[0][w * 512]);
    gload16(VH + vbase + (size_t)srow * SS + sslot * 8, &Vs[0][w * 512]);
    gload16(VL + vbase + (size_t)srow * SS + sslot * 8, &Vl2[0][w * 512]);
    __syncthreads();

    int cur = 0;
    for (int k0 = 0; k0 < SS; k0 += 64) {
        // ---- prefetch next tile into alternate buffer
        if (k0 + 64 < SS) {
            int kn = k0 + 64;
            gload16(KH + kbase + (size_t)(kn + srow) * 64 + sslot * 8, &Ks[cur ^ 1][w * 512]);
            gload16(KL + kbase + (size_t)(kn + srow) * 64 + sslot * 8, &Kl2[cur ^ 1][w * 512]);
            gload16(VH + vbase + (size_t)srow * SS + kn + sslot * 8,   &Vs[cur ^ 1][w * 512]);
            gload16(VL + vbase + (size_t)srow * SS + kn + sslot * 8,   &Vl2[cur ^ 1][w * 512]);
        }

        // ---- S = Q K^T (split, 3 MFMA per fragment)
        f32x4 accs[4] = {};
#pragma unroll
        for (int ks = 0; ks < 2; ++ks) {
            bf16x8 kfh[4], kfl[4];
#pragma unroll
            for (int n = 0; n < 4; ++n) {
                int rb = n * 16 + r16;
                int p = (ks * 4 + g) ^ (r16 & 7);
                kfh[n] = *(const bf16x8*)&Ks[cur][rb * 64 + p * 8];
                kfl[n] = *(const bf16x8*)&Kl2[cur][rb * 64 + p * 8];
            }
            __builtin_amdgcn_s_setprio(1);
#pragma unroll
            for (int n = 0; n < 4; ++n) {
                accs[n] = __builtin_amdgcn_mfma_f32_16x16x32_bf16(qfh[ks], kfh[n], accs[n], 0, 0, 0);
                accs[n] = __builtin_amdgcn_mfma_f32_16x16x32_bf16(qfh[ks], kfl[n], accs[n], 0, 0, 0);
                accs[n] = __builtin_amdgcn_mfma_f32_16x16x32_bf16(qfl[ks], kfh[n], accs[n], 0, 0, 0);
            }
            __builtin_amdgcn_s_setprio(0);
        }

        // ---- online softmax
        float mn[4], corr[4], psum[4];
#pragma unroll
        for (int q = 0; q < 4; ++q) {
            float m = fmaxf(fmaxf(accs[0][q], accs[1][q]), fmaxf(accs[2][q], accs[3][q]));
            m = fmaxf(m, __shfl_xor(m, 1));
            m = fmaxf(m, __shfl_xor(m, 2));
            m = fmaxf(m, __shfl_xor(m, 4));
            m = fmaxf(m, __shfl_xor(m, 8));
            mn[q] = fmaxf(mrun[q], m);
            corr[q] = expf(mrun[q] - mn[q]);
            mrun[q] = mn[q];
            psum[q] = 0.f;
        }
#pragma unroll
        for (int n = 0; n < 4; ++n)
#pragma unroll
            for (int q = 0; q < 4; ++q) {
                float p = expf(accs[n][q] - mn[q]);
                psum[q] += p;
                short ph = bfh(p);
                PhS[w][(g * 4 + q) * LDP + n * 16 + r16] = ph;
                PlS[w][(g * 4 + q) * LDP + n * 16 + r16] = bfh(p - bf2f(ph));
            }
#pragma unroll
        for (int q = 0; q < 4; ++q) {
            psum[q] += __shfl_xor(psum[q], 1);
            psum[q] += __shfl_xor(psum[q], 2);
            psum[q] += __shfl_xor(psum[q], 4);
            psum[q] += __shfl_xor(psum[q], 8);
            lrun[q] = lrun[q] * corr[q] + psum[q];
#pragma unroll
            for (int n = 0; n < 4; ++n) oacc[n][q] *= corr[q];
        }

        // ---- O += P V (split)
#pragma unroll
        for (int ks = 0; ks < 2; ++ks) {
            bf16x8 vfh[4], vfl[4];
#pragma unroll
            for (int n = 0; n < 4; ++n) {
                int rb = n * 16 + r16;
                int p = (ks * 4 + g) ^ (r16 & 7);
                vfh[n] = *(const bf16x8*)&Vs[cur][rb * 64 + p * 8];
                vfl[n] = *(const bf16x8*)&Vl2[cur][rb * 64 + p * 8];
            }
            bf16x8 pfh = *(const bf16x8*)&PhS[w][r16 * LDP + ks * 32 + g * 8];
            bf16x8 pfl = *(const bf16x8*)&PlS[w][r16 * LDP + ks * 32 + g * 8];
            __builtin_amdgcn_s_setprio(1);
#pragma unroll
            for (int n = 0; n < 4; ++n) {
                oacc[n] = __builtin_amdgcn_mfma_f32_16x16x32_bf16(pfh, vfh[n], oacc[n], 0, 0, 0);
                oacc[n] = __builtin_amdgcn_mfma_f32_16x16x32_bf16(pfh, vfl[n], oacc[n], 0, 0, 0);
                oacc[n] = __builtin_amdgcn_mfma_f32_16x16x32_bf16(pfl, vfh[n], oacc[n], 0, 0, 0);
            }
            __builtin_amdgcn_s_setprio(0);
        }
        __syncthreads();   // drains prefetch vmcnt + barriers buffer reuse
        cur ^= 1;
    }

    // ---- epilogue
    float invl[4];
#pragma unroll
    for (int q = 0; q < 4; ++q) invl[q] = 1.f / lrun[q];
#pragma unroll
    for (int n = 0; n < 4; ++n) {
        int col = h * 64 + n * 16 + r16;
#pragma unroll
        for (int q = 0; q < 4; ++q) {
            int rowg = b * SS + q0 + w * 16 + g * 4 + q;
            split_write(oacc[n][q] * invl[q], ohi, olo, (size_t)rowg * DD + col);
        }
    }
}

// ---------------- fused LN2 + router: h2 bf16 out, logits/gate/eid/counts ----------------
__global__ void k_ln2_router(const float* __restrict__ x2, const float* __restrict__ w,
                             const float* __restrict__ b, const float* __restrict__ wr,
                             __hip_bfloat16* __restrict__ h2b, float* __restrict__ logits,
                             float* __restrict__ gate, int* __restrict__ eid,
                             int* __restrict__ counts) {
    int m = blockIdx.x, t = threadIdx.x;
    __shared__ float red[8];
    __shared__ float racc[4][8];
    const float* xp = x2 + (size_t)m * DD;
    float v[4];
    float sum = 0.f, sumsq = 0.f;
#pragma unroll
    for (int l = 0; l < 4; ++l) {
        v[l] = xp[t + l * 256];
        sum += v[l]; sumsq += v[l] * v[l];
    }
#pragma unroll
    for (int off = 32; off; off >>= 1) {
        sum   += __shfl_xor(sum, off);
        sumsq += __shfl_xor(sumsq, off);
    }
    int wid = t >> 6, lane = t & 63;
    if (lane == 0) { red[wid] = sum; red[4 + wid] = sumsq; }
    __syncthreads();
    sum   = red[0] + red[1] + red[2] + red[3];
    sumsq = red[4] + red[5] + red[6] + red[7];
    float mean = sum * (1.f / DD);
    float var  = sumsq * (1.f / DD) - mean * mean;
    float rstd = rsqrtf(var + 1e-5f);
    float acc[EE] = {};
#pragma unroll
    for (int l = 0; l < 4; ++l) {
        int i = t + l * 256;
        float hv = (v[l] - mean) * rstd * w[i] + b[i];
        h2b[(size_t)m * DD + i] = __float2bfloat16(hv);
        const float* wp = wr + (size_t)i * EE;
#pragma unroll
        for (int n = 0; n < EE; ++n) acc[n] += hv * wp[n];
    }
#pragma unroll
    for (int off = 32; off; off >>= 1)
#pragma unroll
        for (int n = 0; n < EE; ++n) acc[n] += __shfl_xor(acc[n], off);
    if (lane == 0)
#pragma unroll
        for (int n = 0; n < EE; ++n) racc[wid][n] = acc[n];
    __syncthreads();
    if (t == 0) {
        float lg[EE];
#pragma unroll
        for (int n = 0; n < EE; ++n) lg[n] = racc[0][n] + racc[1][n] + racc[2][n] + racc[3][n];
        float mx = lg[0]; int best = 0;
#pragma unroll
        for (int n = 1; n < EE; ++n) if (lg[n] > mx) { mx = lg[n]; best = n; }
        float den = 0.f;
#pragma unroll
        for (int n = 0; n < EE; ++n) den += expf(lg[n] - mx);
        gate[m] = 1.f / den;
        eid[m] = best;
        atomicAdd(&counts[best], 1);
#pragma unroll
        for (int n = 0; n < EE; ++n) logits[(size_t)m * EE + n] = lg[n];
    }
}

// ---------------- fused routing bookkeeping: offsets + tiles + scatter (1 block) ----------------
__global__ void k_offscatter(const int* __restrict__ counts,
                             int* __restrict__ te, int* __restrict__ ts, int* __restrict__ tr,
                             int* __restrict__ ntl, const int* __restrict__ eid,
                             int* __restrict__ fill, int* __restrict__ perm) {
    __shared__ int soffs[EE];
    int t = threadIdx.x;
    if (t == 0) {
        int off = 0, nt = 0;
        for (int e = 0; e < EE; ++e) {
            soffs[e] = off;
            int c = counts[e];
            for (int t0 = 0; t0 < c; t0 += 128) {
                te[nt] = e; ts[nt] = off + t0; tr[nt] = (c - t0 < 128) ? (c - t0) : 128; ++nt;
            }
            off += c;
        }
        *ntl = nt;
    }
    __syncthreads();
#pragma unroll
    for (int tok = t; tok < MM; tok += 1024) {
        int e = eid[tok];
        int pos = soffs[e] + atomicAdd(&fill[e], 1);
        perm[pos] = tok;
    }
}

// ---------------- launch ----------------
extern "C" void kernel_launch(void* const* d_in, const int* in_sizes, int n_in,
                              void* d_out, int out_size, void* d_ws, size_t ws_size,
                              hipStream_t stream) {
    const float* x     = (const float*)d_in[0];
    const float* ln1w  = (const float*)d_in[1];
    const float* ln1b  = (const float*)d_in[2];
    const float* ln2w  = (const float*)d_in[3];
    const float* ln2b  = (const float*)d_in[4];
    const float* w_qkv = (const float*)d_in[5];
    const float* b_qkv = (const float*)d_in[6];
    const float* w_out = (const float*)d_in[7];
    const float* b_out = (const float*)d_in[8];
    const float* w_rtr = (const float*)d_in[9];
    const float* wi    = (const float*)d_in[10];
    const float* wo    = (const float*)d_in[11];
    float* out = (float*)d_out;

    char* wsb = (char*)d_ws;
    __hip_bfloat16* wiT  = (__hip_bfloat16*)(wsb + OFF_WIT);
    __hip_bfloat16* woT  = (__hip_bfloat16*)(wsb + OFF_WOT);
    __hip_bfloat16* wqH  = (__hip_bfloat16*)(wsb + OFF_WQH);
    __hip_bfloat16* wqL  = (__hip_bfloat16*)(wsb + OFF_WQL);
    __hip_bfloat16* woH  = (__hip_bfloat16*)(wsb + OFF_WOH);
    __hip_bfloat16* woL  = (__hip_bfloat16*)(wsb + OFF_WOL);
    __hip_bfloat16* h1H  = (__hip_bfloat16*)(wsb + OFF_H1H);
    __hip_bfloat16* h1L  = (__hip_bfloat16*)(wsb + OFF_H1L);
    float*          qkvF = (float*)(wsb + OFF_QKV);
    __hip_bfloat16* oH   = (__hip_bfloat16*)(wsb + OFF_OH);
    __hip_bfloat16* oL   = (__hip_bfloat16*)(wsb + OFF_OL);
    float*          x2F  = (float*)(wsb + OFF_X2);
    __hip_bfloat16* h2B  = (__hip_bfloat16*)(wsb + OFF_H2B);
    __hip_bfloat16* actB = (__hip_bfloat16*)(wsb + OFF_ACT);
    short* KSH = (short*)(wsb + OFF_KSH);
    short* KSL = (short*)(wsb + OFF_KSL);
    short* VTH = (short*)(wsb + OFF_VTH);
    short* VTL = (short*)(wsb + OFF_VTL);
    float* gate = (float*)(wsb + OFF_GATE);
    int* eid    = (int*)(wsb + OFF_EID);
    int* perm   = (int*)(wsb + OFF_PERM);
    int* counts = (int*)(wsb + OFF_CNT);
    int* fill   = (int*)(wsb + OFF_FILL);
    int* ntl    = (int*)(wsb + OFF_NT);
    int* te     = (int*)(wsb + OFF_TE);
    int* tsx    = (int*)(wsb + OFF_TS);
    int* trx    = (int*)(wsb + OFF_TR);

    // 1. slim phase-0: LN1+RoPE + w_qkv split-cvt (inputs of the qkv GEMM)
    k_phase0<<<5120, 256, 0, stream>>>(x, ln1w, ln1b, h1H, h1L, w_qkv, wqH, wqL);
    // 2. qkv GEMM mega-launch: GEMM blocks first; wi/wo transpose-cvt + w_out cvt
    //    ride the GEMM's spare HBM bandwidth (needed only at dispatches 5/8/9)
    k_qkv_mega<<<13696, 256, 0, stream>>>(h1H, h1L, wqH, wqL, b_qkv, qkvF,
                                          wi, wiT, wo, woT, w_out, woH, woL);
    // 3. prep: split K + transposed V (overwrites dead wq/h1 regions)
    k_prep<<<dim3(SS / 64, HH, BB), 256, 0, stream>>>(qkvF, KSH, KSL, VTH, VTL);
    // 4. attention (split-precision MFMA, dbuf, XCD-swizzled 256 blocks)
    k_attn_mfma<<<256, 512, 0, stream>>>(qkvF, KSH, KSL, VTH, VTL, oH, oL);
    // 5. x2 = x + o @ w_out^T + b_out (split precision); block 0 zeroes routing counters
    k_mfma_split1<<<dim3(DD / 128, MM / 128), 256, 0, stream>>>(
        oH, oL, woH, woL, b_out, x, x2F, MM, DD, DD, counts);
    // 6. LN2 + router fused (h2 bf16 + exact f32 logits/argmax)
    k_ln2_router<<<MM, 256, 0, stream>>>(x2F, ln2w, ln2b, w_rtr, h2B,
                                         out + (size_t)MM * DD, gate, eid, counts);
    // 7. fused offsets + tiles + scatter
    k_offscatter<<<1, 1024, 0, stream>>>(counts, te, tsx, trx, ntl, eid, fill, perm);
    // 8. act = silu(h2[perm] @ wiT_a) * (h2[perm] @ wiT_g)
    k_moe_up<<<dim3(2048 / 64, MAX_TILES), 256, 0, stream>>>(
        h2B, wiT, actB, perm, te, tsx, trx, ntl);
    // 9. out = x2 + gate * (act @ woT[e]^T)
    k_moe_dn<<<dim3(DD / 128, MAX_TILES), 256, 0, stream>>>(
        actB, woT, x2F, out, perm, te, tsx, trx, ntl, gate);
}

// Round 11
// 316.385 us; speedup vs baseline: 1.4788x; 1.0585x over previous
//
#include <hip/hip_runtime.h>
#include <hip/hip_bf16.h>
#include <math.h>

// Problem constants
#define BB 2
#define SS 1024
#define DD 1024
#define FF 4096
#define HH 16
#define EE 8
#define MM (BB*SS)          // 2048 tokens
#define MAX_TILES 24        // BM=128 tiles: sum_e ceil(cnt_e/128) <= 24
#define MAX_TILES2 40       // BM=64 tiles: sum_e ceil(cnt_e/64) <= 40

typedef __attribute__((ext_vector_type(8))) short bf16x8;
typedef __attribute__((ext_vector_type(8))) short s16x8;
typedef __attribute__((ext_vector_type(4))) float f32x4;

// ---------------- workspace layout (bytes) ----------------
#define OFF_WIT  ((size_t)0)            // wi^T bf16: 67108864
#define OFF_WOT  ((size_t)67108864)     // wo^T bf16: 33554432
#define OFF_WQH  ((size_t)100663296)    // w_qkv hi bf16 (later: K split hi/lo)
#define OFF_WQL  ((size_t)106954752)    // w_qkv lo bf16
#define OFF_WOH  ((size_t)113246208)    // w_out hi bf16
#define OFF_WOL  ((size_t)115343360)    // w_out lo bf16
#define OFF_H1H  ((size_t)117440512)    // h1 hi bf16 (later: VT hi)
#define OFF_H1L  ((size_t)121634816)    // h1 lo bf16 (later: VT lo)
#define OFF_QKV  ((size_t)125829120)    // qkv f32: 25165824
#define OFF_OH   ((size_t)150994944)    // attn o hi bf16
#define OFF_OL   ((size_t)155189248)    // attn o lo bf16
#define OFF_X2   ((size_t)159383552)    // x2 f32: 8388608
#define OFF_H2B  ((size_t)167772160)    // h2 bf16: 4194304
#define OFF_ACT  ((size_t)171966464)    // act bf16
#define OFF_GATE ((size_t)180879360)
#define OFF_EID  ((size_t)180887552)
#define OFF_PERM ((size_t)180895744)
#define OFF_CNT  ((size_t)180903936)    // 17 ints zeroed by out-proj block 0
#define OFF_FILL ((size_t)180903968)
#define OFF_NT   ((size_t)180904000)
#define OFF_TE   ((size_t)180904192)
#define OFF_TS   ((size_t)180904320)
#define OFF_TR   ((size_t)180904448)
#define OFF_TE2  ((size_t)180904576)    // 40 ints
#define OFF_TS2  ((size_t)180904768)
#define OFF_TR2  ((size_t)180904960)
#define OFF_NT2  ((size_t)180905152)
// attention K/V split buffers (reuse dead regions)
#define OFF_KSH  OFF_WQH
#define OFF_KSL  (OFF_WQH + 4194304)
#define OFF_VTH  OFF_H1H
#define OFF_VTL  OFF_H1L

// ---------------- async global->LDS (16B per lane) ----------------
__device__ __forceinline__ void gload16(const void* g, void* l) {
    __builtin_amdgcn_global_load_lds(
        (const __attribute__((address_space(1))) unsigned int*)g,
        (__attribute__((address_space(3))) unsigned int*)l, 16, 0, 0);
}

__device__ __forceinline__ short bfh(float v) {
    __hip_bfloat16 h = __float2bfloat16(v);
    return *(short*)&h;
}
__device__ __forceinline__ float bf2f(short s) {
    __hip_bfloat16 h = *(__hip_bfloat16*)&s;
    return __bfloat162float(h);
}

__device__ __forceinline__ void split_write(float v, __hip_bfloat16* hp, __hip_bfloat16* lp, size_t idx) {
    __hip_bfloat16 h = __float2bfloat16(v);
    hp[idx] = h;
    lp[idx] = __float2bfloat16(v - __bfloat162float(h));
}

// ---------------- transpose-convert body: in (R,C) f32 -> out (C,R) bf16, 64x64 tile ----------------
__device__ __forceinline__ void tcvt64_body(const float* __restrict__ in, __hip_bfloat16* __restrict__ out,
                                            int R, int C, int r0, int c0, float* tile /*64*65*/) {
    int t = threadIdx.x;
    {
        int ri = t >> 2, cj = (t & 3) * 16;
        const float* ip = &in[(size_t)(r0 + ri) * C + c0 + cj];
#pragma unroll
        for (int k = 0; k < 4; ++k) {
            float4 v = *(const float4*)(ip + k * 4);
            tile[ri * 65 + cj + k * 4 + 0] = v.x;
            tile[ri * 65 + cj + k * 4 + 1] = v.y;
            tile[ri * 65 + cj + k * 4 + 2] = v.z;
            tile[ri * 65 + cj + k * 4 + 3] = v.w;
        }
    }
    __syncthreads();
    {
        int co = t >> 2, rj = (t & 3) * 16;
        bf16x8 v8a, v8b;
#pragma unroll
        for (int q = 0; q < 8; ++q) v8a[q] = bfh(tile[(rj + q) * 65 + co]);
#pragma unroll
        for (int q = 0; q < 8; ++q) v8b[q] = bfh(tile[(rj + 8 + q) * 65 + co]);
        __hip_bfloat16* op = &out[(size_t)(c0 + co) * R + r0 + rj];
        *(bf16x8*)op = v8a;
        *(bf16x8*)(op + 8) = v8b;
    }
}

// ---------------- slim phase-0: LN1+RoPE [0,2048) | w_qkv split-cvt [2048,5120) ----------------
__global__ void k_phase0(const float* __restrict__ x, const float* __restrict__ ln1w,
                         const float* __restrict__ ln1b,
                         __hip_bfloat16* __restrict__ h1H, __hip_bfloat16* __restrict__ h1L,
                         const float* __restrict__ w_qkv, __hip_bfloat16* __restrict__ wqH,
                         __hip_bfloat16* __restrict__ wqL) {
    __shared__ __align__(16) float smem[1032];
    int bid = blockIdx.x, t = threadIdx.x;
    if (bid < 2048) {
        int m = bid, s = m & (SS - 1);
        float* row = smem;
        float* red = smem + 1024;
        const float* xp = x + (size_t)m * DD;
        float sum = 0.f, sumsq = 0.f;
#pragma unroll
        for (int l = 0; l < 4; ++l) {
            int i = t + l * 256;
            float v = xp[i];
            row[i] = v;
            sum += v; sumsq += v * v;
        }
#pragma unroll
        for (int off = 32; off; off >>= 1) {
            sum   += __shfl_xor(sum, off);
            sumsq += __shfl_xor(sumsq, off);
        }
        int wid = t >> 6, lane = t & 63;
        if (lane == 0) { red[wid] = sum; red[4 + wid] = sumsq; }
        __syncthreads();
        sum   = red[0] + red[1] + red[2] + red[3];
        sumsq = red[4] + red[5] + red[6] + red[7];
        float mean = sum * (1.f / DD);
        float var  = sumsq * (1.f / DD) - mean * mean;
        float rstd = rsqrtf(var + 1e-5f);
        size_t base = (size_t)m * DD;
        const float kln = logf(10000.f) / 512.f;
#pragma unroll
        for (int l = 0; l < 2; ++l) {
            int i = t + l * 256;   // 0..511
            float n1 = (row[i]       - mean) * rstd * ln1w[i]       + ln1b[i];
            float n2 = (row[i + 512] - mean) * rstd * ln1w[i + 512] + ln1b[i + 512];
            float inv = expf(-(float)i * kln);
            float ang = (float)s * inv;
            float c = cosf(ang), sn = sinf(ang);
            split_write(n1 * c - n2 * sn,  h1H, h1L, base + i);
            split_write(n1 * sn + n2 * c, h1H, h1L, base + i + 512);
        }
    } else {
        int idx = (bid - 2048) * 256 + t;        // 786432 float4
        float4 v = ((const float4*)w_qkv)[idx];
        split_write(v.x, wqH, wqL, (size_t)idx * 4 + 0);
        split_write(v.y, wqH, wqL, (size_t)idx * 4 + 1);
        split_write(v.z, wqH, wqL, (size_t)idx * 4 + 2);
        split_write(v.w, wqH, wqL, (size_t)idx * 4 + 3);
    }
}

// ---------------- qkv mega-kernel: split GEMM [0,384) | wi tcvt [384,8576) | w_out cvt [8576,9600) ----
__global__ void k_qkv_mega(const __hip_bfloat16* __restrict__ Ah, const __hip_bfloat16* __restrict__ Al,
                           const __hip_bfloat16* __restrict__ Bh, const __hip_bfloat16* __restrict__ Bl,
                           const float* __restrict__ bias, float* __restrict__ Cf,
                           const float* __restrict__ wi, __hip_bfloat16* __restrict__ wiT,
                           const float* __restrict__ w_out, __hip_bfloat16* __restrict__ woH,
                           __hip_bfloat16* __restrict__ woL) {
    __shared__ __align__(16) char smem[32768];
    int bid = blockIdx.x;
    const int t = threadIdx.x;
    if (bid < 384) {
        const int N = 3072, K = DD;
        short* AsH = (short*)smem;
        short* AsL = (short*)(smem + 8192);
        short* BsH = (short*)(smem + 16384);
        short* BsL = (short*)(smem + 24576);
        int n0 = (bid % 24) * 128, m0 = (bid / 24) * 128;
        const int w = t >> 6, lane = t & 63;
        const int wr = w >> 1, wc = w & 1;
        const int sid = w * 64 + lane;

        f32x4 acc[4][4] = {};

        for (int k0 = 0; k0 < K; k0 += 32) {
#pragma unroll
            for (int j = 0; j < 2; ++j) {
                int id = j * 256 + sid;
                int rrow = id >> 2, sl = id & 3;
                int slog = sl ^ ((rrow >> 1) & 3);
                size_t lbase = (size_t)(j * 256 + w * 64) * 8;
                size_t gaoff = (size_t)(m0 + rrow) * K + k0 + slog * 8;
                gload16(Ah + gaoff, &AsH[lbase]);
                gload16(Al + gaoff, &AsL[lbase]);
                size_t gboff = (size_t)(n0 + rrow) * K + k0 + slog * 8;
                gload16(Bh + gboff, &BsH[lbase]);
                gload16(Bl + gboff, &BsL[lbase]);
            }
            __syncthreads();
            bf16x8 ah[4], al[4], bh[4], bl[4];
#pragma unroll
            for (int i = 0; i < 4; ++i) {
                int ra = wr * 64 + i * 16 + (lane & 15);
                int pa = (lane >> 4) ^ ((ra >> 1) & 3);
                ah[i] = *(const bf16x8*)&AsH[ra * 32 + pa * 8];
                al[i] = *(const bf16x8*)&AsL[ra * 32 + pa * 8];
                int rb = wc * 64 + i * 16 + (lane & 15);
                int pb = (lane >> 4) ^ ((rb >> 1) & 3);
                bh[i] = *(const bf16x8*)&BsH[rb * 32 + pb * 8];
                bl[i] = *(const bf16x8*)&BsL[rb * 32 + pb * 8];
            }
#pragma unroll
            for (int i = 0; i < 4; ++i)
#pragma unroll
                for (int n = 0; n < 4; ++n) {
                    acc[i][n] = __builtin_amdgcn_mfma_f32_16x16x32_bf16(ah[i], bh[n], acc[i][n], 0, 0, 0);
                    acc[i][n] = __builtin_amdgcn_mfma_f32_16x16x32_bf16(ah[i], bl[n], acc[i][n], 0, 0, 0);
                    acc[i][n] = __builtin_amdgcn_mfma_f32_16x16x32_bf16(al[i], bh[n], acc[i][n], 0, 0, 0);
                }
            __syncthreads();
        }

        int cn = n0 + wc * 64 + (lane & 15);
#pragma unroll
        for (int i = 0; i < 4; ++i) {
#pragma unroll
            for (int n = 0; n < 4; ++n) {
                int col = cn + n * 16;
#pragma unroll
                for (int q = 0; q < 4; ++q) {
                    int r = wr * 64 + i * 16 + (lane >> 4) * 4 + q;
                    Cf[(size_t)(m0 + r) * N + col] = acc[i][n][q] + bias[col];
                }
            }
        }
    } else if (bid < 8576) {
        // wi (E,1024,4096) -> wiT (E,4096,1024)
        int j = bid - 384;
        int e = j >> 10, rem = j & 1023;
        int ry = rem >> 6, cx = rem & 63;
        tcvt64_body(wi + (size_t)e * DD * FF, wiT + (size_t)e * DD * FF,
                    1024, 4096, ry * 64, cx * 64, (float*)smem);
    } else {
        // w_out split-convert: 262144 float4
        int idx = (bid - 8576) * 256 + t;
        float4 v = ((const float4*)w_out)[idx];
        split_write(v.x, woH, woL, (size_t)idx * 4 + 0);
        split_write(v.y, woH, woL, (size_t)idx * 4 + 1);
        split_write(v.z, woH, woL, (size_t)idx * 4 + 2);
        split_write(v.w, woH, woL, (size_t)idx * 4 + 3);
    }
}

// ---------------- out-proj split GEMM, 64x128 tile (256 blocks, 24KB LDS, 2 blocks/CU) ----------------
// C = A @ Bt^T + bias + addsrc. Block 0 zeroes the 17 routing counters.
__global__ void k_oproj64(const __hip_bfloat16* __restrict__ Ah, const __hip_bfloat16* __restrict__ Al,
                          const __hip_bfloat16* __restrict__ Bh, const __hip_bfloat16* __restrict__ Bl,
                          const float* __restrict__ bias, const float* __restrict__ addsrc,
                          float* __restrict__ Cf, int* __restrict__ zero17) {
    __shared__ __align__(16) short AsH[64 * 32];
    __shared__ __align__(16) short AsL[64 * 32];
    __shared__ __align__(16) short BsH[128 * 32];
    __shared__ __align__(16) short BsL[128 * 32];
    const int N = DD, K = DD;
    int bid = blockIdx.x;
    int m0 = (bid >> 3) * 64, n0 = (bid & 7) * 128;
    const int t = threadIdx.x;
    if (bid == 0 && t < 17) zero17[t] = 0;
    const int w = t >> 6, lane = t & 63;
    const int sid = w * 64 + lane;
    const int g = lane >> 4, r16 = lane & 15;

    f32x4 acc[4][2] = {};

    for (int k0 = 0; k0 < K; k0 += 32) {
        {   // A: 64 rows, 1 pass
            int rrow = sid >> 2, sl = sid & 3;
            int slog = sl ^ ((rrow >> 1) & 3);
            size_t lbase = (size_t)(w * 64) * 8;
            size_t gaoff = (size_t)(m0 + rrow) * K + k0 + slog * 8;
            gload16(Ah + gaoff, &AsH[lbase]);
            gload16(Al + gaoff, &AsL[lbase]);
        }
#pragma unroll
        for (int j = 0; j < 2; ++j) {   // B: 128 rows, 2 passes
            int id = j * 256 + sid;
            int rrow = id >> 2, sl = id & 3;
            int slog = sl ^ ((rrow >> 1) & 3);
            size_t lbase = (size_t)(j * 256 + w * 64) * 8;
            size_t gboff = (size_t)(n0 + rrow) * K + k0 + slog * 8;
            gload16(Bh + gboff, &BsH[lbase]);
            gload16(Bl + gboff, &BsL[lbase]);
        }
        __syncthreads();
        bf16x8 ah[4], al[4], bh[2], bl[2];
#pragma unroll
        for (int i = 0; i < 4; ++i) {
            int ra = i * 16 + r16;
            int pa = g ^ ((ra >> 1) & 3);
            ah[i] = *(const bf16x8*)&AsH[ra * 32 + pa * 8];
            al[i] = *(const bf16x8*)&AsL[ra * 32 + pa * 8];
        }
#pragma unroll
        for (int n = 0; n < 2; ++n) {
            int rb = w * 32 + n * 16 + r16;
            int pb = g ^ ((rb >> 1) & 3);
            bh[n] = *(const bf16x8*)&BsH[rb * 32 + pb * 8];
            bl[n] = *(const bf16x8*)&BsL[rb * 32 + pb * 8];
        }
#pragma unroll
        for (int i = 0; i < 4; ++i)
#pragma unroll
            for (int n = 0; n < 2; ++n) {
                acc[i][n] = __builtin_amdgcn_mfma_f32_16x16x32_bf16(ah[i], bh[n], acc[i][n], 0, 0, 0);
                acc[i][n] = __builtin_amdgcn_mfma_f32_16x16x32_bf16(ah[i], bl[n], acc[i][n], 0, 0, 0);
                acc[i][n] = __builtin_amdgcn_mfma_f32_16x16x32_bf16(al[i], bh[n], acc[i][n], 0, 0, 0);
            }
        __syncthreads();
    }

#pragma unroll
    for (int i = 0; i < 4; ++i) {
#pragma unroll
        for (int n = 0; n < 2; ++n) {
            int col = n0 + w * 32 + n * 16 + r16;
#pragma unroll
            for (int q = 0; q < 4; ++q) {
                int r = m0 + i * 16 + g * 4 + q;
                Cf[(size_t)r * N + col] =
                    acc[i][n][q] + bias[col] + addsrc[(size_t)r * N + col];
            }
        }
    }
}

// ---------------- MoE up-proj mega: GEMM [0,768) | wo tcvt [768,4864) ----------------
// GEMM: interleaved a/g columns + fused silu epilogue (BM=128 tile list).
__global__ void k_moe_up(const __hip_bfloat16* __restrict__ A,     // h2 bf16 (M,1024)
                         const __hip_bfloat16* __restrict__ Bt,    // wiT (E,4096,1024)
                         __hip_bfloat16* __restrict__ act,         // (perm rows, 2048)
                         const int* __restrict__ perm,
                         const int* __restrict__ te, const int* __restrict__ ts,
                         const int* __restrict__ tr, const int* __restrict__ ntl,
                         const float* __restrict__ wo, __hip_bfloat16* __restrict__ woT) {
    __shared__ __align__(16) char smem[17408];
    int bid = blockIdx.x;
    const int t = threadIdx.x;
    if (bid >= 768) {
        // wo (E,2048,1024) -> woT (E,1024,2048)
        int j = bid - 768;
        int e = j >> 9, rem = j & 511;
        int ry = rem >> 4, cx = rem & 15;
        tcvt64_body(wo + (size_t)e * 2048 * 1024, woT + (size_t)e * 2048 * 1024,
                    2048, 1024, ry * 64, cx * 64, (float*)smem);
        return;
    }
    short* As = (short*)smem;                 // 128*32
    short* Bs = (short*)(smem + 8192);        // 128*32
    int* permS = (int*)(smem + 16384);        // 128 ints
    int tile = bid / 32;
    if (tile >= *ntl) return;
    int e = te[tile], rs = ts[tile], rows = tr[tile];
    if (t < 128) permS[t] = (t < rows) ? perm[rs + t] : 0;
    __syncthreads();
    int c0 = (bid & 31) * 64;
    const int w = t >> 6, lane = t & 63;
    const int wr = w >> 1, wc = w & 1;
    const int sid = w * 64 + lane;
    const int g = lane >> 4, r16 = lane & 15;

    const __hip_bfloat16* Bp = Bt + (size_t)e * FF * DD;

    f32x4 acc[4][4] = {};

    for (int k0 = 0; k0 < DD; k0 += 32) {
#pragma unroll
        for (int j = 0; j < 2; ++j) {
            int id = j * 256 + sid;
            int rrow = id >> 2, sl = id & 3;
            int slog = sl ^ ((rrow >> 1) & 3);
            size_t lbase = (size_t)(j * 256 + w * 64) * 8;
            gload16(A + (size_t)permS[rrow] * DD + k0 + slog * 8, &As[lbase]);
            int q = rrow >> 4, rr = rrow & 15;
            int wrow = c0 + (q >> 2) * 32 + ((q & 3) >> 1) * 16 + rr + (q & 1) * 2048;
            gload16(Bp + (size_t)wrow * DD + k0 + slog * 8, &Bs[lbase]);
        }
        __syncthreads();
        bf16x8 af[4], bfr[4];
#pragma unroll
        for (int i = 0; i < 4; ++i) {
            int ra = wr * 64 + i * 16 + r16;
            int pa = g ^ ((ra >> 1) & 3);
            af[i] = *(const bf16x8*)&As[ra * 32 + pa * 8];
            int rb = wc * 64 + i * 16 + r16;
            int pb = g ^ ((rb >> 1) & 3);
            bfr[i] = *(const bf16x8*)&Bs[rb * 32 + pb * 8];
        }
#pragma unroll
        for (int i = 0; i < 4; ++i)
#pragma unroll
            for (int n = 0; n < 4; ++n)
                acc[i][n] = __builtin_amdgcn_mfma_f32_16x16x32_bf16(af[i], bfr[n], acc[i][n], 0, 0, 0);
        __syncthreads();
    }

#pragma unroll
    for (int i = 0; i < 4; ++i) {
#pragma unroll
        for (int p2 = 0; p2 < 2; ++p2) {
            int col = c0 + wc * 32 + p2 * 16 + r16;
#pragma unroll
            for (int q = 0; q < 4; ++q) {
                int r = wr * 64 + i * 16 + g * 4 + q;
                if (r < rows) {
                    float a  = acc[i][2 * p2][q];
                    float gv = acc[i][2 * p2 + 1][q];
                    act[(size_t)(rs + r) * 2048 + col] =
                        __float2bfloat16((a / (1.f + expf(-a))) * gv);
                }
            }
        }
    }
}

// ---------------- MoE down-proj, 64x128 tile (BM=64 tile list): out = x2 + gate*(act@woT^T) ----------
__global__ void k_moe_dn(const __hip_bfloat16* __restrict__ A,     // act (perm rows, 2048)
                         const __hip_bfloat16* __restrict__ Bt,    // woT (E,1024,2048)
                         const float* __restrict__ addsrc, float* __restrict__ Cf,
                         const int* __restrict__ perm,
                         const int* __restrict__ te2, const int* __restrict__ ts2,
                         const int* __restrict__ tr2, const int* __restrict__ ntl2,
                         const float* __restrict__ gate) {
    __shared__ __align__(16) short As[64 * 32];
    __shared__ __align__(16) short Bs[128 * 32];
    __shared__ int permS[64];
    int tile = blockIdx.y;
    if (tile >= *ntl2) return;
    int e = te2[tile], rs = ts2[tile], rows = tr2[tile];
    const int t = threadIdx.x;
    if (t < 64) permS[t] = (t < rows) ? perm[rs + t] : 0;
    __syncthreads();
    int n0 = blockIdx.x * 128;
    const int w = t >> 6, lane = t & 63;
    const int sid = w * 64 + lane;
    const int g = lane >> 4, r16 = lane & 15;
    const int K = FF / 2;

    const __hip_bfloat16* Bp = Bt + (size_t)e * DD * (FF / 2);

    f32x4 acc[4][2] = {};

    for (int k0 = 0; k0 < K; k0 += 32) {
        {   // A: 64 rows, 1 pass
            int rrow = sid >> 2, sl = sid & 3;
            int slog = sl ^ ((rrow >> 1) & 3);
            size_t lbase = (size_t)(w * 64) * 8;
            gload16(A + (size_t)(rs + rrow) * K + k0 + slog * 8, &As[lbase]);
        }
#pragma unroll
        for (int j = 0; j < 2; ++j) {   // B: 128 rows, 2 passes
            int id = j * 256 + sid;
            int rrow = id >> 2, sl = id & 3;
            int slog = sl ^ ((rrow >> 1) & 3);
            size_t lbase = (size_t)(j * 256 + w * 64) * 8;
            gload16(Bp + (size_t)(n0 + rrow) * K + k0 + slog * 8, &Bs[lbase]);
        }
        __syncthreads();
        bf16x8 af[4], bfr[2];
#pragma unroll
        for (int i = 0; i < 4; ++i) {
            int ra = i * 16 + r16;
            int pa = g ^ ((ra >> 1) & 3);
            af[i] = *(const bf16x8*)&As[ra * 32 + pa * 8];
        }
#pragma unroll
        for (int n = 0; n < 2; ++n) {
            int rb = w * 32 + n * 16 + r16;
            int pb = g ^ ((rb >> 1) & 3);
            bfr[n] = *(const bf16x8*)&Bs[rb * 32 + pb * 8];
        }
#pragma unroll
        for (int i = 0; i < 4; ++i)
#pragma unroll
            for (int n = 0; n < 2; ++n)
                acc[i][n] = __builtin_amdgcn_mfma_f32_16x16x32_bf16(af[i], bfr[n], acc[i][n], 0, 0, 0);
        __syncthreads();
    }

#pragma unroll
    for (int i = 0; i < 4; ++i) {
#pragma unroll
        for (int n = 0; n < 2; ++n) {
            int col = n0 + w * 32 + n * 16 + r16;
#pragma unroll
            for (int q = 0; q < 4; ++q) {
                int r = i * 16 + g * 4 + q;
                if (r >= rows) continue;
                int tok = permS[r];
                Cf[(size_t)tok * DD + col] = addsrc[(size_t)tok * DD + col] + gate[tok] * acc[i][n][q];
            }
        }
    }
}

// ---------------- attention prep: split K -> [b,h,s,d] swz, V^T -> [b,h,d,s] swz ----------------
__global__ void k_prep(const float* __restrict__ qkv, short* __restrict__ KH, short* __restrict__ KL,
                       short* __restrict__ VH, short* __restrict__ VL) {
    __shared__ float tile[64][65];
    int b = blockIdx.z, h = blockIdx.y, s0 = blockIdx.x * 64;
    int t = threadIdx.x;
    int row = t >> 2, c0 = (t & 3) * 16;
    const float* kp = qkv + (size_t)(b * SS + s0 + row) * 3072 + 1024 + h * 64 + c0;
    const float* vp = kp + 1024;
    {
        size_t krow = ((size_t)(b * HH + h) * SS + s0 + row) * 64;
        int key = (s0 + row) & 7;
#pragma unroll
        for (int g2 = 0; g2 < 2; ++g2) {
            s16x8 hv, lv;
#pragma unroll
            for (int j = 0; j < 8; ++j) {
                float v = kp[g2 * 8 + j];
                short hh = bfh(v);
                hv[j] = hh; lv[j] = bfh(v - bf2f(hh));
            }
            int p = ((c0 >> 3) + g2) ^ key;
            *(s16x8*)&KH[krow + p * 8] = hv;
            *(s16x8*)&KL[krow + p * 8] = lv;
        }
    }
#pragma unroll
    for (int j = 0; j < 16; ++j) tile[row][c0 + j] = vp[j];
    __syncthreads();
    {
        int d = t >> 2, sc = (t & 3) * 16;
        size_t vrow = ((size_t)(b * HH + h) * 64 + d) * SS + s0;
        int key = d & 7;
#pragma unroll
        for (int g2 = 0; g2 < 2; ++g2) {
            s16x8 hv, lv;
#pragma unroll
            for (int j = 0; j < 8; ++j) {
                float v = tile[sc + g2 * 8 + j][d];
                short hh = bfh(v);
                hv[j] = hh; lv[j] = bfh(v - bf2f(hh));
            }
            int p = ((sc >> 3) + g2) ^ key;
            *(s16x8*)&VH[vrow + p * 8] = hv;
            *(s16x8*)&VL[vrow + p * 8] = lv;
        }
    }
}

// ---------------- MFMA flash attention, split precision, dbuf, 8 waves x 16 q-rows (QB=128),
// 1D XCD-swizzled grid: 256 blocks, id&7 = XCD, 4 (b,h) per XCD ----------------
#define LDP 72
__global__ __launch_bounds__(512, 1)
void k_attn_mfma(const float* __restrict__ qkv,
                 const short* __restrict__ KH, const short* __restrict__ KL,
                 const short* __restrict__ VH, const short* __restrict__ VL,
                 __hip_bfloat16* __restrict__ ohi, __hip_bfloat16* __restrict__ olo) {
    __shared__ __align__(16) short Ks[2][64 * 64], Kl2[2][64 * 64], Vs[2][64 * 64], Vl2[2][64 * 64];
    __shared__ __align__(16) short PhS[8][16 * LDP], PlS[8][16 * LDP];
    int id = blockIdx.x;
    int xcd = id & 7, slot = id >> 3;
    int bh = xcd * 4 + (slot >> 3);
    int q0 = (slot & 7) * 128;
    int b = bh >> 4, h = bh & 15;
    int t = threadIdx.x;
    int w = t >> 6, lane = t & 63;
    int g = lane >> 4, r16 = lane & 15;
    int srow = t >> 3, sslot = t & 7;

    const size_t kbase = ((size_t)bh * SS) * 64;
    const size_t vbase = ((size_t)bh * 64) * SS;

    bf16x8 qfh[2], qfl[2];
    {
        const float* qp = qkv + (size_t)(b * SS + q0 + w * 16 + r16) * 3072 + h * 64;
#pragma unroll
        for (int ks = 0; ks < 2; ++ks) {
            float vv[8];
            *(float4*)&vv[0] = *(const float4*)(qp + ks * 32 + g * 8);
            *(float4*)&vv[4] = *(const float4*)(qp + ks * 32 + g * 8 + 4);
#pragma unroll
            for (int j = 0; j < 8; ++j) {
                float sv = vv[j] * 0.125f;
                short hh = bfh(sv);
                qfh[ks][j] = hh;
                qfl[ks][j] = bfh(sv - bf2f(hh));
            }
        }
    }

    float mrun[4], lrun[4];
    f32x4 oacc[4] = {};
#pragma unroll
    for (int q = 0; q < 4; ++q) { mrun[q] = -1e30f; lrun[q] = 0.f; }

    gload16(KH + kbase + (size_t)srow * 64 + sslot * 8, &Ks[0][w * 512]);
    gload16(KL + kbase + (size_t)srow * 64 + sslot * 8, &Kl2[0][w * 512]);
    gload16(VH + vbase + (size_t)srow * SS + sslot * 8, &Vs[0][w * 512]);
    gload16(VL + vbase + (size_t)srow * SS + sslot * 8, &Vl2[0][w * 512]);
    __syncthreads();

    int cur = 0;
    for (int k0 = 0; k0 < SS; k0 += 64) {
        if (k0 + 64 < SS) {
            int kn = k0 + 64;
            gload16(KH + kbase + (size_t)(kn + srow) * 64 + sslot * 8, &Ks[cur ^ 1][w * 512]);
            gload16(KL + kbase + (size_t)(kn + srow) * 64 + sslot * 8, &Kl2[cur ^ 1][w * 512]);
            gload16(VH + vbase + (size_t)srow * SS + kn + sslot * 8,   &Vs[cur ^ 1][w * 512]);
            gload16(VL + vbase + (size_t)srow * SS + kn + sslot * 8,   &Vl2[cur ^ 1][w * 512]);
        }

        f32x4 accs[4] = {};
#pragma unroll
        for (int ks = 0; ks < 2; ++ks) {
            bf16x8 kfh[4], kfl[4];
#pragma unroll
            for (int n = 0; n < 4; ++n) {
                int rb = n * 16 + r16;
                int p = (ks * 4 + g) ^ (r16 & 7);
                kfh[n] = *(const bf16x8*)&Ks[cur][rb * 64 + p * 8];
                kfl[n] = *(const bf16x8*)&Kl2[cur][rb * 64 + p * 8];
            }
            __builtin_amdgcn_s_setprio(1);
#pragma unroll
            for (int n = 0; n < 4; ++n) {
                accs[n] = __builtin_amdgcn_mfma_f32_16x16x32_bf16(qfh[ks], kfh[n], accs[n], 0, 0, 0);
                accs[n] = __builtin_amdgcn_mfma_f32_16x16x32_bf16(qfh[ks], kfl[n], accs[n], 0, 0, 0);
                accs[n] = __builtin_amdgcn_mfma_f32_16x16x32_bf16(qfl[ks], kfh[n], accs[n], 0, 0, 0);
            }
            __builtin_amdgcn_s_setprio(0);
        }

        float mn[4], corr[4], psum[4];
#pragma unroll
        for (int q = 0; q < 4; ++q) {
            float m = fmaxf(fmaxf(accs[0][q], accs[1][q]), fmaxf(accs[2][q], accs[3][q]));
            m = fmaxf(m, __shfl_xor(m, 1));
            m = fmaxf(m, __shfl_xor(m, 2));
            m = fmaxf(m, __shfl_xor(m, 4));
            m = fmaxf(m, __shfl_xor(m, 8));
            mn[q] = fmaxf(mrun[q], m);
            corr[q] = expf(mrun[q] - mn[q]);
            mrun[q] = mn[q];
            psum[q] = 0.f;
        }
#pragma unroll
        for (int n = 0; n < 4; ++n)
#pragma unroll
            for (int q = 0; q < 4; ++q) {
                float p = expf(accs[n][q] - mn[q]);
                psum[q] += p;
                short ph = bfh(p);
                PhS[w][(g * 4 + q) * LDP + n * 16 + r16] = ph;
                PlS[w][(g * 4 + q) * LDP + n * 16 + r16] = bfh(p - bf2f(ph));
            }
#pragma unroll
        for (int q = 0; q < 4; ++q) {
            psum[q] += __shfl_xor(psum[q], 1);
            psum[q] += __shfl_xor(psum[q], 2);
            psum[q] += __shfl_xor(psum[q], 4);
            psum[q] += __shfl_xor(psum[q], 8);
            lrun[q] = lrun[q] * corr[q] + psum[q];
#pragma unroll
            for (int n = 0; n < 4; ++n) oacc[n][q] *= corr[q];
        }

#pragma unroll
        for (int ks = 0; ks < 2; ++ks) {
            bf16x8 vfh[4], vfl[4];
#pragma unroll
            for (int n = 0; n < 4; ++n) {
                int rb = n * 16 + r16;
                int p = (ks * 4 + g) ^ (r16 & 7);
                vfh[n] = *(const bf16x8*)&Vs[cur][rb * 64 + p * 8];
                vfl[n] = *(const bf16x8*)&Vl2[cur][rb * 64 + p * 8];
            }
            bf16x8 pfh = *(const bf16x8*)&PhS[w][r16 * LDP + ks * 32 + g * 8];
            bf16x8 pfl = *(const bf16x8*)&PlS[w][r16 * LDP + ks * 32 + g * 8];
            __builtin_amdgcn_s_setprio(1);
#pragma unroll
            for (int n = 0; n < 4; ++n) {
                oacc[n] = __builtin_amdgcn_mfma_f32_16x16x32_bf16(pfh, vfh[n], oacc[n], 0, 0, 0);
                oacc[n] = __builtin_amdgcn_mfma_f32_16x16x32_bf16(pfh, vfl[n], oacc[n], 0, 0, 0);
                oacc[n] = __builtin_amdgcn_mfma_f32_16x16x32_bf16(pfl, vfh[n], oacc[n], 0, 0, 0);
            }
            __builtin_amdgcn_s_setprio(0);
        }
        __syncthreads();
        cur ^= 1;
    }

    float invl[4];
#pragma unroll
    for (int q = 0; q < 4; ++q) invl[q] = 1.f / lrun[q];
#pragma unroll
    for (int n = 0; n < 4; ++n) {
        int col = h * 64 + n * 16 + r16;
#pragma unroll
        for (int q = 0; q < 4; ++q) {
            int rowg = b * SS + q0 + w * 16 + g * 4 + q;
            split_write(oacc[n][q] * invl[q], ohi, olo, (size_t)rowg * DD + col);
        }
    }
}

// ---------------- fused LN2 + router ----------------
__global__ void k_ln2_router(const float* __restrict__ x2, const float* __restrict__ w,
                             const float* __restrict__ b, const float* __restrict__ wr,
                             __hip_bfloat16* __restrict__ h2b, float* __restrict__ logits,
                             float* __restrict__ gate, int* __restrict__ eid,
                             int* __restrict__ counts) {
    int m = blockIdx.x, t = threadIdx.x;
    __shared__ float red[8];
    __shared__ float racc[4][8];
    const float* xp = x2 + (size_t)m * DD;
    float v[4];
    float sum = 0.f, sumsq = 0.f;
#pragma unroll
    for (int l = 0; l < 4; ++l) {
        v[l] = xp[t + l * 256];
        sum += v[l]; sumsq += v[l] * v[l];
    }
#pragma unroll
    for (int off = 32; off; off >>= 1) {
        sum   += __shfl_xor(sum, off);
        sumsq += __shfl_xor(sumsq, off);
    }
    int wid = t >> 6, lane = t & 63;
    if (lane == 0) { red[wid] = sum; red[4 + wid] = sumsq; }
    __syncthreads();
    sum   = red[0] + red[1] + red[2] + red[3];
    sumsq = red[4] + red[5] + red[6] + red[7];
    float mean = sum * (1.f / DD);
    float var  = sumsq * (1.f / DD) - mean * mean;
    float rstd = rsqrtf(var + 1e-5f);
    float acc[EE] = {};
#pragma unroll
    for (int l = 0; l < 4; ++l) {
        int i = t + l * 256;
        float hv = (v[l] - mean) * rstd * w[i] + b[i];
        h2b[(size_t)m * DD + i] = __float2bfloat16(hv);
        const float* wp = wr + (size_t)i * EE;
#pragma unroll
        for (int n = 0; n < EE; ++n) acc[n] += hv * wp[n];
    }
#pragma unroll
    for (int off = 32; off; off >>= 1)
#pragma unroll
        for (int n = 0; n < EE; ++n) acc[n] += __shfl_xor(acc[n], off);
    if (lane == 0)
#pragma unroll
        for (int n = 0; n < EE; ++n) racc[wid][n] = acc[n];
    __syncthreads();
    if (t == 0) {
        float lg[EE];
#pragma unroll
        for (int n = 0; n < EE; ++n) lg[n] = racc[0][n] + racc[1][n] + racc[2][n] + racc[3][n];
        float mx = lg[0]; int best = 0;
#pragma unroll
        for (int n = 1; n < EE; ++n) if (lg[n] > mx) { mx = lg[n]; best = n; }
        float den = 0.f;
#pragma unroll
        for (int n = 0; n < EE; ++n) den += expf(lg[n] - mx);
        gate[m] = 1.f / den;
        eid[m] = best;
        atomicAdd(&counts[best], 1);
#pragma unroll
        for (int n = 0; n < EE; ++n) logits[(size_t)m * EE + n] = lg[n];
    }
}

// ---------------- fused routing bookkeeping: offsets + dual tile lists + scatter ----------------
__global__ void k_offscatter(const int* __restrict__ counts,
                             int* __restrict__ te, int* __restrict__ ts, int* __restrict__ tr,
                             int* __restrict__ ntl,
                             int* __restrict__ te2, int* __restrict__ ts2, int* __restrict__ tr2,
                             int* __restrict__ ntl2,
                             const int* __restrict__ eid,
                             int* __restrict__ fill, int* __restrict__ perm) {
    __shared__ int soffs[EE];
    int t = threadIdx.x;
    if (t == 0) {
        int off = 0, nt = 0, nt2 = 0;
        for (int e = 0; e < EE; ++e) {
            soffs[e] = off;
            int c = counts[e];
            for (int t0 = 0; t0 < c; t0 += 128) {
                te[nt] = e; ts[nt] = off + t0; tr[nt] = (c - t0 < 128) ? (c - t0) : 128; ++nt;
            }
            for (int t0 = 0; t0 < c; t0 += 64) {
                te2[nt2] = e; ts2[nt2] = off + t0; tr2[nt2] = (c - t0 < 64) ? (c - t0) : 64; ++nt2;
            }
            off += c;
        }
        *ntl = nt;
        *ntl2 = nt2;
    }
    __syncthreads();
#pragma unroll
    for (int tok = t; tok < MM; tok += 1024) {
        int e = eid[tok];
        int pos = soffs[e] + atomicAdd(&fill[e], 1);
        perm[pos] = tok;
    }
}

// ---------------- launch ----------------
extern "C" void kernel_launch(void* const* d_in, const int* in_sizes, int n_in,
                              void* d_out, int out_size, void* d_ws, size_t ws_size,
                              hipStream_t stream) {
    const float* x     = (const float*)d_in[0];
    const float* ln1w  = (const float*)d_in[1];
    const float* ln1b  = (const float*)d_in[2];
    const float* ln2w  = (const float*)d_in[3];
    const float* ln2b  = (const float*)d_in[4];
    const float* w_qkv = (const float*)d_in[5];
    const float* b_qkv = (const float*)d_in[6];
    const float* w_out = (const float*)d_in[7];
    const float* b_out = (const float*)d_in[8];
    const float* w_rtr = (const float*)d_in[9];
    const float* wi    = (const float*)d_in[10];
    const float* wo    = (const float*)d_in[11];
    float* out = (float*)d_out;

    char* wsb = (char*)d_ws;
    __hip_bfloat16* wiT  = (__hip_bfloat16*)(wsb + OFF_WIT);
    __hip_bfloat16* woT  = (__hip_bfloat16*)(wsb + OFF_WOT);
    __hip_bfloat16* wqH  = (__hip_bfloat16*)(wsb + OFF_WQH);
    __hip_bfloat16* wqL  = (__hip_bfloat16*)(wsb + OFF_WQL);
    __hip_bfloat16* woH  = (__hip_bfloat16*)(wsb + OFF_WOH);
    __hip_bfloat16* woL  = (__hip_bfloat16*)(wsb + OFF_WOL);
    __hip_bfloat16* h1H  = (__hip_bfloat16*)(wsb + OFF_H1H);
    __hip_bfloat16* h1L  = (__hip_bfloat16*)(wsb + OFF_H1L);
    float*          qkvF = (float*)(wsb + OFF_QKV);
    __hip_bfloat16* oH   = (__hip_bfloat16*)(wsb + OFF_OH);
    __hip_bfloat16* oL   = (__hip_bfloat16*)(wsb + OFF_OL);
    float*          x2F  = (float*)(wsb + OFF_X2);
    __hip_bfloat16* h2B  = (__hip_bfloat16*)(wsb + OFF_H2B);
    __hip_bfloat16* actB = (__hip_bfloat16*)(wsb + OFF_ACT);
    short* KSH = (short*)(wsb + OFF_KSH);
    short* KSL = (short*)(wsb + OFF_KSL);
    short* VTH = (short*)(wsb + OFF_VTH);
    short* VTL = (short*)(wsb + OFF_VTL);
    float* gate = (float*)(wsb + OFF_GATE);
    int* eid    = (int*)(wsb + OFF_EID);
    int* perm   = (int*)(wsb + OFF_PERM);
    int* counts = (int*)(wsb + OFF_CNT);
    int* fill   = (int*)(wsb + OFF_FILL);
    int* ntl    = (int*)(wsb + OFF_NT);
    int* te     = (int*)(wsb + OFF_TE);
    int* tsx    = (int*)(wsb + OFF_TS);
    int* trx    = (int*)(wsb + OFF_TR);
    int* te2    = (int*)(wsb + OFF_TE2);
    int* ts2    = (int*)(wsb + OFF_TS2);
    int* tr2    = (int*)(wsb + OFF_TR2);
    int* ntl2   = (int*)(wsb + OFF_NT2);

    // 1. slim phase-0: LN1+RoPE + w_qkv split-cvt
    k_phase0<<<5120, 256, 0, stream>>>(x, ln1w, ln1b, h1H, h1L, w_qkv, wqH, wqL);
    // 2. qkv GEMM mega: GEMM + wi tcvt + w_out cvt (wo tcvt moved to moe_up mega)
    k_qkv_mega<<<9600, 256, 0, stream>>>(h1H, h1L, wqH, wqL, b_qkv, qkvF,
                                         wi, wiT, w_out, woH, woL);
    // 3. prep: split K + transposed V
    k_prep<<<dim3(SS / 64, HH, BB), 256, 0, stream>>>(qkvF, KSH, KSL, VTH, VTL);
    // 4. attention
    k_attn_mfma<<<256, 512, 0, stream>>>(qkvF, KSH, KSL, VTH, VTL, oH, oL);
    // 5. x2 = x + o @ w_out^T + b_out (64x128 tile, 256 blocks, 2/CU); zeroes counters
    k_oproj64<<<256, 256, 0, stream>>>(oH, oL, woH, woL, b_out, x, x2F, counts);
    // 6. LN2 + router fused
    k_ln2_router<<<MM, 256, 0, stream>>>(x2F, ln2w, ln2b, w_rtr, h2B,
                                         out + (size_t)MM * DD, gate, eid, counts);
    // 7. offsets + dual tile lists + scatter
    k_offscatter<<<1, 1024, 0, stream>>>(counts, te, tsx, trx, ntl,
                                         te2, ts2, tr2, ntl2, eid, fill, perm);
    // 8. moe_up mega: act GEMM (BM=128 list) + wo tcvt riding spare BW
    k_moe_up<<<768 + 4096, 256, 0, stream>>>(h2B, wiT, actB, perm, te, tsx, trx, ntl,
                                             wo, woT);
    // 9. out = x2 + gate * (act @ woT^T) (64x128 tile, BM=64 list)
    k_moe_dn<<<dim3(DD / 128, MAX_TILES2), 256, 0, stream>>>(
        actB, woT, x2F, out, perm, te2, ts2, tr2, ntl2, gate);
}